// Round 12
// baseline (348.973 us; speedup 1.0000x reference)
//
#include <hip/hip_runtime.h>
#include <math.h>

#define BATCH 8
#define DIM   512
#define NPTS  2048
#define KNN   10
#define NPAIR 45
#define NCHK  32
#define CHKSZ 64

typedef __attribute__((ext_vector_type(8))) short    bf16x8;
typedef __attribute__((ext_vector_type(4))) float    f32x4;
typedef __attribute__((ext_vector_type(4))) unsigned int u32x4;

__device__ inline unsigned short bf16_rne(float x) {
    unsigned int u = __float_as_uint(x);
    u += 0x7FFFu + ((u >> 16) & 1u);
    return (unsigned short)(u >> 16);
}
__device__ inline float bf16_to_f(unsigned short h) {
    return __uint_as_float(((unsigned int)h) << 16);
}

// ===========================================================================
// Kernel S: split se/te into 3 bf16 planes (h,m,l), transposed to [b][n][d].
// ===========================================================================
__global__ __launch_bounds__(256)
void split_kernel(const float* __restrict__ se, const float* __restrict__ te,
                  unsigned short* __restrict__ pA, unsigned short* __restrict__ pB)
{
    const int bid = blockIdx.x;
    const int tensor = bid >> 11;
    const int rr_ = bid & 2047;
    const int b  = rr_ >> 8;
    const int dt = (rr_ >> 5) & 7;
    const int nt = rr_ & 31;
    const float* srcp = (tensor == 0 ? se : te)
                        + ((size_t)b * DIM + dt * 64) * NPTS + nt * 64;
    unsigned short* dst = (tensor == 0 ? pA : pB);
    const size_t PL = (size_t)BATCH * NPTS * DIM;
    unsigned short* base = dst + (size_t)b * NPTS * DIM + (size_t)nt * 64 * DIM + dt * 64;

    __shared__ float T[64][65];
    const int t = threadIdx.x;
    {
        int r = t >> 4, c4 = t & 15;
        #pragma unroll
        for (int it = 0; it < 4; ++it) {
            int d = r + it * 16;
            float4 v = *(const float4*)&srcp[(size_t)d * NPTS + c4 * 4];
            T[d][c4 * 4 + 0] = v.x; T[d][c4 * 4 + 1] = v.y;
            T[d][c4 * 4 + 2] = v.z; T[d][c4 * 4 + 3] = v.w;
        }
    }
    __syncthreads();
    const int n  = t >> 2;
    const int d0 = (t & 3) * 16;
    unsigned short hh[16], mm[16], ll[16];
    #pragma unroll
    for (int j = 0; j < 16; ++j) {
        float a = T[d0 + j][n];
        unsigned short h = bf16_rne(a);
        float r1 = a - bf16_to_f(h);
        unsigned short m = bf16_rne(r1);
        float r2 = r1 - bf16_to_f(m);
        unsigned short l = bf16_rne(r2);
        hh[j] = h; mm[j] = m; ll[j] = l;
    }
    unsigned short* o = base + (size_t)n * DIM + d0;
    *(u32x4*)(o)            = *(u32x4*)&hh[0];
    *(u32x4*)(o + 8)        = *(u32x4*)&hh[8];
    *(u32x4*)(o + PL)       = *(u32x4*)&mm[0];
    *(u32x4*)(o + PL + 8)   = *(u32x4*)&mm[8];
    *(u32x4*)(o + 2*PL)     = *(u32x4*)&ll[0];
    *(u32x4*)(o + 2*PL + 8) = *(u32x4*)&ll[8];
}

// ===========================================================================
// Kernel H: phase-1 GEMM on h-planes only (K=512). Writes uhat (bf16 of
// 10000*dot_h/sqrt(512)) for ALL 2048x2048 per batch.
// ===========================================================================
__global__ __launch_bounds__(256, 2)
void score_h(const unsigned short* __restrict__ pA, const unsigned short* __restrict__ pB,
             unsigned short* __restrict__ uhat)
{
    const int bid  = blockIdx.x;
    const int xcd  = bid & 7;
    const int slot = bid >> 3;
    const int g    = xcd + 8 * (slot >> 4);
    const int ntile = slot & 15;
    const int b    = g >> 2;
    const int mc   = g & 3;
    const int n0 = ntile * 128;
    const int t  = threadIdx.x;
    const int w  = t >> 6;
    const int l  = t & 63;
    const int wn = w >> 1, wm = w & 1;
    const int l15 = l & 15, l4 = l >> 4;

    __shared__ unsigned short As[128 * 64];
    __shared__ unsigned short Bs[128 * 64];

    int srow[4], skg[4], ldsoff[4];
    #pragma unroll
    for (int qq = 0; qq < 4; ++qq) {
        int s = qq * 256 + t;
        int row = s >> 3, slt = s & 7;
        srow[qq] = row;
        skg[qq] = slt ^ (row & 7);
        ldsoff[qq] = row * 64 + slt * 8;
    }
    int aroff[4], arxor[4], broff[4], brxor[4];
    #pragma unroll
    for (int i = 0; i < 4; ++i) {
        int ar = wn * 64 + i * 16 + l15;
        aroff[i] = ar * 64; arxor[i] = ar & 7;
        int br = wm * 64 + i * 16 + l15;
        broff[i] = br * 64; brxor[i] = br & 7;
    }

    const float scl = 10000.0f / sqrtf((float)DIM);
    const unsigned short* Ab = pA + (size_t)b * NPTS * DIM;
    const unsigned short* Bb = pB + (size_t)b * NPTS * DIM;

    for (int mt = 0; mt < 4; ++mt) {
        const int m0 = mc * 512 + mt * 128;
        f32x4 acc[4][4];
        #pragma unroll
        for (int i = 0; i < 4; ++i)
            #pragma unroll
            for (int j = 0; j < 4; ++j) acc[i][j] = (f32x4){0.f, 0.f, 0.f, 0.f};

        for (int k0 = 0; k0 < 512; k0 += 64) {
            __syncthreads();
            bf16x8 ra[4], rb[4];
            #pragma unroll
            for (int qq = 0; qq < 4; ++qq) {
                ra[qq] = *(const bf16x8*)&Ab[(size_t)(n0 + srow[qq]) * DIM + k0 + skg[qq] * 8];
                rb[qq] = *(const bf16x8*)&Bb[(size_t)(m0 + srow[qq]) * DIM + k0 + skg[qq] * 8];
            }
            #pragma unroll
            for (int qq = 0; qq < 4; ++qq) {
                *(bf16x8*)&As[ldsoff[qq]] = ra[qq];
                *(bf16x8*)&Bs[ldsoff[qq]] = rb[qq];
            }
            __syncthreads();
            #pragma unroll
            for (int ks = 0; ks < 2; ++ks) {
                bf16x8 af[4], bfr[4];
                #pragma unroll
                for (int i = 0; i < 4; ++i) {
                    af[i]  = *(const bf16x8*)&As[aroff[i] + (((ks * 4 + l4) ^ arxor[i]) * 8)];
                    bfr[i] = *(const bf16x8*)&Bs[broff[i] + (((ks * 4 + l4) ^ brxor[i]) * 8)];
                }
                #pragma unroll
                for (int i = 0; i < 4; ++i)
                    #pragma unroll
                    for (int j = 0; j < 4; ++j)
                        acc[i][j] = __builtin_amdgcn_mfma_f32_16x16x32_bf16(af[i], bfr[j], acc[i][j], 0, 0, 0);
            }
        }
        #pragma unroll
        for (int i = 0; i < 4; ++i) {
            #pragma unroll
            for (int j = 0; j < 4; ++j) {
                int mcol = m0 + wm * 64 + j * 16 + l15;
                #pragma unroll
                for (int r = 0; r < 4; ++r) {
                    int nabs = n0 + wn * 64 + i * 16 + l4 * 4 + r;
                    uhat[((size_t)(b * NPTS + nabs)) * NPTS + mcol] =
                        bf16_rne(scl * acc[i][j][r]);
                }
            }
        }
    }
}

// ===========================================================================
// Kernel R: resolve. One wave per row. Fast path register-only; slow path
// wave-parallel exact 26-bit rescore.
// ===========================================================================
__global__ __launch_bounds__(256)
void resolve(const unsigned short* __restrict__ uhat,
             const unsigned short* __restrict__ pA, const unsigned short* __restrict__ pB,
             const float* __restrict__ tgt,
             float* __restrict__ corr_tgt, int* __restrict__ corres_i,
             float* __restrict__ corres_out)
{
    const int wid  = threadIdx.x >> 6;
    const int lane = threadIdx.x & 63;
    const int gid  = blockIdx.x * 4 + wid;
    const int b    = gid >> 11;
    const int n    = gid & 2047;

    __shared__ int s_m[4][64];
    __shared__ int s_cnt[4];

    if (lane == 0) s_cnt[wid] = 0;
    __syncthreads();

    const unsigned short* urow = uhat + (size_t)gid * NPTS;
    float v[32];
    float lmax = -3.402823466e38f; int lk = 0;
    #pragma unroll
    for (int g2 = 0; g2 < 4; ++g2) {
        u32x4 pk = *(const u32x4*)&urow[lane * 32 + g2 * 8];
        #pragma unroll
        for (int e = 0; e < 4; ++e) {
            unsigned int w2 = pk[e];
            float f0 = __uint_as_float((w2 & 0xFFFFu) << 16);
            float f1 = __uint_as_float(w2 & 0xFFFF0000u);
            int k0 = g2 * 8 + e * 2;
            v[k0] = f0; v[k0 + 1] = f1;
            if (f0 > lmax) { lmax = f0; lk = k0; }
            if (f1 > lmax) { lmax = f1; lk = k0 + 1; }
        }
    }
    float vmax = lmax; int argm = lane * 32 + lk;
    #pragma unroll
    for (int mask = 1; mask < 64; mask <<= 1) {
        float ov = __shfl_xor(vmax, mask);
        int   oi = __shfl_xor(argm, mask);
        if (ov > vmax || (ov == vmax && oi < argm)) { vmax = ov; argm = oi; }
    }
    const float cut = vmax - 1200.0f;
    int cnt = 0;
    #pragma unroll
    for (int k = 0; k < 32; ++k) cnt += (v[k] >= cut) ? 1 : 0;
    int nc = cnt;
    #pragma unroll
    for (int mask = 1; mask < 64; mask <<= 1) nc += __shfl_xor(nc, mask);

    if (nc > 1) {
        #pragma unroll
        for (int k = 0; k < 32; ++k) {
            if (v[k] >= cut) {
                int slot = atomicAdd(&s_cnt[wid], 1);
                if (slot < 64) s_m[wid][slot] = lane * 32 + k;
            }
        }
    }
    __syncthreads();
    if (nc > 1 && lane == 0) {
        int ncc = nc > 64 ? 64 : nc;
        for (int i = 1; i < ncc; ++i) {
            int key = s_m[wid][i]; int j = i - 1;
            while (j >= 0 && s_m[wid][j] > key) { s_m[wid][j + 1] = s_m[wid][j]; --j; }
            s_m[wid][j + 1] = key;
        }
    }
    __syncthreads();

    if (nc == 1) {
        if (lane < 3) corr_tgt[(size_t)gid * 3 + lane] = tgt[((size_t)b * 3 + lane) * NPTS + argm];
        if (lane == 0) { corres_i[gid] = argm; corres_out[gid] = (float)argm; }
        return;
    }
    const int ncc = nc > 64 ? 64 : nc;

    const size_t PL = (size_t)BATCH * NPTS * DIM;
    const unsigned short* Ar = pA + ((size_t)b * NPTS + n) * DIM + lane * 8;
    bf16x8 a_h = *(const bf16x8*)&Ar[0];
    bf16x8 a_m = *(const bf16x8*)&Ar[PL];
    bf16x8 a_l = *(const bf16x8*)&Ar[2 * PL];
    float ah[8], am[8], al[8];
    #pragma unroll
    for (int e = 0; e < 8; ++e) {
        ah[e] = bf16_to_f((unsigned short)a_h[e]);
        am[e] = bf16_to_f((unsigned short)a_m[e]);
        al[e] = bf16_to_f((unsigned short)a_l[e]);
    }

    const float sqd = sqrtf((float)DIM);
    float umax = -3.402823466e38f; int uarg = 0x7fffffff;
    float myu = 0.f;
    for (int c = 0; c < ncc; ++c) {
        int mB = s_m[wid][c];
        const unsigned short* Br = pB + ((size_t)b * NPTS + mB) * DIM + lane * 8;
        bf16x8 b_h = *(const bf16x8*)&Br[0];
        bf16x8 b_m = *(const bf16x8*)&Br[PL];
        bf16x8 b_l = *(const bf16x8*)&Br[2 * PL];
        float part = 0.f;
        #pragma unroll
        for (int e = 0; e < 8; ++e) {
            float bh = bf16_to_f((unsigned short)b_h[e]);
            float bm = bf16_to_f((unsigned short)b_m[e]);
            float bl = bf16_to_f((unsigned short)b_l[e]);
            part += ah[e] * bh;
            part += ah[e] * bm;
            part += am[e] * bh;
            part += ah[e] * bl;
            part += am[e] * bm;
            part += al[e] * bh;
        }
        #pragma unroll
        for (int mask = 1; mask < 64; mask <<= 1) part += __shfl_xor(part, mask);
        float u = 10000.0f * (part / sqd);
        if (u > umax) { umax = u; uarg = mB; }
        if (lane == c) myu = u;
    }

    float p = (lane < ncc) ? expf(myu - umax) : 0.f;
    int myM = (lane < ncc) ? s_m[wid][lane] : 0;
    float tx = 0.f, ty = 0.f, tz = 0.f, ps = p;
    if (lane < ncc) {
        tx = p * tgt[((size_t)b * 3 + 0) * NPTS + myM];
        ty = p * tgt[((size_t)b * 3 + 1) * NPTS + myM];
        tz = p * tgt[((size_t)b * 3 + 2) * NPTS + myM];
    }
    #pragma unroll
    for (int mask = 1; mask < 64; mask <<= 1) {
        ps += __shfl_xor(ps, mask);
        tx += __shfl_xor(tx, mask);
        ty += __shfl_xor(ty, mask);
        tz += __shfl_xor(tz, mask);
    }
    if (lane == 0) {
        corr_tgt[(size_t)gid * 3 + 0] = tx / ps;
        corr_tgt[(size_t)gid * 3 + 1] = ty / ps;
        corr_tgt[(size_t)gid * 3 + 2] = tz / ps;
        corres_i[gid]   = uarg;
        corres_out[gid] = (float)uarg;
    }
}

// ===========================================================================
// FALLBACK Kernel A (round-8 proven): 6-product MFMA + fused online softmax
// ===========================================================================
__global__ __launch_bounds__(256, 2)
void score_mfma(const unsigned short* __restrict__ pA, const unsigned short* __restrict__ pB,
                const float* __restrict__ tgt, float* __restrict__ part)
{
    const int bid  = blockIdx.x;
    const int xcd  = bid & 7;
    const int slot = bid >> 3;
    const int g    = xcd + 8 * (slot >> 4);
    const int ntile = slot & 15;
    const int b    = g >> 2;
    const int mc   = g & 3;
    const int n0 = ntile * 128;
    const int t  = threadIdx.x;
    const int w  = t >> 6;
    const int l  = t & 63;
    const int wn = w >> 1, wm = w & 1;
    const int l15 = l & 15, l4 = l >> 4;

    __shared__ unsigned short As[128 * 64];
    __shared__ unsigned short Bs[128 * 64];

    const size_t PL = (size_t)BATCH * NPTS * DIM;

    int srow[4], skg[4], ldsoff[4];
    #pragma unroll
    for (int qq = 0; qq < 4; ++qq) {
        int s = qq * 256 + t;
        int row = s >> 3, slt = s & 7;
        srow[qq] = row;
        skg[qq] = slt ^ (row & 7);
        ldsoff[qq] = row * 64 + slt * 8;
    }
    int aroff[4], arxor[4], broff[4], brxor[4];
    #pragma unroll
    for (int i = 0; i < 4; ++i) {
        int ar = wn * 64 + i * 16 + l15;
        aroff[i] = ar * 64; arxor[i] = ar & 7;
        int br = wm * 64 + i * 16 + l15;
        broff[i] = br * 64; brxor[i] = br & 7;
    }

    float mx[16], sm[16], ax[16], ay[16], az[16]; int ag[16];
    #pragma unroll
    for (int si = 0; si < 16; ++si) {
        mx[si] = -3.402823466e38f; sm[si] = 0.f;
        ax[si] = 0.f; ay[si] = 0.f; az[si] = 0.f; ag[si] = 0;
    }

    const float sqd = sqrtf((float)DIM);
    const unsigned short* Ab = pA + (size_t)b * NPTS * DIM;
    const unsigned short* Bb = pB + (size_t)b * NPTS * DIM;
    const int AIDX[6] = {0, 0, 1, 0, 1, 2};
    const int BIDX[6] = {0, 1, 0, 2, 1, 0};

    for (int mt = 0; mt < 4; ++mt) {
        const int m0 = mc * 512 + mt * 128;
        f32x4 acc[4][4];
        #pragma unroll
        for (int i = 0; i < 4; ++i)
            #pragma unroll
            for (int j = 0; j < 4; ++j) acc[i][j] = (f32x4){0.f, 0.f, 0.f, 0.f};

        for (int q = 0; q < 6; ++q) {
            const unsigned short* Ap = Ab + (size_t)AIDX[q] * PL;
            const unsigned short* Bp = Bb + (size_t)BIDX[q] * PL;
            for (int k0 = 0; k0 < 512; k0 += 64) {
                __syncthreads();
                bf16x8 ra[4], rb[4];
                #pragma unroll
                for (int qq = 0; qq < 4; ++qq) {
                    ra[qq] = *(const bf16x8*)&Ap[(size_t)(n0 + srow[qq]) * DIM + k0 + skg[qq] * 8];
                    rb[qq] = *(const bf16x8*)&Bp[(size_t)(m0 + srow[qq]) * DIM + k0 + skg[qq] * 8];
                }
                #pragma unroll
                for (int qq = 0; qq < 4; ++qq) {
                    *(bf16x8*)&As[ldsoff[qq]] = ra[qq];
                    *(bf16x8*)&Bs[ldsoff[qq]] = rb[qq];
                }
                __syncthreads();
                #pragma unroll
                for (int ks = 0; ks < 2; ++ks) {
                    bf16x8 af[4], bfr[4];
                    #pragma unroll
                    for (int i = 0; i < 4; ++i) {
                        af[i]  = *(const bf16x8*)&As[aroff[i] + (((ks * 4 + l4) ^ arxor[i]) * 8)];
                        bfr[i] = *(const bf16x8*)&Bs[broff[i] + (((ks * 4 + l4) ^ brxor[i]) * 8)];
                    }
                    #pragma unroll
                    for (int i = 0; i < 4; ++i)
                        #pragma unroll
                        for (int j = 0; j < 4; ++j)
                            acc[i][j] = __builtin_amdgcn_mfma_f32_16x16x32_bf16(af[i], bfr[j], acc[i][j], 0, 0, 0);
                }
            }
        }
        float tg0[4], tg1[4], tg2[4];
        #pragma unroll
        for (int j = 0; j < 4; ++j) {
            int mcol = m0 + wm * 64 + j * 16 + l15;
            tg0[j] = tgt[((size_t)b * 3 + 0) * NPTS + mcol];
            tg1[j] = tgt[((size_t)b * 3 + 1) * NPTS + mcol];
            tg2[j] = tgt[((size_t)b * 3 + 2) * NPTS + mcol];
        }
        #pragma unroll
        for (int i = 0; i < 4; ++i) {
            #pragma unroll
            for (int r = 0; r < 4; ++r) {
                const int si = i * 4 + r;
                float u[4];
                float lm = -3.402823466e38f; int la = 0;
                #pragma unroll
                for (int j = 0; j < 4; ++j) {
                    float s  = acc[i][j][r] / sqd;
                    float uu = 10000.0f * s;
                    u[j] = uu;
                    if (uu > lm) { lm = uu; la = m0 + wm * 64 + j * 16 + l15; }
                }
                float nm = fmaxf(mx[si], lm);
                if (lm > mx[si]) ag[si] = la;
                float f = expf(mx[si] - nm);
                mx[si] = nm;
                float s_ = sm[si] * f, x_ = ax[si] * f, y_ = ay[si] * f, z_ = az[si] * f;
                #pragma unroll
                for (int j = 0; j < 4; ++j) {
                    float p = expf(u[j] - nm);
                    s_ += p; x_ += p * tg0[j]; y_ += p * tg1[j]; z_ += p * tg2[j];
                }
                sm[si] = s_; ax[si] = x_; ay[si] = y_; az[si] = z_;
            }
        }
    }

    #pragma unroll
    for (int si = 0; si < 16; ++si) {
        for (int mask = 1; mask < 16; mask <<= 1) {
            float omx = __shfl_xor(mx[si], mask);
            float osm = __shfl_xor(sm[si], mask);
            float oax = __shfl_xor(ax[si], mask);
            float oay = __shfl_xor(ay[si], mask);
            float oaz = __shfl_xor(az[si], mask);
            int   oag = __shfl_xor(ag[si], mask);
            float nm = fmaxf(mx[si], omx);
            float f1 = expf(mx[si] - nm), f2 = expf(omx - nm);
            sm[si] = sm[si] * f1 + osm * f2;
            ax[si] = ax[si] * f1 + oax * f2;
            ay[si] = ay[si] * f1 + oay * f2;
            az[si] = az[si] * f1 + oaz * f2;
            ag[si] = (omx > mx[si]) ? oag : ((omx == mx[si]) ? min(ag[si], oag) : ag[si]);
            mx[si] = nm;
        }
    }
    if (l15 == 0) {
        const int chunk = mc * 2 + wm;
        #pragma unroll
        for (int i = 0; i < 4; ++i)
            #pragma unroll
            for (int r = 0; r < 4; ++r) {
                const int si = i * 4 + r;
                int nabs = n0 + wn * 64 + i * 16 + l4 * 4 + r;
                size_t o = (((size_t)b * NPTS + nabs) * 8 + chunk) * 8;
                part[o + 0] = mx[si]; part[o + 1] = sm[si];
                part[o + 2] = ax[si]; part[o + 3] = ay[si]; part[o + 4] = az[si];
                part[o + 5] = __int_as_float(ag[si]);
            }
    }
}

__global__ __launch_bounds__(256)
void merge8_kernel(const float* __restrict__ part, float* __restrict__ corr_tgt,
                   int* __restrict__ corres_i, float* __restrict__ corres_out)
{
    int r = blockIdx.x * 256 + threadIdx.x;
    float m = -3.402823466e38f, s = 0.f, x = 0.f, y = 0.f, z = 0.f; int a = 0x7fffffff;
    for (int c = 0; c < 8; ++c) {
        const float* p = &part[((size_t)r * 8 + c) * 8];
        float pm = p[0]; int pa = __float_as_int(p[5]);
        float nm = fmaxf(m, pm);
        float f1 = expf(m - nm), f2 = expf(pm - nm);
        s = s * f1 + p[1] * f2;
        x = x * f1 + p[2] * f2;
        y = y * f1 + p[3] * f2;
        z = z * f1 + p[4] * f2;
        if (pm > m) a = pa; else if (pm == m) a = min(a, pa);
        m = nm;
    }
    corr_tgt[(size_t)r * 3 + 0] = x / s;
    corr_tgt[(size_t)r * 3 + 1] = y / s;
    corr_tgt[(size_t)r * 3 + 2] = z / s;
    corres_i[r]   = a;
    corres_out[r] = (float)a;
}

// ===========================================================================
// Kernel B0: P4 = (x,y,z,|p|^2) per source point
// ===========================================================================
__global__ __launch_bounds__(256)
void prep_p4(const float* __restrict__ src, float4* __restrict__ P4)
{
    int i = blockIdx.x * 256 + threadIdx.x;
    int b = i >> 11, m = i & 2047;
    float x = src[((size_t)b * 3 + 0) * NPTS + m];
    float y = src[((size_t)b * 3 + 1) * NPTS + m];
    float z = src[((size_t)b * 3 + 2) * NPTS + m];
    P4[i] = make_float4(x, y, z, x * x + y * y + z * z);
}

// ===========================================================================
// Kernel B1: per-(n, 64-chunk) stable top-10 via u64 keys. 32 chunks/row
// (grid 2048 blocks = 8/CU = full occupancy; same aggregate work as before).
// ===========================================================================
__global__ __launch_bounds__(256)
void knn_scan(const float4* __restrict__ P4, unsigned long long* __restrict__ candK)
{
    const int bid = blockIdx.x;                        // 0..2047
    const int b = bid >> 8, nblk = bid & 255;          // 256 blocks per batch
    const int t = threadIdx.x;
    const int c  = t & (NCHK - 1);                     // chunk 0..31
    const int nl = t >> 5;                             // 0..7
    const int n = nblk * 8 + nl;
    const float4* Pb = P4 + (size_t)b * NPTS;
    const float4 pn = Pb[n];

    unsigned long long kl[KNN];
    #pragma unroll
    for (int k = 0; k < KNN; ++k) kl[k] = 0xFFFFFFFFFFFFFFFFull;

    const int m0 = c * CHKSZ;
    for (int mm = 0; mm < CHKSZ; ++mm) {
        int m = m0 + mm;
        float4 pm = Pb[m];
        float dot = pn.x * pm.x + pn.y * pm.y + pn.z * pm.z;
        float d2  = (pn.w + pm.w) - 2.0f * dot;
        if (d2 < 0.f) d2 = 0.f;
        float w = expf(-d2 * 0.5f);
        unsigned long long key =
            ((unsigned long long)(~__float_as_uint(w)) << 32) | (unsigned int)m;
        if (key < kl[KNN - 1]) {
            unsigned long long ck = key;
            #pragma unroll
            for (int k = 0; k < KNN; ++k) {
                if (ck < kl[k]) { unsigned long long tv = kl[k]; kl[k] = ck; ck = tv; }
            }
        }
    }
    size_t base = (((size_t)b * NPTS + n) * NCHK + c) * KNN;
    #pragma unroll
    for (int k = 0; k < KNN; ++k) candK[base + k] = kl[k];
}

// ===========================================================================
// Kernel B1b: merge 32 chunk-lists of u64 keys -> global top-10 indices
// ===========================================================================
__global__ __launch_bounds__(256)
void merge10_kernel(const unsigned long long* __restrict__ candK, int* __restrict__ topI)
{
    const int gid = blockIdx.x * 256 + threadIdx.x;
    unsigned long long K[KNN];
    #pragma unroll
    for (int k = 0; k < KNN; ++k) K[k] = 0xFFFFFFFFFFFFFFFFull;
    const size_t cb = (size_t)gid * (NCHK * KNN);
    for (int e = 0; e < NCHK * KNN; ++e) {
        unsigned long long ck = candK[cb + e];
        if (ck < K[KNN - 1]) {
            #pragma unroll
            for (int k = 0; k < KNN; ++k) {
                if (ck < K[k]) { unsigned long long tv = K[k]; K[k] = ck; ck = tv; }
            }
        }
    }
    #pragma unroll
    for (int k = 0; k < KNN; ++k)
        topI[(size_t)gid * KNN + k] = (int)(K[k] & 0xFFFFFFFFull);
}

// ===========================================================================
// Kernel B2: wave-per-n GFM finish (4096 blocks x 4 waves)
// ===========================================================================
__global__ __launch_bounds__(256)
void gfm_finish(const float4* __restrict__ P4, const float* __restrict__ corr_tgt,
                const int* __restrict__ topI, float* __restrict__ mean_loss)
{
    const int wid  = threadIdx.x >> 6;
    const int lane = threadIdx.x & 63;
    const int gid  = blockIdx.x * 4 + wid;
    const int b    = gid >> 11;

    __shared__ float PT[4][KNN][6];
    __shared__ float LS[4][48];
    __shared__ float SR[4][48];
    __shared__ float TOT[4][48];

    if (lane < KNN) {
        int idx = topI[(size_t)gid * KNN + lane];
        float4 pk = P4[(b << 11) + idx];
        size_t o = ((size_t)(b << 11) + idx) * 3;
        PT[wid][lane][0] = pk.x; PT[wid][lane][1] = pk.y; PT[wid][lane][2] = pk.z;
        PT[wid][lane][3] = corr_tgt[o];
        PT[wid][lane][4] = corr_tgt[o + 1];
        PT[wid][lane][5] = corr_tgt[o + 2];
    }
    float4 pn = P4[gid];
    size_t on = (size_t)gid * 3;
    const float cnx = corr_tgt[on], cny = corr_tgt[on + 1], cnz = corr_tgt[on + 2];
    __syncthreads();

    int pi = 0, pj = 1;
    {
        int pp = lane;
        #pragma unroll
        for (int r = 0; r < 9; ++r) {
            int cnt = 9 - r;
            if (pp >= 0 && pp < cnt) { pi = r; pj = r + 1 + pp; }
            pp -= cnt;
        }
    }

    float ls_p = 0.f, rg_p = 0.f;
    if (lane < NPAIR) {
        float e1x = PT[wid][pi][0] - pn.x, e1y = PT[wid][pi][1] - pn.y, e1z = PT[wid][pi][2] - pn.z;
        float e2x = PT[wid][pj][0] - pn.x, e2y = PT[wid][pj][1] - pn.y, e2z = PT[wid][pj][2] - pn.z;
        float cx = e1y * e2z - e1z * e2y;
        float cy = e1z * e2x - e1x * e2z;
        float cz = e1x * e2y - e1y * e2x;
        float as_ = 0.5f * sqrtf(cx * cx + cy * cy + cz * cz);
        float f1x = PT[wid][pi][3] - cnx, f1y = PT[wid][pi][4] - cny, f1z = PT[wid][pi][5] - cnz;
        float f2x = PT[wid][pj][3] - cnx, f2y = PT[wid][pj][4] - cny, f2z = PT[wid][pj][5] - cnz;
        float gx = f1y * f2z - f1z * f2y;
        float gy = f1z * f2x - f1x * f2z;
        float gz = f1x * f2y - f1y * f2x;
        float at_ = 0.5f * sqrtf(gx * gx + gy * gy + gz * gz);
        float tl2 = at_ + 1e-6f;
        float dd  = as_ - tl2;
        float e2_ = 1e-6f * 1e-6f;
        float num = (e2_ + e2_) + dd * dd;
        float den = (1e-6f + 1e-6f) + (as_ + tl2);
        ls_p = num / den;
        rg_p = sqrtf(num);
        LS[wid][lane] = ls_p;
    }
    __syncthreads();

    int rk = 0;
    if (lane < NPAIR) {
        #pragma unroll
        for (int q = 0; q < NPAIR; ++q) {
            float lq = LS[wid][q];
            rk += (lq < ls_p) || (lq == ls_p && q < lane);
        }
        SR[wid][rk] = ls_p;
    }
    __syncthreads();

    float tot_p = 0.f;
    if (lane < NPAIR) {
        tot_p = SR[wid][lane] + 0.1f * rg_p;
        TOT[wid][lane] = tot_p;
    }
    __syncthreads();

    int rt2 = 0;
    if (lane < NPAIR) {
        #pragma unroll
        for (int q = 0; q < NPAIR; ++q) {
            float tq = TOT[wid][q];
            rt2 += (tq < tot_p) || (tq == tot_p && q < lane);
        }
        SR[wid][rt2] = tot_p;
    }
    __syncthreads();

    float med = SR[wid][22];
    float thr = 3.0f * med;
    if (lane < KNN) {
        float v = tot_p;
        v = (v > thr) ? 0.0f : v;
        LS[wid][lane] = sqrtf(v + 1e-6f);
    }
    __syncthreads();
    if (lane == 0) {
        float acc = 0.f;
        #pragma unroll
        for (int k = 0; k < KNN; ++k) acc += LS[wid][k];
        mean_loss[gid] = acc / 10.0f;
    }
}

// ===========================================================================
// Kernel C: per-batch min + binary weight
// ===========================================================================
__global__ __launch_bounds__(256)
void weight_kernel(const float* __restrict__ mean_loss, float* __restrict__ weight_out)
{
    const int b = blockIdx.x;
    const int t = threadIdx.x;
    __shared__ float red[256];
    float mn = 3.402823466e38f;
    for (int i = t; i < NPTS; i += 256)
        mn = fminf(mn, mean_loss[(size_t)b * NPTS + i]);
    red[t] = mn; __syncthreads();
    for (int s2 = 128; s2 > 0; s2 >>= 1) {
        if (t < s2) red[t] = fminf(red[t], red[t + s2]);
        __syncthreads();
    }
    float ml = red[0];
    for (int i = t; i < NPTS; i += 256) {
        float d = mean_loss[(size_t)b * NPTS + i] - ml;
        float e = expf(-20.0f * d);
        float wts = 2.0f * (e / (1.0f + e));
        weight_out[(size_t)b * NPTS + i] = (wts > 0.5f) ? 1.0f : 0.0f;
    }
}

// ===========================================================================
// Kernel D: weighted Procrustes per batch (Horn quaternion)
// ===========================================================================
__device__ void jacobi4(double A[4][4], double V[4][4]) {
    for (int i = 0; i < 4; ++i)
        for (int j = 0; j < 4; ++j) V[i][j] = (i == j) ? 1.0 : 0.0;
    for (int sweep = 0; sweep < 12; ++sweep) {
        for (int p = 0; p < 3; ++p) for (int q = p + 1; q < 4; ++q) {
            double apq = A[p][q];
            if (fabs(apq) < 1e-30) continue;
            double theta = (A[q][q] - A[p][p]) / (2.0 * apq);
            double tt = (theta >= 0 ? 1.0 : -1.0) / (fabs(theta) + sqrt(theta * theta + 1.0));
            double c = 1.0 / sqrt(tt * tt + 1.0), s = tt * c;
            for (int k = 0; k < 4; ++k) {
                double akp = A[k][p], akq = A[k][q];
                A[k][p] = c * akp - s * akq;
                A[k][q] = s * akp + c * akq;
            }
            for (int k = 0; k < 4; ++k) {
                double apk = A[p][k], aqk = A[q][k];
                A[p][k] = c * apk - s * aqk;
                A[q][k] = s * apk + c * aqk;
            }
            for (int k = 0; k < 4; ++k) {
                double vkp = V[k][p], vkq = V[k][q];
                V[k][p] = c * vkp - s * vkq;
                V[k][q] = s * vkp + c * vkq;
            }
        }
    }
}

__global__ __launch_bounds__(256)
void procrustes_kernel(const float* __restrict__ src, const float* __restrict__ tgt,
                       const int* __restrict__ corres_i, const float* __restrict__ weight,
                       float* __restrict__ outR, float* __restrict__ outT)
{
    const int b = blockIdx.x;
    const int t = threadIdx.x;
    __shared__ float red[256][9];
    __shared__ float s_tw, s_mx[3], s_my[3];
    __shared__ float s_cov[9];

    float a0 = 0, a1 = 0, a2 = 0, a3 = 0, a4 = 0, a5 = 0, a6 = 0;
    for (int i = t; i < NPTS; i += 256) {
        float w = weight[(size_t)b * NPTS + i];
        float X0 = src[((size_t)b * 3 + 0) * NPTS + i];
        float X1 = src[((size_t)b * 3 + 1) * NPTS + i];
        float X2 = src[((size_t)b * 3 + 2) * NPTS + i];
        int c = corres_i[(size_t)b * NPTS + i];
        float Y0 = tgt[((size_t)b * 3 + 0) * NPTS + c];
        float Y1 = tgt[((size_t)b * 3 + 1) * NPTS + c];
        float Y2 = tgt[((size_t)b * 3 + 2) * NPTS + c];
        a0 += w;
        a1 += w * X0; a2 += w * X1; a3 += w * X2;
        a4 += w * Y0; a5 += w * Y1; a6 += w * Y2;
    }
    red[t][0] = a0; red[t][1] = a1; red[t][2] = a2; red[t][3] = a3;
    red[t][4] = a4; red[t][5] = a5; red[t][6] = a6; red[t][7] = 0; red[t][8] = 0;
    __syncthreads();
    for (int s2 = 128; s2 > 0; s2 >>= 1) {
        if (t < s2)
            for (int k = 0; k < 7; ++k) red[t][k] += red[t + s2][k];
        __syncthreads();
    }
    if (t == 0) {
        float tw = red[0][0];
        float itw = tw + 1e-7f;
        s_tw = tw;
        s_mx[0] = red[0][1] / itw; s_mx[1] = red[0][2] / itw; s_mx[2] = red[0][3] / itw;
        s_my[0] = red[0][4] / itw; s_my[1] = red[0][5] / itw; s_my[2] = red[0][6] / itw;
    }
    __syncthreads();
    const float twp = s_tw + 1e-7f;
    const float mx0 = s_mx[0], mx1 = s_mx[1], mx2 = s_mx[2];
    const float my0 = s_my[0], my1 = s_my[1], my2 = s_my[2];

    float cv[9] = {0,0,0,0,0,0,0,0,0};
    for (int i = t; i < NPTS; i += 256) {
        float w = weight[(size_t)b * NPTS + i];
        float nwn = w / twp;
        float X0 = src[((size_t)b * 3 + 0) * NPTS + i] - mx0;
        float X1 = src[((size_t)b * 3 + 1) * NPTS + i] - mx1;
        float X2 = src[((size_t)b * 3 + 2) * NPTS + i] - mx2;
        int c = corres_i[(size_t)b * NPTS + i];
        float Y0 = tgt[((size_t)b * 3 + 0) * NPTS + c] - my0;
        float Y1 = tgt[((size_t)b * 3 + 1) * NPTS + c] - my1;
        float Y2 = tgt[((size_t)b * 3 + 2) * NPTS + c] - my2;
        float b0 = nwn * X0, b1 = nwn * X1, b2 = nwn * X2;
        cv[0] += Y0 * b0; cv[1] += Y0 * b1; cv[2] += Y0 * b2;
        cv[3] += Y1 * b0; cv[4] += Y1 * b1; cv[5] += Y1 * b2;
        cv[6] += Y2 * b0; cv[7] += Y2 * b1; cv[8] += Y2 * b2;
    }
    __syncthreads();
    for (int k = 0; k < 9; ++k) red[t][k] = cv[k];
    __syncthreads();
    for (int s2 = 128; s2 > 0; s2 >>= 1) {
        if (t < s2)
            for (int k = 0; k < 9; ++k) red[t][k] += red[t + s2][k];
        __syncthreads();
    }
    if (t == 0) for (int k = 0; k < 9; ++k) s_cov[k] = red[0][k];
    __syncthreads();

    if (t == 0) {
        double cov[3][3];
        for (int i = 0; i < 3; ++i)
            for (int j = 0; j < 3; ++j) cov[i][j] = (double)s_cov[i * 3 + j];
        double S[3][3];
        for (int a = 0; a < 3; ++a)
            for (int bb = 0; bb < 3; ++bb) S[a][bb] = cov[bb][a];
        double N4[4][4];
        N4[0][0] = S[0][0] + S[1][1] + S[2][2];
        N4[0][1] = S[1][2] - S[2][1];
        N4[0][2] = S[2][0] - S[0][2];
        N4[0][3] = S[0][1] - S[1][0];
        N4[1][1] = S[0][0] - S[1][1] - S[2][2];
        N4[1][2] = S[0][1] + S[1][0];
        N4[1][3] = S[2][0] + S[0][2];
        N4[2][2] = -S[0][0] + S[1][1] - S[2][2];
        N4[2][3] = S[1][2] + S[2][1];
        N4[3][3] = -S[0][0] - S[1][1] + S[2][2];
        N4[1][0] = N4[0][1]; N4[2][0] = N4[0][2]; N4[3][0] = N4[0][3];
        N4[2][1] = N4[1][2]; N4[3][1] = N4[1][3]; N4[3][2] = N4[2][3];
        double V[4][4];
        jacobi4(N4, V);
        int best = 0; double bl = N4[0][0];
        for (int k = 1; k < 4; ++k) if (N4[k][k] > bl) { bl = N4[k][k]; best = k; }
        double q0 = V[0][best], qx = V[1][best], qy = V[2][best], qz = V[3][best];
        double nq = sqrt(q0 * q0 + qx * qx + qy * qy + qz * qz);
        q0 /= nq; qx /= nq; qy /= nq; qz /= nq;
        double Rm[3][3];
        Rm[0][0] = q0*q0 + qx*qx - qy*qy - qz*qz;
        Rm[0][1] = 2.0 * (qx*qy - q0*qz);
        Rm[0][2] = 2.0 * (qx*qz + q0*qy);
        Rm[1][0] = 2.0 * (qx*qy + q0*qz);
        Rm[1][1] = q0*q0 - qx*qx + qy*qy - qz*qz;
        Rm[1][2] = 2.0 * (qy*qz - q0*qx);
        Rm[2][0] = 2.0 * (qx*qz - q0*qy);
        Rm[2][1] = 2.0 * (qy*qz + q0*qx);
        Rm[2][2] = q0*q0 - qx*qx - qy*qy + qz*qz;
        double o1 = 0, o2 = 0;
        for (int i = 0; i < 3; ++i)
            for (int j = 0; j < 3; ++j) { o1 += Rm[i][j] * cov[i][j]; o2 += Rm[j][i] * cov[i][j]; }
        if (o2 > o1) {
            for (int i = 0; i < 3; ++i)
                for (int j = i + 1; j < 3; ++j) {
                    double tv = Rm[i][j]; Rm[i][j] = Rm[j][i]; Rm[j][i] = tv;
                }
        }
        float Rf[3][3];
        for (int i = 0; i < 3; ++i)
            for (int j = 0; j < 3; ++j) {
                Rf[i][j] = (float)Rm[i][j];
                outR[(size_t)b * 9 + i * 3 + j] = Rf[i][j];
            }
        float rm[3];
        float mxv[3] = {mx0, mx1, mx2};
        float myv[3] = {my0, my1, my2};
        for (int i = 0; i < 3; ++i)
            rm[i] = Rf[i][0] * mxv[0] + Rf[i][1] * mxv[1] + Rf[i][2] * mxv[2];
        for (int i = 0; i < 3; ++i)
            for (int j = 0; j < 3; ++j)
                outT[(size_t)b * 9 + i * 3 + j] = myv[j] - rm[i];
    }
}

// ===========================================================================
extern "C" void kernel_launch(void* const* d_in, const int* in_sizes, int n_in,
                              void* d_out, int out_size, void* d_ws, size_t ws_size,
                              hipStream_t stream)
{
    const float* se  = (const float*)d_in[0];
    const float* te  = (const float*)d_in[1];
    const float* src = (const float*)d_in[2];
    const float* tgt = (const float*)d_in[3];

    float* out  = (float*)d_out;
    float* outR = out;
    float* outT = out + 72;
    float* outC = out + 144;
    float* outW = out + 144 + BATCH * NPTS;

    char* wsb = (char*)d_ws;
    float* corr_tgt  = (float*)wsb;                                    // 196608 B
    int*   corres_i  = (int*)(wsb + 196608);                           // 65536 B
    float* mean_loss = (float*)(wsb + 262144);                         // 65536 B
    float* part      = (float*)(wsb + 327680);                         // 4 MB

    float4* P4    = (float4*)(wsb + 327680);                           // 262144 B
    // candK (40 MB) + topI live in the plane region, which is dead by the
    // time knn_scan runs (planes consumed by resolve / merge8).
    unsigned long long* candK = (unsigned long long*)(wsb + 589824);   // 41943040 B
    int*    topI  = (int*)(wsb + 589824 + 41943040);                   // 655360 B

    const size_t PLANES_OFF = 4521984;
    const size_t PL_BYTES   = (size_t)3 * BATCH * NPTS * DIM * 2;      // 50331648
    const size_t NEED       = PLANES_OFF + 2 * PL_BYTES;               // 105185280
    const size_t UHAT_BYTES = (size_t)BATCH * NPTS * NPTS * 2;         // 67108864
    const size_t NEED2      = NEED + UHAT_BYTES;                       // 172294144

    unsigned short* pA = (unsigned short*)(wsb + PLANES_OFF);
    unsigned short* pB = (unsigned short*)(wsb + PLANES_OFF + PL_BYTES);
    unsigned short* uhat = (unsigned short*)(wsb + NEED);

    hipLaunchKernelGGL(split_kernel, dim3(4096), dim3(256), 0, stream, se, te, pA, pB);
    if (ws_size >= NEED2) {
        hipLaunchKernelGGL(score_h, dim3(512), dim3(256), 0, stream, pA, pB, uhat);
        hipLaunchKernelGGL(resolve, dim3(BATCH * NPTS / 4), dim3(256), 0, stream,
                           uhat, pA, pB, tgt, corr_tgt, corres_i, outC);
    } else {
        hipLaunchKernelGGL(score_mfma, dim3(512), dim3(256), 0, stream, pA, pB, tgt, part);
        hipLaunchKernelGGL(merge8_kernel, dim3(BATCH * NPTS / 256), dim3(256), 0, stream,
                           part, corr_tgt, corres_i, outC);
    }
    hipLaunchKernelGGL(prep_p4, dim3(BATCH * NPTS / 256), dim3(256), 0, stream, src, P4);
    hipLaunchKernelGGL(knn_scan, dim3(BATCH * 256), dim3(256), 0, stream, P4, candK);
    hipLaunchKernelGGL(merge10_kernel, dim3(BATCH * NPTS / 256), dim3(256), 0, stream,
                       candK, topI);
    hipLaunchKernelGGL(gfm_finish, dim3(BATCH * NPTS / 4), dim3(256), 0, stream,
                       P4, corr_tgt, topI, mean_loss);
    hipLaunchKernelGGL(weight_kernel, dim3(BATCH), dim3(256), 0, stream,
                       mean_loss, outW);
    hipLaunchKernelGGL(procrustes_kernel, dim3(BATCH), dim3(256), 0, stream,
                       src, tgt, corres_i, outW, outR, outT);
}

// Round 13
// 299.437 us; speedup vs baseline: 1.1654x; 1.1654x over previous
//
#include <hip/hip_runtime.h>
#include <math.h>

#define BATCH 8
#define DIM   512
#define NPTS  2048
#define KNN   10
#define NPAIR 45
#define FCHK   16
#define FCHKSZ 128

typedef __attribute__((ext_vector_type(8))) short    bf16x8;
typedef __attribute__((ext_vector_type(4))) float    f32x4;
typedef __attribute__((ext_vector_type(4))) unsigned int u32x4;

__device__ inline unsigned short bf16_rne(float x) {
    unsigned int u = __float_as_uint(x);
    u += 0x7FFFu + ((u >> 16) & 1u);
    return (unsigned short)(u >> 16);
}
__device__ inline float bf16_to_f(unsigned short h) {
    return __uint_as_float(((unsigned int)h) << 16);
}

// ===========================================================================
// Kernel S: split se/te into 3 bf16 planes (h,m,l), transposed to [b][n][d].
// ===========================================================================
__global__ __launch_bounds__(256)
void split_kernel(const float* __restrict__ se, const float* __restrict__ te,
                  unsigned short* __restrict__ pA, unsigned short* __restrict__ pB)
{
    const int bid = blockIdx.x;
    const int tensor = bid >> 11;
    const int rr_ = bid & 2047;
    const int b  = rr_ >> 8;
    const int dt = (rr_ >> 5) & 7;
    const int nt = rr_ & 31;
    const float* srcp = (tensor == 0 ? se : te)
                        + ((size_t)b * DIM + dt * 64) * NPTS + nt * 64;
    unsigned short* dst = (tensor == 0 ? pA : pB);
    const size_t PL = (size_t)BATCH * NPTS * DIM;
    unsigned short* base = dst + (size_t)b * NPTS * DIM + (size_t)nt * 64 * DIM + dt * 64;

    __shared__ float T[64][65];
    const int t = threadIdx.x;
    {
        int r = t >> 4, c4 = t & 15;
        #pragma unroll
        for (int it = 0; it < 4; ++it) {
            int d = r + it * 16;
            float4 v = *(const float4*)&srcp[(size_t)d * NPTS + c4 * 4];
            T[d][c4 * 4 + 0] = v.x; T[d][c4 * 4 + 1] = v.y;
            T[d][c4 * 4 + 2] = v.z; T[d][c4 * 4 + 3] = v.w;
        }
    }
    __syncthreads();
    const int n  = t >> 2;
    const int d0 = (t & 3) * 16;
    unsigned short hh[16], mm[16], ll[16];
    #pragma unroll
    for (int j = 0; j < 16; ++j) {
        float a = T[d0 + j][n];
        unsigned short h = bf16_rne(a);
        float r1 = a - bf16_to_f(h);
        unsigned short m = bf16_rne(r1);
        float r2 = r1 - bf16_to_f(m);
        unsigned short l = bf16_rne(r2);
        hh[j] = h; mm[j] = m; ll[j] = l;
    }
    unsigned short* o = base + (size_t)n * DIM + d0;
    *(u32x4*)(o)            = *(u32x4*)&hh[0];
    *(u32x4*)(o + 8)        = *(u32x4*)&hh[8];
    *(u32x4*)(o + PL)       = *(u32x4*)&mm[0];
    *(u32x4*)(o + PL + 8)   = *(u32x4*)&mm[8];
    *(u32x4*)(o + 2*PL)     = *(u32x4*)&ll[0];
    *(u32x4*)(o + 2*PL + 8) = *(u32x4*)&ll[8];
}

// ===========================================================================
// Kernel H: phase-1 GEMM on h-planes only (K=512). Writes uhat (bf16 of
// 10000*dot_h/sqrt(512)) for ALL 2048x2048 per batch.
// ===========================================================================
__global__ __launch_bounds__(256, 2)
void score_h(const unsigned short* __restrict__ pA, const unsigned short* __restrict__ pB,
             unsigned short* __restrict__ uhat)
{
    const int bid  = blockIdx.x;
    const int xcd  = bid & 7;
    const int slot = bid >> 3;
    const int g    = xcd + 8 * (slot >> 4);
    const int ntile = slot & 15;
    const int b    = g >> 2;
    const int mc   = g & 3;
    const int n0 = ntile * 128;
    const int t  = threadIdx.x;
    const int w  = t >> 6;
    const int l  = t & 63;
    const int wn = w >> 1, wm = w & 1;
    const int l15 = l & 15, l4 = l >> 4;

    __shared__ unsigned short As[128 * 64];
    __shared__ unsigned short Bs[128 * 64];

    int srow[4], skg[4], ldsoff[4];
    #pragma unroll
    for (int qq = 0; qq < 4; ++qq) {
        int s = qq * 256 + t;
        int row = s >> 3, slt = s & 7;
        srow[qq] = row;
        skg[qq] = slt ^ (row & 7);
        ldsoff[qq] = row * 64 + slt * 8;
    }
    int aroff[4], arxor[4], broff[4], brxor[4];
    #pragma unroll
    for (int i = 0; i < 4; ++i) {
        int ar = wn * 64 + i * 16 + l15;
        aroff[i] = ar * 64; arxor[i] = ar & 7;
        int br = wm * 64 + i * 16 + l15;
        broff[i] = br * 64; brxor[i] = br & 7;
    }

    const float scl = 10000.0f / sqrtf((float)DIM);
    const unsigned short* Ab = pA + (size_t)b * NPTS * DIM;
    const unsigned short* Bb = pB + (size_t)b * NPTS * DIM;

    for (int mt = 0; mt < 4; ++mt) {
        const int m0 = mc * 512 + mt * 128;
        f32x4 acc[4][4];
        #pragma unroll
        for (int i = 0; i < 4; ++i)
            #pragma unroll
            for (int j = 0; j < 4; ++j) acc[i][j] = (f32x4){0.f, 0.f, 0.f, 0.f};

        for (int k0 = 0; k0 < 512; k0 += 64) {
            __syncthreads();
            bf16x8 ra[4], rb[4];
            #pragma unroll
            for (int qq = 0; qq < 4; ++qq) {
                ra[qq] = *(const bf16x8*)&Ab[(size_t)(n0 + srow[qq]) * DIM + k0 + skg[qq] * 8];
                rb[qq] = *(const bf16x8*)&Bb[(size_t)(m0 + srow[qq]) * DIM + k0 + skg[qq] * 8];
            }
            #pragma unroll
            for (int qq = 0; qq < 4; ++qq) {
                *(bf16x8*)&As[ldsoff[qq]] = ra[qq];
                *(bf16x8*)&Bs[ldsoff[qq]] = rb[qq];
            }
            __syncthreads();
            #pragma unroll
            for (int ks = 0; ks < 2; ++ks) {
                bf16x8 af[4], bfr[4];
                #pragma unroll
                for (int i = 0; i < 4; ++i) {
                    af[i]  = *(const bf16x8*)&As[aroff[i] + (((ks * 4 + l4) ^ arxor[i]) * 8)];
                    bfr[i] = *(const bf16x8*)&Bs[broff[i] + (((ks * 4 + l4) ^ brxor[i]) * 8)];
                }
                #pragma unroll
                for (int i = 0; i < 4; ++i)
                    #pragma unroll
                    for (int j = 0; j < 4; ++j)
                        acc[i][j] = __builtin_amdgcn_mfma_f32_16x16x32_bf16(af[i], bfr[j], acc[i][j], 0, 0, 0);
            }
        }
        #pragma unroll
        for (int i = 0; i < 4; ++i) {
            #pragma unroll
            for (int j = 0; j < 4; ++j) {
                int mcol = m0 + wm * 64 + j * 16 + l15;
                #pragma unroll
                for (int r = 0; r < 4; ++r) {
                    int nabs = n0 + wn * 64 + i * 16 + l4 * 4 + r;
                    uhat[((size_t)(b * NPTS + nabs)) * NPTS + mcol] =
                        bf16_rne(scl * acc[i][j][r]);
                }
            }
        }
    }
}

// ===========================================================================
// Kernel R: resolve. One wave per row. Fast path register-only; slow path
// wave-parallel exact 26-bit rescore.
// ===========================================================================
__global__ __launch_bounds__(256)
void resolve(const unsigned short* __restrict__ uhat,
             const unsigned short* __restrict__ pA, const unsigned short* __restrict__ pB,
             const float* __restrict__ tgt,
             float* __restrict__ corr_tgt, int* __restrict__ corres_i,
             float* __restrict__ corres_out)
{
    const int wid  = threadIdx.x >> 6;
    const int lane = threadIdx.x & 63;
    const int gid  = blockIdx.x * 4 + wid;
    const int b    = gid >> 11;
    const int n    = gid & 2047;

    __shared__ int s_m[4][64];
    __shared__ int s_cnt[4];

    if (lane == 0) s_cnt[wid] = 0;
    __syncthreads();

    const unsigned short* urow = uhat + (size_t)gid * NPTS;
    float v[32];
    float lmax = -3.402823466e38f; int lk = 0;
    #pragma unroll
    for (int g2 = 0; g2 < 4; ++g2) {
        u32x4 pk = *(const u32x4*)&urow[lane * 32 + g2 * 8];
        #pragma unroll
        for (int e = 0; e < 4; ++e) {
            unsigned int w2 = pk[e];
            float f0 = __uint_as_float((w2 & 0xFFFFu) << 16);
            float f1 = __uint_as_float(w2 & 0xFFFF0000u);
            int k0 = g2 * 8 + e * 2;
            v[k0] = f0; v[k0 + 1] = f1;
            if (f0 > lmax) { lmax = f0; lk = k0; }
            if (f1 > lmax) { lmax = f1; lk = k0 + 1; }
        }
    }
    float vmax = lmax; int argm = lane * 32 + lk;
    #pragma unroll
    for (int mask = 1; mask < 64; mask <<= 1) {
        float ov = __shfl_xor(vmax, mask);
        int   oi = __shfl_xor(argm, mask);
        if (ov > vmax || (ov == vmax && oi < argm)) { vmax = ov; argm = oi; }
    }
    const float cut = vmax - 1200.0f;
    int cnt = 0;
    #pragma unroll
    for (int k = 0; k < 32; ++k) cnt += (v[k] >= cut) ? 1 : 0;
    int nc = cnt;
    #pragma unroll
    for (int mask = 1; mask < 64; mask <<= 1) nc += __shfl_xor(nc, mask);

    if (nc > 1) {
        #pragma unroll
        for (int k = 0; k < 32; ++k) {
            if (v[k] >= cut) {
                int slot = atomicAdd(&s_cnt[wid], 1);
                if (slot < 64) s_m[wid][slot] = lane * 32 + k;
            }
        }
    }
    __syncthreads();
    if (nc > 1 && lane == 0) {
        int ncc = nc > 64 ? 64 : nc;
        for (int i = 1; i < ncc; ++i) {
            int key = s_m[wid][i]; int j = i - 1;
            while (j >= 0 && s_m[wid][j] > key) { s_m[wid][j + 1] = s_m[wid][j]; --j; }
            s_m[wid][j + 1] = key;
        }
    }
    __syncthreads();

    if (nc == 1) {
        if (lane < 3) corr_tgt[(size_t)gid * 3 + lane] = tgt[((size_t)b * 3 + lane) * NPTS + argm];
        if (lane == 0) { corres_i[gid] = argm; corres_out[gid] = (float)argm; }
        return;
    }
    const int ncc = nc > 64 ? 64 : nc;

    const size_t PL = (size_t)BATCH * NPTS * DIM;
    const unsigned short* Ar = pA + ((size_t)b * NPTS + n) * DIM + lane * 8;
    bf16x8 a_h = *(const bf16x8*)&Ar[0];
    bf16x8 a_m = *(const bf16x8*)&Ar[PL];
    bf16x8 a_l = *(const bf16x8*)&Ar[2 * PL];
    float ah[8], am[8], al[8];
    #pragma unroll
    for (int e = 0; e < 8; ++e) {
        ah[e] = bf16_to_f((unsigned short)a_h[e]);
        am[e] = bf16_to_f((unsigned short)a_m[e]);
        al[e] = bf16_to_f((unsigned short)a_l[e]);
    }

    const float sqd = sqrtf((float)DIM);
    float umax = -3.402823466e38f; int uarg = 0x7fffffff;
    float myu = 0.f;
    for (int c = 0; c < ncc; ++c) {
        int mB = s_m[wid][c];
        const unsigned short* Br = pB + ((size_t)b * NPTS + mB) * DIM + lane * 8;
        bf16x8 b_h = *(const bf16x8*)&Br[0];
        bf16x8 b_m = *(const bf16x8*)&Br[PL];
        bf16x8 b_l = *(const bf16x8*)&Br[2 * PL];
        float part = 0.f;
        #pragma unroll
        for (int e = 0; e < 8; ++e) {
            float bh = bf16_to_f((unsigned short)b_h[e]);
            float bm = bf16_to_f((unsigned short)b_m[e]);
            float bl = bf16_to_f((unsigned short)b_l[e]);
            part += ah[e] * bh;
            part += ah[e] * bm;
            part += am[e] * bh;
            part += ah[e] * bl;
            part += am[e] * bm;
            part += al[e] * bh;
        }
        #pragma unroll
        for (int mask = 1; mask < 64; mask <<= 1) part += __shfl_xor(part, mask);
        float u = 10000.0f * (part / sqd);
        if (u > umax) { umax = u; uarg = mB; }
        if (lane == c) myu = u;
    }

    float p = (lane < ncc) ? expf(myu - umax) : 0.f;
    int myM = (lane < ncc) ? s_m[wid][lane] : 0;
    float tx = 0.f, ty = 0.f, tz = 0.f, ps = p;
    if (lane < ncc) {
        tx = p * tgt[((size_t)b * 3 + 0) * NPTS + myM];
        ty = p * tgt[((size_t)b * 3 + 1) * NPTS + myM];
        tz = p * tgt[((size_t)b * 3 + 2) * NPTS + myM];
    }
    #pragma unroll
    for (int mask = 1; mask < 64; mask <<= 1) {
        ps += __shfl_xor(ps, mask);
        tx += __shfl_xor(tx, mask);
        ty += __shfl_xor(ty, mask);
        tz += __shfl_xor(tz, mask);
    }
    if (lane == 0) {
        corr_tgt[(size_t)gid * 3 + 0] = tx / ps;
        corr_tgt[(size_t)gid * 3 + 1] = ty / ps;
        corr_tgt[(size_t)gid * 3 + 2] = tz / ps;
        corres_i[gid]   = uarg;
        corres_out[gid] = (float)uarg;
    }
}

// ===========================================================================
// FALLBACK Kernel A (round-8 proven): 6-product MFMA + fused online softmax
// ===========================================================================
__global__ __launch_bounds__(256, 2)
void score_mfma(const unsigned short* __restrict__ pA, const unsigned short* __restrict__ pB,
                const float* __restrict__ tgt, float* __restrict__ part)
{
    const int bid  = blockIdx.x;
    const int xcd  = bid & 7;
    const int slot = bid >> 3;
    const int g    = xcd + 8 * (slot >> 4);
    const int ntile = slot & 15;
    const int b    = g >> 2;
    const int mc   = g & 3;
    const int n0 = ntile * 128;
    const int t  = threadIdx.x;
    const int w  = t >> 6;
    const int l  = t & 63;
    const int wn = w >> 1, wm = w & 1;
    const int l15 = l & 15, l4 = l >> 4;

    __shared__ unsigned short As[128 * 64];
    __shared__ unsigned short Bs[128 * 64];

    const size_t PL = (size_t)BATCH * NPTS * DIM;

    int srow[4], skg[4], ldsoff[4];
    #pragma unroll
    for (int qq = 0; qq < 4; ++qq) {
        int s = qq * 256 + t;
        int row = s >> 3, slt = s & 7;
        srow[qq] = row;
        skg[qq] = slt ^ (row & 7);
        ldsoff[qq] = row * 64 + slt * 8;
    }
    int aroff[4], arxor[4], broff[4], brxor[4];
    #pragma unroll
    for (int i = 0; i < 4; ++i) {
        int ar = wn * 64 + i * 16 + l15;
        aroff[i] = ar * 64; arxor[i] = ar & 7;
        int br = wm * 64 + i * 16 + l15;
        broff[i] = br * 64; brxor[i] = br & 7;
    }

    float mx[16], sm[16], ax[16], ay[16], az[16]; int ag[16];
    #pragma unroll
    for (int si = 0; si < 16; ++si) {
        mx[si] = -3.402823466e38f; sm[si] = 0.f;
        ax[si] = 0.f; ay[si] = 0.f; az[si] = 0.f; ag[si] = 0;
    }

    const float sqd = sqrtf((float)DIM);
    const unsigned short* Ab = pA + (size_t)b * NPTS * DIM;
    const unsigned short* Bb = pB + (size_t)b * NPTS * DIM;
    const int AIDX[6] = {0, 0, 1, 0, 1, 2};
    const int BIDX[6] = {0, 1, 0, 2, 1, 0};

    for (int mt = 0; mt < 4; ++mt) {
        const int m0 = mc * 512 + mt * 128;
        f32x4 acc[4][4];
        #pragma unroll
        for (int i = 0; i < 4; ++i)
            #pragma unroll
            for (int j = 0; j < 4; ++j) acc[i][j] = (f32x4){0.f, 0.f, 0.f, 0.f};

        for (int q = 0; q < 6; ++q) {
            const unsigned short* Ap = Ab + (size_t)AIDX[q] * PL;
            const unsigned short* Bp = Bb + (size_t)BIDX[q] * PL;
            for (int k0 = 0; k0 < 512; k0 += 64) {
                __syncthreads();
                bf16x8 ra[4], rb[4];
                #pragma unroll
                for (int qq = 0; qq < 4; ++qq) {
                    ra[qq] = *(const bf16x8*)&Ap[(size_t)(n0 + srow[qq]) * DIM + k0 + skg[qq] * 8];
                    rb[qq] = *(const bf16x8*)&Bp[(size_t)(m0 + srow[qq]) * DIM + k0 + skg[qq] * 8];
                }
                #pragma unroll
                for (int qq = 0; qq < 4; ++qq) {
                    *(bf16x8*)&As[ldsoff[qq]] = ra[qq];
                    *(bf16x8*)&Bs[ldsoff[qq]] = rb[qq];
                }
                __syncthreads();
                #pragma unroll
                for (int ks = 0; ks < 2; ++ks) {
                    bf16x8 af[4], bfr[4];
                    #pragma unroll
                    for (int i = 0; i < 4; ++i) {
                        af[i]  = *(const bf16x8*)&As[aroff[i] + (((ks * 4 + l4) ^ arxor[i]) * 8)];
                        bfr[i] = *(const bf16x8*)&Bs[broff[i] + (((ks * 4 + l4) ^ brxor[i]) * 8)];
                    }
                    #pragma unroll
                    for (int i = 0; i < 4; ++i)
                        #pragma unroll
                        for (int j = 0; j < 4; ++j)
                            acc[i][j] = __builtin_amdgcn_mfma_f32_16x16x32_bf16(af[i], bfr[j], acc[i][j], 0, 0, 0);
                }
            }
        }
        float tg0[4], tg1[4], tg2[4];
        #pragma unroll
        for (int j = 0; j < 4; ++j) {
            int mcol = m0 + wm * 64 + j * 16 + l15;
            tg0[j] = tgt[((size_t)b * 3 + 0) * NPTS + mcol];
            tg1[j] = tgt[((size_t)b * 3 + 1) * NPTS + mcol];
            tg2[j] = tgt[((size_t)b * 3 + 2) * NPTS + mcol];
        }
        #pragma unroll
        for (int i = 0; i < 4; ++i) {
            #pragma unroll
            for (int r = 0; r < 4; ++r) {
                const int si = i * 4 + r;
                float u[4];
                float lm = -3.402823466e38f; int la = 0;
                #pragma unroll
                for (int j = 0; j < 4; ++j) {
                    float s  = acc[i][j][r] / sqd;
                    float uu = 10000.0f * s;
                    u[j] = uu;
                    if (uu > lm) { lm = uu; la = m0 + wm * 64 + j * 16 + l15; }
                }
                float nm = fmaxf(mx[si], lm);
                if (lm > mx[si]) ag[si] = la;
                float f = expf(mx[si] - nm);
                mx[si] = nm;
                float s_ = sm[si] * f, x_ = ax[si] * f, y_ = ay[si] * f, z_ = az[si] * f;
                #pragma unroll
                for (int j = 0; j < 4; ++j) {
                    float p = expf(u[j] - nm);
                    s_ += p; x_ += p * tg0[j]; y_ += p * tg1[j]; z_ += p * tg2[j];
                }
                sm[si] = s_; ax[si] = x_; ay[si] = y_; az[si] = z_;
            }
        }
    }

    #pragma unroll
    for (int si = 0; si < 16; ++si) {
        for (int mask = 1; mask < 16; mask <<= 1) {
            float omx = __shfl_xor(mx[si], mask);
            float osm = __shfl_xor(sm[si], mask);
            float oax = __shfl_xor(ax[si], mask);
            float oay = __shfl_xor(ay[si], mask);
            float oaz = __shfl_xor(az[si], mask);
            int   oag = __shfl_xor(ag[si], mask);
            float nm = fmaxf(mx[si], omx);
            float f1 = expf(mx[si] - nm), f2 = expf(omx - nm);
            sm[si] = sm[si] * f1 + osm * f2;
            ax[si] = ax[si] * f1 + oax * f2;
            ay[si] = ay[si] * f1 + oay * f2;
            az[si] = az[si] * f1 + oaz * f2;
            ag[si] = (omx > mx[si]) ? oag : ((omx == mx[si]) ? min(ag[si], oag) : ag[si]);
            mx[si] = nm;
        }
    }
    if (l15 == 0) {
        const int chunk = mc * 2 + wm;
        #pragma unroll
        for (int i = 0; i < 4; ++i)
            #pragma unroll
            for (int r = 0; r < 4; ++r) {
                const int si = i * 4 + r;
                int nabs = n0 + wn * 64 + i * 16 + l4 * 4 + r;
                size_t o = (((size_t)b * NPTS + nabs) * 8 + chunk) * 8;
                part[o + 0] = mx[si]; part[o + 1] = sm[si];
                part[o + 2] = ax[si]; part[o + 3] = ay[si]; part[o + 4] = az[si];
                part[o + 5] = __int_as_float(ag[si]);
            }
    }
}

__global__ __launch_bounds__(256)
void merge8_kernel(const float* __restrict__ part, float* __restrict__ corr_tgt,
                   int* __restrict__ corres_i, float* __restrict__ corres_out)
{
    int r = blockIdx.x * 256 + threadIdx.x;
    float m = -3.402823466e38f, s = 0.f, x = 0.f, y = 0.f, z = 0.f; int a = 0x7fffffff;
    for (int c = 0; c < 8; ++c) {
        const float* p = &part[((size_t)r * 8 + c) * 8];
        float pm = p[0]; int pa = __float_as_int(p[5]);
        float nm = fmaxf(m, pm);
        float f1 = expf(m - nm), f2 = expf(pm - nm);
        s = s * f1 + p[1] * f2;
        x = x * f1 + p[2] * f2;
        y = y * f1 + p[3] * f2;
        z = z * f1 + p[4] * f2;
        if (pm > m) a = pa; else if (pm == m) a = min(a, pa);
        m = nm;
    }
    corr_tgt[(size_t)r * 3 + 0] = x / s;
    corr_tgt[(size_t)r * 3 + 1] = y / s;
    corr_tgt[(size_t)r * 3 + 2] = z / s;
    corres_i[r]   = a;
    corres_out[r] = (float)a;
}

// ===========================================================================
// Kernel B0: P4 = (x,y,z,|p|^2) per source point
// ===========================================================================
__global__ __launch_bounds__(256)
void prep_p4(const float* __restrict__ src, float4* __restrict__ P4)
{
    int i = blockIdx.x * 256 + threadIdx.x;
    int b = i >> 11, m = i & 2047;
    float x = src[((size_t)b * 3 + 0) * NPTS + m];
    float y = src[((size_t)b * 3 + 1) * NPTS + m];
    float z = src[((size_t)b * 3 + 2) * NPTS + m];
    P4[i] = make_float4(x, y, z, x * x + y * y + z * z);
}

// ===========================================================================
// Kernel B1 (FUSED): per-(n,chunk) top-10 scan + in-LDS 160-candidate merge.
// 16 chunks x 128 pts; block = 256 thr = 16 rows x 16 chunks; grid 1024
// (4 blocks/CU, 50% occupancy). No global candidate round-trip.
// ===========================================================================
__global__ __launch_bounds__(256)
void knn_topk(const float4* __restrict__ P4, int* __restrict__ topI)
{
    const int bid = blockIdx.x;                    // 0..1023
    const int b = bid >> 7, nblk = bid & 127;      // 128 blocks/batch
    const int t = threadIdx.x;
    const int c  = t & (FCHK - 1);                 // chunk 0..15
    const int rl = t >> 4;                         // row-in-block 0..15
    const int n = nblk * 16 + rl;
    const float4* Pb = P4 + (size_t)b * NPTS;
    const float4 pn = Pb[n];

    __shared__ unsigned long long L[16][FCHK * KNN];   // 20 KB

    unsigned long long kl[KNN];
    #pragma unroll
    for (int k = 0; k < KNN; ++k) kl[k] = 0xFFFFFFFFFFFFFFFFull;

    const int m0 = c * FCHKSZ;
    for (int mm = 0; mm < FCHKSZ; ++mm) {
        int m = m0 + mm;
        float4 pm = Pb[m];
        float dot = pn.x * pm.x + pn.y * pm.y + pn.z * pm.z;
        float d2  = (pn.w + pm.w) - 2.0f * dot;
        if (d2 < 0.f) d2 = 0.f;
        float w = expf(-d2 * 0.5f);
        unsigned long long key =
            ((unsigned long long)(~__float_as_uint(w)) << 32) | (unsigned int)m;
        if (key < kl[KNN - 1]) {
            unsigned long long ck = key;
            #pragma unroll
            for (int k = 0; k < KNN; ++k) {
                if (ck < kl[k]) { unsigned long long tv = kl[k]; kl[k] = ck; ck = tv; }
            }
        }
    }
    #pragma unroll
    for (int k = 0; k < KNN; ++k) L[rl][c * KNN + k] = kl[k];
    __syncthreads();

    if (t < 16) {                                  // one thread per row
        const int row = t;
        unsigned long long K[KNN];
        #pragma unroll
        for (int k = 0; k < KNN; ++k) K[k] = 0xFFFFFFFFFFFFFFFFull;
        for (int e = 0; e < FCHK * KNN; ++e) {
            unsigned long long ck = L[row][e];
            if (ck < K[KNN - 1]) {
                #pragma unroll
                for (int k = 0; k < KNN; ++k) {
                    if (ck < K[k]) { unsigned long long tv = K[k]; K[k] = ck; ck = tv; }
                }
            }
        }
        size_t gid = (size_t)(b << 11) + nblk * 16 + row;
        #pragma unroll
        for (int k = 0; k < KNN; ++k)
            topI[gid * KNN + k] = (int)(K[k] & 0xFFFFFFFFull);
    }
}

// ===========================================================================
// Kernel B2: wave-per-n GFM finish (4096 blocks x 4 waves)
// ===========================================================================
__global__ __launch_bounds__(256)
void gfm_finish(const float4* __restrict__ P4, const float* __restrict__ corr_tgt,
                const int* __restrict__ topI, float* __restrict__ mean_loss)
{
    const int wid  = threadIdx.x >> 6;
    const int lane = threadIdx.x & 63;
    const int gid  = blockIdx.x * 4 + wid;
    const int b    = gid >> 11;

    __shared__ float PT[4][KNN][6];
    __shared__ float LS[4][48];
    __shared__ float SR[4][48];
    __shared__ float TOT[4][48];

    if (lane < KNN) {
        int idx = topI[(size_t)gid * KNN + lane];
        float4 pk = P4[(b << 11) + idx];
        size_t o = ((size_t)(b << 11) + idx) * 3;
        PT[wid][lane][0] = pk.x; PT[wid][lane][1] = pk.y; PT[wid][lane][2] = pk.z;
        PT[wid][lane][3] = corr_tgt[o];
        PT[wid][lane][4] = corr_tgt[o + 1];
        PT[wid][lane][5] = corr_tgt[o + 2];
    }
    float4 pn = P4[gid];
    size_t on = (size_t)gid * 3;
    const float cnx = corr_tgt[on], cny = corr_tgt[on + 1], cnz = corr_tgt[on + 2];
    __syncthreads();

    int pi = 0, pj = 1;
    {
        int pp = lane;
        #pragma unroll
        for (int r = 0; r < 9; ++r) {
            int cnt = 9 - r;
            if (pp >= 0 && pp < cnt) { pi = r; pj = r + 1 + pp; }
            pp -= cnt;
        }
    }

    float ls_p = 0.f, rg_p = 0.f;
    if (lane < NPAIR) {
        float e1x = PT[wid][pi][0] - pn.x, e1y = PT[wid][pi][1] - pn.y, e1z = PT[wid][pi][2] - pn.z;
        float e2x = PT[wid][pj][0] - pn.x, e2y = PT[wid][pj][1] - pn.y, e2z = PT[wid][pj][2] - pn.z;
        float cx = e1y * e2z - e1z * e2y;
        float cy = e1z * e2x - e1x * e2z;
        float cz = e1x * e2y - e1y * e2x;
        float as_ = 0.5f * sqrtf(cx * cx + cy * cy + cz * cz);
        float f1x = PT[wid][pi][3] - cnx, f1y = PT[wid][pi][4] - cny, f1z = PT[wid][pi][5] - cnz;
        float f2x = PT[wid][pj][3] - cnx, f2y = PT[wid][pj][4] - cny, f2z = PT[wid][pj][5] - cnz;
        float gx = f1y * f2z - f1z * f2y;
        float gy = f1z * f2x - f1x * f2z;
        float gz = f1x * f2y - f1y * f2x;
        float at_ = 0.5f * sqrtf(gx * gx + gy * gy + gz * gz);
        float tl2 = at_ + 1e-6f;
        float dd  = as_ - tl2;
        float e2_ = 1e-6f * 1e-6f;
        float num = (e2_ + e2_) + dd * dd;
        float den = (1e-6f + 1e-6f) + (as_ + tl2);
        ls_p = num / den;
        rg_p = sqrtf(num);
        LS[wid][lane] = ls_p;
    }
    __syncthreads();

    int rk = 0;
    if (lane < NPAIR) {
        #pragma unroll
        for (int q = 0; q < NPAIR; ++q) {
            float lq = LS[wid][q];
            rk += (lq < ls_p) || (lq == ls_p && q < lane);
        }
        SR[wid][rk] = ls_p;
    }
    __syncthreads();

    float tot_p = 0.f;
    if (lane < NPAIR) {
        tot_p = SR[wid][lane] + 0.1f * rg_p;
        TOT[wid][lane] = tot_p;
    }
    __syncthreads();

    int rt2 = 0;
    if (lane < NPAIR) {
        #pragma unroll
        for (int q = 0; q < NPAIR; ++q) {
            float tq = TOT[wid][q];
            rt2 += (tq < tot_p) || (tq == tot_p && q < lane);
        }
        SR[wid][rt2] = tot_p;
    }
    __syncthreads();

    float med = SR[wid][22];
    float thr = 3.0f * med;
    if (lane < KNN) {
        float v = tot_p;
        v = (v > thr) ? 0.0f : v;
        LS[wid][lane] = sqrtf(v + 1e-6f);
    }
    __syncthreads();
    if (lane == 0) {
        float acc = 0.f;
        #pragma unroll
        for (int k = 0; k < KNN; ++k) acc += LS[wid][k];
        mean_loss[gid] = acc / 10.0f;
    }
}

// ===========================================================================
// Kernel C: per-batch min + binary weight
// ===========================================================================
__global__ __launch_bounds__(256)
void weight_kernel(const float* __restrict__ mean_loss, float* __restrict__ weight_out)
{
    const int b = blockIdx.x;
    const int t = threadIdx.x;
    __shared__ float red[256];
    float mn = 3.402823466e38f;
    for (int i = t; i < NPTS; i += 256)
        mn = fminf(mn, mean_loss[(size_t)b * NPTS + i]);
    red[t] = mn; __syncthreads();
    for (int s2 = 128; s2 > 0; s2 >>= 1) {
        if (t < s2) red[t] = fminf(red[t], red[t + s2]);
        __syncthreads();
    }
    float ml = red[0];
    for (int i = t; i < NPTS; i += 256) {
        float d = mean_loss[(size_t)b * NPTS + i] - ml;
        float e = expf(-20.0f * d);
        float wts = 2.0f * (e / (1.0f + e));
        weight_out[(size_t)b * NPTS + i] = (wts > 0.5f) ? 1.0f : 0.0f;
    }
}

// ===========================================================================
// Kernel D: weighted Procrustes per batch (Horn quaternion)
// ===========================================================================
__device__ void jacobi4(double A[4][4], double V[4][4]) {
    for (int i = 0; i < 4; ++i)
        for (int j = 0; j < 4; ++j) V[i][j] = (i == j) ? 1.0 : 0.0;
    for (int sweep = 0; sweep < 12; ++sweep) {
        for (int p = 0; p < 3; ++p) for (int q = p + 1; q < 4; ++q) {
            double apq = A[p][q];
            if (fabs(apq) < 1e-30) continue;
            double theta = (A[q][q] - A[p][p]) / (2.0 * apq);
            double tt = (theta >= 0 ? 1.0 : -1.0) / (fabs(theta) + sqrt(theta * theta + 1.0));
            double c = 1.0 / sqrt(tt * tt + 1.0), s = tt * c;
            for (int k = 0; k < 4; ++k) {
                double akp = A[k][p], akq = A[k][q];
                A[k][p] = c * akp - s * akq;
                A[k][q] = s * akp + c * akq;
            }
            for (int k = 0; k < 4; ++k) {
                double apk = A[p][k], aqk = A[q][k];
                A[p][k] = c * apk - s * aqk;
                A[q][k] = s * apk + c * aqk;
            }
            for (int k = 0; k < 4; ++k) {
                double vkp = V[k][p], vkq = V[k][q];
                V[k][p] = c * vkp - s * vkq;
                V[k][q] = s * vkp + c * vkq;
            }
        }
    }
}

__global__ __launch_bounds__(256)
void procrustes_kernel(const float* __restrict__ src, const float* __restrict__ tgt,
                       const int* __restrict__ corres_i, const float* __restrict__ weight,
                       float* __restrict__ outR, float* __restrict__ outT)
{
    const int b = blockIdx.x;
    const int t = threadIdx.x;
    __shared__ float red[256][9];
    __shared__ float s_tw, s_mx[3], s_my[3];
    __shared__ float s_cov[9];

    float a0 = 0, a1 = 0, a2 = 0, a3 = 0, a4 = 0, a5 = 0, a6 = 0;
    for (int i = t; i < NPTS; i += 256) {
        float w = weight[(size_t)b * NPTS + i];
        float X0 = src[((size_t)b * 3 + 0) * NPTS + i];
        float X1 = src[((size_t)b * 3 + 1) * NPTS + i];
        float X2 = src[((size_t)b * 3 + 2) * NPTS + i];
        int c = corres_i[(size_t)b * NPTS + i];
        float Y0 = tgt[((size_t)b * 3 + 0) * NPTS + c];
        float Y1 = tgt[((size_t)b * 3 + 1) * NPTS + c];
        float Y2 = tgt[((size_t)b * 3 + 2) * NPTS + c];
        a0 += w;
        a1 += w * X0; a2 += w * X1; a3 += w * X2;
        a4 += w * Y0; a5 += w * Y1; a6 += w * Y2;
    }
    red[t][0] = a0; red[t][1] = a1; red[t][2] = a2; red[t][3] = a3;
    red[t][4] = a4; red[t][5] = a5; red[t][6] = a6; red[t][7] = 0; red[t][8] = 0;
    __syncthreads();
    for (int s2 = 128; s2 > 0; s2 >>= 1) {
        if (t < s2)
            for (int k = 0; k < 7; ++k) red[t][k] += red[t + s2][k];
        __syncthreads();
    }
    if (t == 0) {
        float tw = red[0][0];
        float itw = tw + 1e-7f;
        s_tw = tw;
        s_mx[0] = red[0][1] / itw; s_mx[1] = red[0][2] / itw; s_mx[2] = red[0][3] / itw;
        s_my[0] = red[0][4] / itw; s_my[1] = red[0][5] / itw; s_my[2] = red[0][6] / itw;
    }
    __syncthreads();
    const float twp = s_tw + 1e-7f;
    const float mx0 = s_mx[0], mx1 = s_mx[1], mx2 = s_mx[2];
    const float my0 = s_my[0], my1 = s_my[1], my2 = s_my[2];

    float cv[9] = {0,0,0,0,0,0,0,0,0};
    for (int i = t; i < NPTS; i += 256) {
        float w = weight[(size_t)b * NPTS + i];
        float nwn = w / twp;
        float X0 = src[((size_t)b * 3 + 0) * NPTS + i] - mx0;
        float X1 = src[((size_t)b * 3 + 1) * NPTS + i] - mx1;
        float X2 = src[((size_t)b * 3 + 2) * NPTS + i] - mx2;
        int c = corres_i[(size_t)b * NPTS + i];
        float Y0 = tgt[((size_t)b * 3 + 0) * NPTS + c] - my0;
        float Y1 = tgt[((size_t)b * 3 + 1) * NPTS + c] - my1;
        float Y2 = tgt[((size_t)b * 3 + 2) * NPTS + c] - my2;
        float b0 = nwn * X0, b1 = nwn * X1, b2 = nwn * X2;
        cv[0] += Y0 * b0; cv[1] += Y0 * b1; cv[2] += Y0 * b2;
        cv[3] += Y1 * b0; cv[4] += Y1 * b1; cv[5] += Y1 * b2;
        cv[6] += Y2 * b0; cv[7] += Y2 * b1; cv[8] += Y2 * b2;
    }
    __syncthreads();
    for (int k = 0; k < 9; ++k) red[t][k] = cv[k];
    __syncthreads();
    for (int s2 = 128; s2 > 0; s2 >>= 1) {
        if (t < s2)
            for (int k = 0; k < 9; ++k) red[t][k] += red[t + s2][k];
        __syncthreads();
    }
    if (t == 0) for (int k = 0; k < 9; ++k) s_cov[k] = red[0][k];
    __syncthreads();

    if (t == 0) {
        double cov[3][3];
        for (int i = 0; i < 3; ++i)
            for (int j = 0; j < 3; ++j) cov[i][j] = (double)s_cov[i * 3 + j];
        double S[3][3];
        for (int a = 0; a < 3; ++a)
            for (int bb = 0; bb < 3; ++bb) S[a][bb] = cov[bb][a];
        double N4[4][4];
        N4[0][0] = S[0][0] + S[1][1] + S[2][2];
        N4[0][1] = S[1][2] - S[2][1];
        N4[0][2] = S[2][0] - S[0][2];
        N4[0][3] = S[0][1] - S[1][0];
        N4[1][1] = S[0][0] - S[1][1] - S[2][2];
        N4[1][2] = S[0][1] + S[1][0];
        N4[1][3] = S[2][0] + S[0][2];
        N4[2][2] = -S[0][0] + S[1][1] - S[2][2];
        N4[2][3] = S[1][2] + S[2][1];
        N4[3][3] = -S[0][0] - S[1][1] + S[2][2];
        N4[1][0] = N4[0][1]; N4[2][0] = N4[0][2]; N4[3][0] = N4[0][3];
        N4[2][1] = N4[1][2]; N4[3][1] = N4[1][3]; N4[3][2] = N4[2][3];
        double V[4][4];
        jacobi4(N4, V);
        int best = 0; double bl = N4[0][0];
        for (int k = 1; k < 4; ++k) if (N4[k][k] > bl) { bl = N4[k][k]; best = k; }
        double q0 = V[0][best], qx = V[1][best], qy = V[2][best], qz = V[3][best];
        double nq = sqrt(q0 * q0 + qx * qx + qy * qy + qz * qz);
        q0 /= nq; qx /= nq; qy /= nq; qz /= nq;
        double Rm[3][3];
        Rm[0][0] = q0*q0 + qx*qx - qy*qy - qz*qz;
        Rm[0][1] = 2.0 * (qx*qy - q0*qz);
        Rm[0][2] = 2.0 * (qx*qz + q0*qy);
        Rm[1][0] = 2.0 * (qx*qy + q0*qz);
        Rm[1][1] = q0*q0 - qx*qx + qy*qy - qz*qz;
        Rm[1][2] = 2.0 * (qy*qz - q0*qx);
        Rm[2][0] = 2.0 * (qx*qz - q0*qy);
        Rm[2][1] = 2.0 * (qy*qz + q0*qx);
        Rm[2][2] = q0*q0 - qx*qx - qy*qy + qz*qz;
        double o1 = 0, o2 = 0;
        for (int i = 0; i < 3; ++i)
            for (int j = 0; j < 3; ++j) { o1 += Rm[i][j] * cov[i][j]; o2 += Rm[j][i] * cov[i][j]; }
        if (o2 > o1) {
            for (int i = 0; i < 3; ++i)
                for (int j = i + 1; j < 3; ++j) {
                    double tv = Rm[i][j]; Rm[i][j] = Rm[j][i]; Rm[j][i] = tv;
                }
        }
        float Rf[3][3];
        for (int i = 0; i < 3; ++i)
            for (int j = 0; j < 3; ++j) {
                Rf[i][j] = (float)Rm[i][j];
                outR[(size_t)b * 9 + i * 3 + j] = Rf[i][j];
            }
        float rm[3];
        float mxv[3] = {mx0, mx1, mx2};
        float myv[3] = {my0, my1, my2};
        for (int i = 0; i < 3; ++i)
            rm[i] = Rf[i][0] * mxv[0] + Rf[i][1] * mxv[1] + Rf[i][2] * mxv[2];
        for (int i = 0; i < 3; ++i)
            for (int j = 0; j < 3; ++j)
                outT[(size_t)b * 9 + i * 3 + j] = myv[j] - rm[i];
    }
}

// ===========================================================================
extern "C" void kernel_launch(void* const* d_in, const int* in_sizes, int n_in,
                              void* d_out, int out_size, void* d_ws, size_t ws_size,
                              hipStream_t stream)
{
    const float* se  = (const float*)d_in[0];
    const float* te  = (const float*)d_in[1];
    const float* src = (const float*)d_in[2];
    const float* tgt = (const float*)d_in[3];

    float* out  = (float*)d_out;
    float* outR = out;
    float* outT = out + 72;
    float* outC = out + 144;
    float* outW = out + 144 + BATCH * NPTS;

    char* wsb = (char*)d_ws;
    float* corr_tgt  = (float*)wsb;                                    // 196608 B
    int*   corres_i  = (int*)(wsb + 196608);                           // 65536 B
    float* mean_loss = (float*)(wsb + 262144);                         // 65536 B
    float* part      = (float*)(wsb + 327680);                         // 4 MB (fallback only)

    float4* P4   = (float4*)(wsb + 327680);                            // 262144 B
    int*    topI = (int*)(wsb + 589824);                               // 655360 B

    const size_t PLANES_OFF = 4521984;
    const size_t PL_BYTES   = (size_t)3 * BATCH * NPTS * DIM * 2;      // 50331648
    const size_t NEED       = PLANES_OFF + 2 * PL_BYTES;               // 105185280
    const size_t UHAT_BYTES = (size_t)BATCH * NPTS * NPTS * 2;         // 67108864
    const size_t NEED2      = NEED + UHAT_BYTES;                       // 172294144

    unsigned short* pA = (unsigned short*)(wsb + PLANES_OFF);
    unsigned short* pB = (unsigned short*)(wsb + PLANES_OFF + PL_BYTES);
    unsigned short* uhat = (unsigned short*)(wsb + NEED);

    hipLaunchKernelGGL(split_kernel, dim3(4096), dim3(256), 0, stream, se, te, pA, pB);
    if (ws_size >= NEED2) {
        hipLaunchKernelGGL(score_h, dim3(512), dim3(256), 0, stream, pA, pB, uhat);
        hipLaunchKernelGGL(resolve, dim3(BATCH * NPTS / 4), dim3(256), 0, stream,
                           uhat, pA, pB, tgt, corr_tgt, corres_i, outC);
    } else {
        hipLaunchKernelGGL(score_mfma, dim3(512), dim3(256), 0, stream, pA, pB, tgt, part);
        hipLaunchKernelGGL(merge8_kernel, dim3(BATCH * NPTS / 256), dim3(256), 0, stream,
                           part, corr_tgt, corres_i, outC);
    }
    hipLaunchKernelGGL(prep_p4, dim3(BATCH * NPTS / 256), dim3(256), 0, stream, src, P4);
    hipLaunchKernelGGL(knn_topk, dim3(BATCH * 128), dim3(256), 0, stream, P4, topI);
    hipLaunchKernelGGL(gfm_finish, dim3(BATCH * NPTS / 4), dim3(256), 0, stream,
                       P4, corr_tgt, topI, mean_loss);
    hipLaunchKernelGGL(weight_kernel, dim3(BATCH), dim3(256), 0, stream,
                       mean_loss, outW);
    hipLaunchKernelGGL(procrustes_kernel, dim3(BATCH), dim3(256), 0, stream,
                       src, tgt, corres_i, outW, outR, outT);
}

// Round 14
// 282.168 us; speedup vs baseline: 1.2368x; 1.0612x over previous
//
#include <hip/hip_runtime.h>
#include <math.h>

#define BATCH 8
#define DIM   512
#define NPTS  2048
#define KNN   10
#define NPAIR 45
#define FCHK   16
#define FCHKSZ 128

typedef __attribute__((ext_vector_type(8))) short    bf16x8;
typedef __attribute__((ext_vector_type(4))) float    f32x4;
typedef __attribute__((ext_vector_type(4))) unsigned int u32x4;

__device__ inline unsigned short bf16_rne(float x) {
    unsigned int u = __float_as_uint(x);
    u += 0x7FFFu + ((u >> 16) & 1u);
    return (unsigned short)(u >> 16);
}
__device__ inline float bf16_to_f(unsigned short h) {
    return __uint_as_float(((unsigned int)h) << 16);
}
__device__ inline unsigned long long shflx_u64(unsigned long long v, int mask) {
    unsigned int lo = (unsigned int)v, hi = (unsigned int)(v >> 32);
    lo = (unsigned int)__shfl_xor((int)lo, mask);
    hi = (unsigned int)__shfl_xor((int)hi, mask);
    return ((unsigned long long)hi << 32) | lo;
}

// ===========================================================================
// Kernel S: split se/te into 3 bf16 planes (h,m,l), transposed to [b][n][d].
// ===========================================================================
__global__ __launch_bounds__(256)
void split_kernel(const float* __restrict__ se, const float* __restrict__ te,
                  unsigned short* __restrict__ pA, unsigned short* __restrict__ pB)
{
    const int bid = blockIdx.x;
    const int tensor = bid >> 11;
    const int rr_ = bid & 2047;
    const int b  = rr_ >> 8;
    const int dt = (rr_ >> 5) & 7;
    const int nt = rr_ & 31;
    const float* srcp = (tensor == 0 ? se : te)
                        + ((size_t)b * DIM + dt * 64) * NPTS + nt * 64;
    unsigned short* dst = (tensor == 0 ? pA : pB);
    const size_t PL = (size_t)BATCH * NPTS * DIM;
    unsigned short* base = dst + (size_t)b * NPTS * DIM + (size_t)nt * 64 * DIM + dt * 64;

    __shared__ float T[64][65];
    const int t = threadIdx.x;
    {
        int r = t >> 4, c4 = t & 15;
        #pragma unroll
        for (int it = 0; it < 4; ++it) {
            int d = r + it * 16;
            float4 v = *(const float4*)&srcp[(size_t)d * NPTS + c4 * 4];
            T[d][c4 * 4 + 0] = v.x; T[d][c4 * 4 + 1] = v.y;
            T[d][c4 * 4 + 2] = v.z; T[d][c4 * 4 + 3] = v.w;
        }
    }
    __syncthreads();
    const int n  = t >> 2;
    const int d0 = (t & 3) * 16;
    unsigned short hh[16], mm[16], ll[16];
    #pragma unroll
    for (int j = 0; j < 16; ++j) {
        float a = T[d0 + j][n];
        unsigned short h = bf16_rne(a);
        float r1 = a - bf16_to_f(h);
        unsigned short m = bf16_rne(r1);
        float r2 = r1 - bf16_to_f(m);
        unsigned short l = bf16_rne(r2);
        hh[j] = h; mm[j] = m; ll[j] = l;
    }
    unsigned short* o = base + (size_t)n * DIM + d0;
    *(u32x4*)(o)            = *(u32x4*)&hh[0];
    *(u32x4*)(o + 8)        = *(u32x4*)&hh[8];
    *(u32x4*)(o + PL)       = *(u32x4*)&mm[0];
    *(u32x4*)(o + PL + 8)   = *(u32x4*)&mm[8];
    *(u32x4*)(o + 2*PL)     = *(u32x4*)&ll[0];
    *(u32x4*)(o + 2*PL + 8) = *(u32x4*)&ll[8];
}

// ===========================================================================
// Kernel H: phase-1 GEMM on h-planes only (K=512). Writes uhat (bf16 of
// 10000*dot_h/sqrt(512)) for ALL 2048x2048 per batch.
// ===========================================================================
__global__ __launch_bounds__(256, 2)
void score_h(const unsigned short* __restrict__ pA, const unsigned short* __restrict__ pB,
             unsigned short* __restrict__ uhat)
{
    const int bid  = blockIdx.x;
    const int xcd  = bid & 7;
    const int slot = bid >> 3;
    const int g    = xcd + 8 * (slot >> 4);
    const int ntile = slot & 15;
    const int b    = g >> 2;
    const int mc   = g & 3;
    const int n0 = ntile * 128;
    const int t  = threadIdx.x;
    const int w  = t >> 6;
    const int l  = t & 63;
    const int wn = w >> 1, wm = w & 1;
    const int l15 = l & 15, l4 = l >> 4;

    __shared__ unsigned short As[128 * 64];
    __shared__ unsigned short Bs[128 * 64];

    int srow[4], skg[4], ldsoff[4];
    #pragma unroll
    for (int qq = 0; qq < 4; ++qq) {
        int s = qq * 256 + t;
        int row = s >> 3, slt = s & 7;
        srow[qq] = row;
        skg[qq] = slt ^ (row & 7);
        ldsoff[qq] = row * 64 + slt * 8;
    }
    int aroff[4], arxor[4], broff[4], brxor[4];
    #pragma unroll
    for (int i = 0; i < 4; ++i) {
        int ar = wn * 64 + i * 16 + l15;
        aroff[i] = ar * 64; arxor[i] = ar & 7;
        int br = wm * 64 + i * 16 + l15;
        broff[i] = br * 64; brxor[i] = br & 7;
    }

    const float scl = 10000.0f / sqrtf((float)DIM);
    const unsigned short* Ab = pA + (size_t)b * NPTS * DIM;
    const unsigned short* Bb = pB + (size_t)b * NPTS * DIM;

    for (int mt = 0; mt < 4; ++mt) {
        const int m0 = mc * 512 + mt * 128;
        f32x4 acc[4][4];
        #pragma unroll
        for (int i = 0; i < 4; ++i)
            #pragma unroll
            for (int j = 0; j < 4; ++j) acc[i][j] = (f32x4){0.f, 0.f, 0.f, 0.f};

        for (int k0 = 0; k0 < 512; k0 += 64) {
            __syncthreads();
            bf16x8 ra[4], rb[4];
            #pragma unroll
            for (int qq = 0; qq < 4; ++qq) {
                ra[qq] = *(const bf16x8*)&Ab[(size_t)(n0 + srow[qq]) * DIM + k0 + skg[qq] * 8];
                rb[qq] = *(const bf16x8*)&Bb[(size_t)(m0 + srow[qq]) * DIM + k0 + skg[qq] * 8];
            }
            #pragma unroll
            for (int qq = 0; qq < 4; ++qq) {
                *(bf16x8*)&As[ldsoff[qq]] = ra[qq];
                *(bf16x8*)&Bs[ldsoff[qq]] = rb[qq];
            }
            __syncthreads();
            #pragma unroll
            for (int ks = 0; ks < 2; ++ks) {
                bf16x8 af[4], bfr[4];
                #pragma unroll
                for (int i = 0; i < 4; ++i) {
                    af[i]  = *(const bf16x8*)&As[aroff[i] + (((ks * 4 + l4) ^ arxor[i]) * 8)];
                    bfr[i] = *(const bf16x8*)&Bs[broff[i] + (((ks * 4 + l4) ^ brxor[i]) * 8)];
                }
                #pragma unroll
                for (int i = 0; i < 4; ++i)
                    #pragma unroll
                    for (int j = 0; j < 4; ++j)
                        acc[i][j] = __builtin_amdgcn_mfma_f32_16x16x32_bf16(af[i], bfr[j], acc[i][j], 0, 0, 0);
            }
        }
        #pragma unroll
        for (int i = 0; i < 4; ++i) {
            #pragma unroll
            for (int j = 0; j < 4; ++j) {
                int mcol = m0 + wm * 64 + j * 16 + l15;
                #pragma unroll
                for (int r = 0; r < 4; ++r) {
                    int nabs = n0 + wn * 64 + i * 16 + l4 * 4 + r;
                    uhat[((size_t)(b * NPTS + nabs)) * NPTS + mcol] =
                        bf16_rne(scl * acc[i][j][r]);
                }
            }
        }
    }
}

// ===========================================================================
// Kernel R: resolve. One wave per row. Fast path register-only; slow path
// wave-parallel exact 26-bit rescore.
// ===========================================================================
__global__ __launch_bounds__(256)
void resolve(const unsigned short* __restrict__ uhat,
             const unsigned short* __restrict__ pA, const unsigned short* __restrict__ pB,
             const float* __restrict__ tgt,
             float* __restrict__ corr_tgt, int* __restrict__ corres_i,
             float* __restrict__ corres_out)
{
    const int wid  = threadIdx.x >> 6;
    const int lane = threadIdx.x & 63;
    const int gid  = blockIdx.x * 4 + wid;
    const int b    = gid >> 11;
    const int n    = gid & 2047;

    __shared__ int s_m[4][64];
    __shared__ int s_cnt[4];

    if (lane == 0) s_cnt[wid] = 0;
    __syncthreads();

    const unsigned short* urow = uhat + (size_t)gid * NPTS;
    float v[32];
    float lmax = -3.402823466e38f; int lk = 0;
    #pragma unroll
    for (int g2 = 0; g2 < 4; ++g2) {
        u32x4 pk = *(const u32x4*)&urow[lane * 32 + g2 * 8];
        #pragma unroll
        for (int e = 0; e < 4; ++e) {
            unsigned int w2 = pk[e];
            float f0 = __uint_as_float((w2 & 0xFFFFu) << 16);
            float f1 = __uint_as_float(w2 & 0xFFFF0000u);
            int k0 = g2 * 8 + e * 2;
            v[k0] = f0; v[k0 + 1] = f1;
            if (f0 > lmax) { lmax = f0; lk = k0; }
            if (f1 > lmax) { lmax = f1; lk = k0 + 1; }
        }
    }
    float vmax = lmax; int argm = lane * 32 + lk;
    #pragma unroll
    for (int mask = 1; mask < 64; mask <<= 1) {
        float ov = __shfl_xor(vmax, mask);
        int   oi = __shfl_xor(argm, mask);
        if (ov > vmax || (ov == vmax && oi < argm)) { vmax = ov; argm = oi; }
    }
    const float cut = vmax - 1200.0f;
    int cnt = 0;
    #pragma unroll
    for (int k = 0; k < 32; ++k) cnt += (v[k] >= cut) ? 1 : 0;
    int nc = cnt;
    #pragma unroll
    for (int mask = 1; mask < 64; mask <<= 1) nc += __shfl_xor(nc, mask);

    if (nc > 1) {
        #pragma unroll
        for (int k = 0; k < 32; ++k) {
            if (v[k] >= cut) {
                int slot = atomicAdd(&s_cnt[wid], 1);
                if (slot < 64) s_m[wid][slot] = lane * 32 + k;
            }
        }
    }
    __syncthreads();
    if (nc > 1 && lane == 0) {
        int ncc = nc > 64 ? 64 : nc;
        for (int i = 1; i < ncc; ++i) {
            int key = s_m[wid][i]; int j = i - 1;
            while (j >= 0 && s_m[wid][j] > key) { s_m[wid][j + 1] = s_m[wid][j]; --j; }
            s_m[wid][j + 1] = key;
        }
    }
    __syncthreads();

    if (nc == 1) {
        if (lane < 3) corr_tgt[(size_t)gid * 3 + lane] = tgt[((size_t)b * 3 + lane) * NPTS + argm];
        if (lane == 0) { corres_i[gid] = argm; corres_out[gid] = (float)argm; }
        return;
    }
    const int ncc = nc > 64 ? 64 : nc;

    const size_t PL = (size_t)BATCH * NPTS * DIM;
    const unsigned short* Ar = pA + ((size_t)b * NPTS + n) * DIM + lane * 8;
    bf16x8 a_h = *(const bf16x8*)&Ar[0];
    bf16x8 a_m = *(const bf16x8*)&Ar[PL];
    bf16x8 a_l = *(const bf16x8*)&Ar[2 * PL];
    float ah[8], am[8], al[8];
    #pragma unroll
    for (int e = 0; e < 8; ++e) {
        ah[e] = bf16_to_f((unsigned short)a_h[e]);
        am[e] = bf16_to_f((unsigned short)a_m[e]);
        al[e] = bf16_to_f((unsigned short)a_l[e]);
    }

    const float sqd = sqrtf((float)DIM);
    float umax = -3.402823466e38f; int uarg = 0x7fffffff;
    float myu = 0.f;
    for (int c = 0; c < ncc; ++c) {
        int mB = s_m[wid][c];
        const unsigned short* Br = pB + ((size_t)b * NPTS + mB) * DIM + lane * 8;
        bf16x8 b_h = *(const bf16x8*)&Br[0];
        bf16x8 b_m = *(const bf16x8*)&Br[PL];
        bf16x8 b_l = *(const bf16x8*)&Br[2 * PL];
        float part = 0.f;
        #pragma unroll
        for (int e = 0; e < 8; ++e) {
            float bh = bf16_to_f((unsigned short)b_h[e]);
            float bm = bf16_to_f((unsigned short)b_m[e]);
            float bl = bf16_to_f((unsigned short)b_l[e]);
            part += ah[e] * bh;
            part += ah[e] * bm;
            part += am[e] * bh;
            part += ah[e] * bl;
            part += am[e] * bm;
            part += al[e] * bh;
        }
        #pragma unroll
        for (int mask = 1; mask < 64; mask <<= 1) part += __shfl_xor(part, mask);
        float u = 10000.0f * (part / sqd);
        if (u > umax) { umax = u; uarg = mB; }
        if (lane == c) myu = u;
    }

    float p = (lane < ncc) ? expf(myu - umax) : 0.f;
    int myM = (lane < ncc) ? s_m[wid][lane] : 0;
    float tx = 0.f, ty = 0.f, tz = 0.f, ps = p;
    if (lane < ncc) {
        tx = p * tgt[((size_t)b * 3 + 0) * NPTS + myM];
        ty = p * tgt[((size_t)b * 3 + 1) * NPTS + myM];
        tz = p * tgt[((size_t)b * 3 + 2) * NPTS + myM];
    }
    #pragma unroll
    for (int mask = 1; mask < 64; mask <<= 1) {
        ps += __shfl_xor(ps, mask);
        tx += __shfl_xor(tx, mask);
        ty += __shfl_xor(ty, mask);
        tz += __shfl_xor(tz, mask);
    }
    if (lane == 0) {
        corr_tgt[(size_t)gid * 3 + 0] = tx / ps;
        corr_tgt[(size_t)gid * 3 + 1] = ty / ps;
        corr_tgt[(size_t)gid * 3 + 2] = tz / ps;
        corres_i[gid]   = uarg;
        corres_out[gid] = (float)uarg;
    }
}

// ===========================================================================
// FALLBACK Kernel A (round-8 proven): 6-product MFMA + fused online softmax
// ===========================================================================
__global__ __launch_bounds__(256, 2)
void score_mfma(const unsigned short* __restrict__ pA, const unsigned short* __restrict__ pB,
                const float* __restrict__ tgt, float* __restrict__ part)
{
    const int bid  = blockIdx.x;
    const int xcd  = bid & 7;
    const int slot = bid >> 3;
    const int g    = xcd + 8 * (slot >> 4);
    const int ntile = slot & 15;
    const int b    = g >> 2;
    const int mc   = g & 3;
    const int n0 = ntile * 128;
    const int t  = threadIdx.x;
    const int w  = t >> 6;
    const int l  = t & 63;
    const int wn = w >> 1, wm = w & 1;
    const int l15 = l & 15, l4 = l >> 4;

    __shared__ unsigned short As[128 * 64];
    __shared__ unsigned short Bs[128 * 64];

    const size_t PL = (size_t)BATCH * NPTS * DIM;

    int srow[4], skg[4], ldsoff[4];
    #pragma unroll
    for (int qq = 0; qq < 4; ++qq) {
        int s = qq * 256 + t;
        int row = s >> 3, slt = s & 7;
        srow[qq] = row;
        skg[qq] = slt ^ (row & 7);
        ldsoff[qq] = row * 64 + slt * 8;
    }
    int aroff[4], arxor[4], broff[4], brxor[4];
    #pragma unroll
    for (int i = 0; i < 4; ++i) {
        int ar = wn * 64 + i * 16 + l15;
        aroff[i] = ar * 64; arxor[i] = ar & 7;
        int br = wm * 64 + i * 16 + l15;
        broff[i] = br * 64; brxor[i] = br & 7;
    }

    float mx[16], sm[16], ax[16], ay[16], az[16]; int ag[16];
    #pragma unroll
    for (int si = 0; si < 16; ++si) {
        mx[si] = -3.402823466e38f; sm[si] = 0.f;
        ax[si] = 0.f; ay[si] = 0.f; az[si] = 0.f; ag[si] = 0;
    }

    const float sqd = sqrtf((float)DIM);
    const unsigned short* Ab = pA + (size_t)b * NPTS * DIM;
    const unsigned short* Bb = pB + (size_t)b * NPTS * DIM;
    const int AIDX[6] = {0, 0, 1, 0, 1, 2};
    const int BIDX[6] = {0, 1, 0, 2, 1, 0};

    for (int mt = 0; mt < 4; ++mt) {
        const int m0 = mc * 512 + mt * 128;
        f32x4 acc[4][4];
        #pragma unroll
        for (int i = 0; i < 4; ++i)
            #pragma unroll
            for (int j = 0; j < 4; ++j) acc[i][j] = (f32x4){0.f, 0.f, 0.f, 0.f};

        for (int q = 0; q < 6; ++q) {
            const unsigned short* Ap = Ab + (size_t)AIDX[q] * PL;
            const unsigned short* Bp = Bb + (size_t)BIDX[q] * PL;
            for (int k0 = 0; k0 < 512; k0 += 64) {
                __syncthreads();
                bf16x8 ra[4], rb[4];
                #pragma unroll
                for (int qq = 0; qq < 4; ++qq) {
                    ra[qq] = *(const bf16x8*)&Ap[(size_t)(n0 + srow[qq]) * DIM + k0 + skg[qq] * 8];
                    rb[qq] = *(const bf16x8*)&Bp[(size_t)(m0 + srow[qq]) * DIM + k0 + skg[qq] * 8];
                }
                #pragma unroll
                for (int qq = 0; qq < 4; ++qq) {
                    *(bf16x8*)&As[ldsoff[qq]] = ra[qq];
                    *(bf16x8*)&Bs[ldsoff[qq]] = rb[qq];
                }
                __syncthreads();
                #pragma unroll
                for (int ks = 0; ks < 2; ++ks) {
                    bf16x8 af[4], bfr[4];
                    #pragma unroll
                    for (int i = 0; i < 4; ++i) {
                        af[i]  = *(const bf16x8*)&As[aroff[i] + (((ks * 4 + l4) ^ arxor[i]) * 8)];
                        bfr[i] = *(const bf16x8*)&Bs[broff[i] + (((ks * 4 + l4) ^ brxor[i]) * 8)];
                    }
                    #pragma unroll
                    for (int i = 0; i < 4; ++i)
                        #pragma unroll
                        for (int j = 0; j < 4; ++j)
                            acc[i][j] = __builtin_amdgcn_mfma_f32_16x16x32_bf16(af[i], bfr[j], acc[i][j], 0, 0, 0);
                }
            }
        }
        float tg0[4], tg1[4], tg2[4];
        #pragma unroll
        for (int j = 0; j < 4; ++j) {
            int mcol = m0 + wm * 64 + j * 16 + l15;
            tg0[j] = tgt[((size_t)b * 3 + 0) * NPTS + mcol];
            tg1[j] = tgt[((size_t)b * 3 + 1) * NPTS + mcol];
            tg2[j] = tgt[((size_t)b * 3 + 2) * NPTS + mcol];
        }
        #pragma unroll
        for (int i = 0; i < 4; ++i) {
            #pragma unroll
            for (int r = 0; r < 4; ++r) {
                const int si = i * 4 + r;
                float u[4];
                float lm = -3.402823466e38f; int la = 0;
                #pragma unroll
                for (int j = 0; j < 4; ++j) {
                    float s  = acc[i][j][r] / sqd;
                    float uu = 10000.0f * s;
                    u[j] = uu;
                    if (uu > lm) { lm = uu; la = m0 + wm * 64 + j * 16 + l15; }
                }
                float nm = fmaxf(mx[si], lm);
                if (lm > mx[si]) ag[si] = la;
                float f = expf(mx[si] - nm);
                mx[si] = nm;
                float s_ = sm[si] * f, x_ = ax[si] * f, y_ = ay[si] * f, z_ = az[si] * f;
                #pragma unroll
                for (int j = 0; j < 4; ++j) {
                    float p = expf(u[j] - nm);
                    s_ += p; x_ += p * tg0[j]; y_ += p * tg1[j]; z_ += p * tg2[j];
                }
                sm[si] = s_; ax[si] = x_; ay[si] = y_; az[si] = z_;
            }
        }
    }

    #pragma unroll
    for (int si = 0; si < 16; ++si) {
        for (int mask = 1; mask < 16; mask <<= 1) {
            float omx = __shfl_xor(mx[si], mask);
            float osm = __shfl_xor(sm[si], mask);
            float oax = __shfl_xor(ax[si], mask);
            float oay = __shfl_xor(ay[si], mask);
            float oaz = __shfl_xor(az[si], mask);
            int   oag = __shfl_xor(ag[si], mask);
            float nm = fmaxf(mx[si], omx);
            float f1 = expf(mx[si] - nm), f2 = expf(omx - nm);
            sm[si] = sm[si] * f1 + osm * f2;
            ax[si] = ax[si] * f1 + oax * f2;
            ay[si] = ay[si] * f1 + oay * f2;
            az[si] = az[si] * f1 + oaz * f2;
            ag[si] = (omx > mx[si]) ? oag : ((omx == mx[si]) ? min(ag[si], oag) : ag[si]);
            mx[si] = nm;
        }
    }
    if (l15 == 0) {
        const int chunk = mc * 2 + wm;
        #pragma unroll
        for (int i = 0; i < 4; ++i)
            #pragma unroll
            for (int r = 0; r < 4; ++r) {
                const int si = i * 4 + r;
                int nabs = n0 + wn * 64 + i * 16 + l4 * 4 + r;
                size_t o = (((size_t)b * NPTS + nabs) * 8 + chunk) * 8;
                part[o + 0] = mx[si]; part[o + 1] = sm[si];
                part[o + 2] = ax[si]; part[o + 3] = ay[si]; part[o + 4] = az[si];
                part[o + 5] = __int_as_float(ag[si]);
            }
    }
}

__global__ __launch_bounds__(256)
void merge8_kernel(const float* __restrict__ part, float* __restrict__ corr_tgt,
                   int* __restrict__ corres_i, float* __restrict__ corres_out)
{
    int r = blockIdx.x * 256 + threadIdx.x;
    float m = -3.402823466e38f, s = 0.f, x = 0.f, y = 0.f, z = 0.f; int a = 0x7fffffff;
    for (int c = 0; c < 8; ++c) {
        const float* p = &part[((size_t)r * 8 + c) * 8];
        float pm = p[0]; int pa = __float_as_int(p[5]);
        float nm = fmaxf(m, pm);
        float f1 = expf(m - nm), f2 = expf(pm - nm);
        s = s * f1 + p[1] * f2;
        x = x * f1 + p[2] * f2;
        y = y * f1 + p[3] * f2;
        z = z * f1 + p[4] * f2;
        if (pm > m) a = pa; else if (pm == m) a = min(a, pa);
        m = nm;
    }
    corr_tgt[(size_t)r * 3 + 0] = x / s;
    corr_tgt[(size_t)r * 3 + 1] = y / s;
    corr_tgt[(size_t)r * 3 + 2] = z / s;
    corres_i[r]   = a;
    corres_out[r] = (float)a;
}

// ===========================================================================
// Kernel B0: P4 = (x,y,z,|p|^2) per source point
// ===========================================================================
__global__ __launch_bounds__(256)
void prep_p4(const float* __restrict__ src, float4* __restrict__ P4)
{
    int i = blockIdx.x * 256 + threadIdx.x;
    int b = i >> 11, m = i & 2047;
    float x = src[((size_t)b * 3 + 0) * NPTS + m];
    float y = src[((size_t)b * 3 + 1) * NPTS + m];
    float z = src[((size_t)b * 3 + 2) * NPTS + m];
    P4[i] = make_float4(x, y, z, x * x + y * y + z * z);
}

// ===========================================================================
// Kernel B1 (FUSED v2): per-(n,chunk) top-10 scan + SHUFFLE butterfly merge.
// 16 chunks x 128 pts; the 16 chunk-threads of a row are 16 consecutive
// lanes of one wave -> merge via __shfl_xor, zero LDS, no serial tail.
// Two sorted ascending 10-lists merged branchlessly via
//   M[k] = min_{i=0..k+1} max(A[i-1], B[k-i])   (all compile-time indices).
// ===========================================================================
__global__ __launch_bounds__(256)
void knn_topk(const float4* __restrict__ P4, int* __restrict__ topI)
{
    const int bid = blockIdx.x;                    // 0..1023
    const int b = bid >> 7, nblk = bid & 127;      // 128 blocks/batch
    const int t = threadIdx.x;
    const int c  = t & (FCHK - 1);                 // chunk 0..15 (lane%16)
    const int rl = t >> 4;                         // row-in-block 0..15
    const int n = nblk * 16 + rl;
    const float4* Pb = P4 + (size_t)b * NPTS;
    const float4 pn = Pb[n];

    unsigned long long kl[KNN];
    #pragma unroll
    for (int k = 0; k < KNN; ++k) kl[k] = 0xFFFFFFFFFFFFFFFFull;

    const int m0 = c * FCHKSZ;
    for (int mm = 0; mm < FCHKSZ; ++mm) {
        int m = m0 + mm;
        float4 pm = Pb[m];
        float dot = pn.x * pm.x + pn.y * pm.y + pn.z * pm.z;
        float d2  = (pn.w + pm.w) - 2.0f * dot;
        if (d2 < 0.f) d2 = 0.f;
        float w = expf(-d2 * 0.5f);
        unsigned long long key =
            ((unsigned long long)(~__float_as_uint(w)) << 32) | (unsigned int)m;
        if (key < kl[KNN - 1]) {
            unsigned long long ck = key;
            #pragma unroll
            for (int k = 0; k < KNN; ++k) {
                if (ck < kl[k]) { unsigned long long tv = kl[k]; kl[k] = ck; ck = tv; }
            }
        }
    }

    // butterfly merge across the 16 chunk-lanes of this row
    #pragma unroll
    for (int mask = 1; mask < FCHK; mask <<= 1) {
        unsigned long long B[KNN];
        #pragma unroll
        for (int k = 0; k < KNN; ++k) B[k] = shflx_u64(kl[k], mask);
        unsigned long long M[KNN];
        #pragma unroll
        for (int k = 0; k < KNN; ++k) {
            unsigned long long best = B[k];                     // i = 0 term
            #pragma unroll
            for (int i = 1; i <= k; ++i) {
                unsigned long long hi = kl[i - 1] > B[k - i] ? kl[i - 1] : B[k - i];
                best = hi < best ? hi : best;
            }
            unsigned long long ak = kl[k];                      // i = k+1 term
            M[k] = ak < best ? ak : best;
        }
        #pragma unroll
        for (int k = 0; k < KNN; ++k) kl[k] = M[k];
    }

    if (c == 0) {
        size_t gid = (size_t)(b << 11) + n;
        #pragma unroll
        for (int k = 0; k < KNN; ++k)
            topI[gid * KNN + k] = (int)(kl[k] & 0xFFFFFFFFull);
    }
}

// ===========================================================================
// Kernel B2: wave-per-n GFM finish (4096 blocks x 4 waves)
// ===========================================================================
__global__ __launch_bounds__(256)
void gfm_finish(const float4* __restrict__ P4, const float* __restrict__ corr_tgt,
                const int* __restrict__ topI, float* __restrict__ mean_loss)
{
    const int wid  = threadIdx.x >> 6;
    const int lane = threadIdx.x & 63;
    const int gid  = blockIdx.x * 4 + wid;
    const int b    = gid >> 11;

    __shared__ float PT[4][KNN][6];
    __shared__ float LS[4][48];
    __shared__ float SR[4][48];
    __shared__ float TOT[4][48];

    if (lane < KNN) {
        int idx = topI[(size_t)gid * KNN + lane];
        float4 pk = P4[(b << 11) + idx];
        size_t o = ((size_t)(b << 11) + idx) * 3;
        PT[wid][lane][0] = pk.x; PT[wid][lane][1] = pk.y; PT[wid][lane][2] = pk.z;
        PT[wid][lane][3] = corr_tgt[o];
        PT[wid][lane][4] = corr_tgt[o + 1];
        PT[wid][lane][5] = corr_tgt[o + 2];
    }
    float4 pn = P4[gid];
    size_t on = (size_t)gid * 3;
    const float cnx = corr_tgt[on], cny = corr_tgt[on + 1], cnz = corr_tgt[on + 2];
    __syncthreads();

    int pi = 0, pj = 1;
    {
        int pp = lane;
        #pragma unroll
        for (int r = 0; r < 9; ++r) {
            int cnt = 9 - r;
            if (pp >= 0 && pp < cnt) { pi = r; pj = r + 1 + pp; }
            pp -= cnt;
        }
    }

    float ls_p = 0.f, rg_p = 0.f;
    if (lane < NPAIR) {
        float e1x = PT[wid][pi][0] - pn.x, e1y = PT[wid][pi][1] - pn.y, e1z = PT[wid][pi][2] - pn.z;
        float e2x = PT[wid][pj][0] - pn.x, e2y = PT[wid][pj][1] - pn.y, e2z = PT[wid][pj][2] - pn.z;
        float cx = e1y * e2z - e1z * e2y;
        float cy = e1z * e2x - e1x * e2z;
        float cz = e1x * e2y - e1y * e2x;
        float as_ = 0.5f * sqrtf(cx * cx + cy * cy + cz * cz);
        float f1x = PT[wid][pi][3] - cnx, f1y = PT[wid][pi][4] - cny, f1z = PT[wid][pi][5] - cnz;
        float f2x = PT[wid][pj][3] - cnx, f2y = PT[wid][pj][4] - cny, f2z = PT[wid][pj][5] - cnz;
        float gx = f1y * f2z - f1z * f2y;
        float gy = f1z * f2x - f1x * f2z;
        float gz = f1x * f2y - f1y * f2x;
        float at_ = 0.5f * sqrtf(gx * gx + gy * gy + gz * gz);
        float tl2 = at_ + 1e-6f;
        float dd  = as_ - tl2;
        float e2_ = 1e-6f * 1e-6f;
        float num = (e2_ + e2_) + dd * dd;
        float den = (1e-6f + 1e-6f) + (as_ + tl2);
        ls_p = num / den;
        rg_p = sqrtf(num);
        LS[wid][lane] = ls_p;
    }
    __syncthreads();

    int rk = 0;
    if (lane < NPAIR) {
        #pragma unroll
        for (int q = 0; q < NPAIR; ++q) {
            float lq = LS[wid][q];
            rk += (lq < ls_p) || (lq == ls_p && q < lane);
        }
        SR[wid][rk] = ls_p;
    }
    __syncthreads();

    float tot_p = 0.f;
    if (lane < NPAIR) {
        tot_p = SR[wid][lane] + 0.1f * rg_p;
        TOT[wid][lane] = tot_p;
    }
    __syncthreads();

    int rt2 = 0;
    if (lane < NPAIR) {
        #pragma unroll
        for (int q = 0; q < NPAIR; ++q) {
            float tq = TOT[wid][q];
            rt2 += (tq < tot_p) || (tq == tot_p && q < lane);
        }
        SR[wid][rt2] = tot_p;
    }
    __syncthreads();

    float med = SR[wid][22];
    float thr = 3.0f * med;
    if (lane < KNN) {
        float v = tot_p;
        v = (v > thr) ? 0.0f : v;
        LS[wid][lane] = sqrtf(v + 1e-6f);
    }
    __syncthreads();
    if (lane == 0) {
        float acc = 0.f;
        #pragma unroll
        for (int k = 0; k < KNN; ++k) acc += LS[wid][k];
        mean_loss[gid] = acc / 10.0f;
    }
}

// ===========================================================================
// Kernel C: per-batch min + binary weight
// ===========================================================================
__global__ __launch_bounds__(256)
void weight_kernel(const float* __restrict__ mean_loss, float* __restrict__ weight_out)
{
    const int b = blockIdx.x;
    const int t = threadIdx.x;
    __shared__ float red[256];
    float mn = 3.402823466e38f;
    for (int i = t; i < NPTS; i += 256)
        mn = fminf(mn, mean_loss[(size_t)b * NPTS + i]);
    red[t] = mn; __syncthreads();
    for (int s2 = 128; s2 > 0; s2 >>= 1) {
        if (t < s2) red[t] = fminf(red[t], red[t + s2]);
        __syncthreads();
    }
    float ml = red[0];
    for (int i = t; i < NPTS; i += 256) {
        float d = mean_loss[(size_t)b * NPTS + i] - ml;
        float e = expf(-20.0f * d);
        float wts = 2.0f * (e / (1.0f + e));
        weight_out[(size_t)b * NPTS + i] = (wts > 0.5f) ? 1.0f : 0.0f;
    }
}

// ===========================================================================
// Kernel D: weighted Procrustes per batch (Horn quaternion)
// ===========================================================================
__device__ void jacobi4(double A[4][4], double V[4][4]) {
    for (int i = 0; i < 4; ++i)
        for (int j = 0; j < 4; ++j) V[i][j] = (i == j) ? 1.0 : 0.0;
    for (int sweep = 0; sweep < 12; ++sweep) {
        for (int p = 0; p < 3; ++p) for (int q = p + 1; q < 4; ++q) {
            double apq = A[p][q];
            if (fabs(apq) < 1e-30) continue;
            double theta = (A[q][q] - A[p][p]) / (2.0 * apq);
            double tt = (theta >= 0 ? 1.0 : -1.0) / (fabs(theta) + sqrt(theta * theta + 1.0));
            double c = 1.0 / sqrt(tt * tt + 1.0), s = tt * c;
            for (int k = 0; k < 4; ++k) {
                double akp = A[k][p], akq = A[k][q];
                A[k][p] = c * akp - s * akq;
                A[k][q] = s * akp + c * akq;
            }
            for (int k = 0; k < 4; ++k) {
                double apk = A[p][k], aqk = A[q][k];
                A[p][k] = c * apk - s * aqk;
                A[q][k] = s * apk + c * aqk;
            }
            for (int k = 0; k < 4; ++k) {
                double vkp = V[k][p], vkq = V[k][q];
                V[k][p] = c * vkp - s * vkq;
                V[k][q] = s * vkp + c * vkq;
            }
        }
    }
}

__global__ __launch_bounds__(256)
void procrustes_kernel(const float* __restrict__ src, const float* __restrict__ tgt,
                       const int* __restrict__ corres_i, const float* __restrict__ weight,
                       float* __restrict__ outR, float* __restrict__ outT)
{
    const int b = blockIdx.x;
    const int t = threadIdx.x;
    __shared__ float red[256][9];
    __shared__ float s_tw, s_mx[3], s_my[3];
    __shared__ float s_cov[9];

    float a0 = 0, a1 = 0, a2 = 0, a3 = 0, a4 = 0, a5 = 0, a6 = 0;
    for (int i = t; i < NPTS; i += 256) {
        float w = weight[(size_t)b * NPTS + i];
        float X0 = src[((size_t)b * 3 + 0) * NPTS + i];
        float X1 = src[((size_t)b * 3 + 1) * NPTS + i];
        float X2 = src[((size_t)b * 3 + 2) * NPTS + i];
        int c = corres_i[(size_t)b * NPTS + i];
        float Y0 = tgt[((size_t)b * 3 + 0) * NPTS + c];
        float Y1 = tgt[((size_t)b * 3 + 1) * NPTS + c];
        float Y2 = tgt[((size_t)b * 3 + 2) * NPTS + c];
        a0 += w;
        a1 += w * X0; a2 += w * X1; a3 += w * X2;
        a4 += w * Y0; a5 += w * Y1; a6 += w * Y2;
    }
    red[t][0] = a0; red[t][1] = a1; red[t][2] = a2; red[t][3] = a3;
    red[t][4] = a4; red[t][5] = a5; red[t][6] = a6; red[t][7] = 0; red[t][8] = 0;
    __syncthreads();
    for (int s2 = 128; s2 > 0; s2 >>= 1) {
        if (t < s2)
            for (int k = 0; k < 7; ++k) red[t][k] += red[t + s2][k];
        __syncthreads();
    }
    if (t == 0) {
        float tw = red[0][0];
        float itw = tw + 1e-7f;
        s_tw = tw;
        s_mx[0] = red[0][1] / itw; s_mx[1] = red[0][2] / itw; s_mx[2] = red[0][3] / itw;
        s_my[0] = red[0][4] / itw; s_my[1] = red[0][5] / itw; s_my[2] = red[0][6] / itw;
    }
    __syncthreads();
    const float twp = s_tw + 1e-7f;
    const float mx0 = s_mx[0], mx1 = s_mx[1], mx2 = s_mx[2];
    const float my0 = s_my[0], my1 = s_my[1], my2 = s_my[2];

    float cv[9] = {0,0,0,0,0,0,0,0,0};
    for (int i = t; i < NPTS; i += 256) {
        float w = weight[(size_t)b * NPTS + i];
        float nwn = w / twp;
        float X0 = src[((size_t)b * 3 + 0) * NPTS + i] - mx0;
        float X1 = src[((size_t)b * 3 + 1) * NPTS + i] - mx1;
        float X2 = src[((size_t)b * 3 + 2) * NPTS + i] - mx2;
        int c = corres_i[(size_t)b * NPTS + i];
        float Y0 = tgt[((size_t)b * 3 + 0) * NPTS + c] - my0;
        float Y1 = tgt[((size_t)b * 3 + 1) * NPTS + c] - my1;
        float Y2 = tgt[((size_t)b * 3 + 2) * NPTS + c] - my2;
        float b0 = nwn * X0, b1 = nwn * X1, b2 = nwn * X2;
        cv[0] += Y0 * b0; cv[1] += Y0 * b1; cv[2] += Y0 * b2;
        cv[3] += Y1 * b0; cv[4] += Y1 * b1; cv[5] += Y1 * b2;
        cv[6] += Y2 * b0; cv[7] += Y2 * b1; cv[8] += Y2 * b2;
    }
    __syncthreads();
    for (int k = 0; k < 9; ++k) red[t][k] = cv[k];
    __syncthreads();
    for (int s2 = 128; s2 > 0; s2 >>= 1) {
        if (t < s2)
            for (int k = 0; k < 9; ++k) red[t][k] += red[t + s2][k];
        __syncthreads();
    }
    if (t == 0) for (int k = 0; k < 9; ++k) s_cov[k] = red[0][k];
    __syncthreads();

    if (t == 0) {
        double cov[3][3];
        for (int i = 0; i < 3; ++i)
            for (int j = 0; j < 3; ++j) cov[i][j] = (double)s_cov[i * 3 + j];
        double S[3][3];
        for (int a = 0; a < 3; ++a)
            for (int bb = 0; bb < 3; ++bb) S[a][bb] = cov[bb][a];
        double N4[4][4];
        N4[0][0] = S[0][0] + S[1][1] + S[2][2];
        N4[0][1] = S[1][2] - S[2][1];
        N4[0][2] = S[2][0] - S[0][2];
        N4[0][3] = S[0][1] - S[1][0];
        N4[1][1] = S[0][0] - S[1][1] - S[2][2];
        N4[1][2] = S[0][1] + S[1][0];
        N4[1][3] = S[2][0] + S[0][2];
        N4[2][2] = -S[0][0] + S[1][1] - S[2][2];
        N4[2][3] = S[1][2] + S[2][1];
        N4[3][3] = -S[0][0] - S[1][1] + S[2][2];
        N4[1][0] = N4[0][1]; N4[2][0] = N4[0][2]; N4[3][0] = N4[0][3];
        N4[2][1] = N4[1][2]; N4[3][1] = N4[1][3]; N4[3][2] = N4[2][3];
        double V[4][4];
        jacobi4(N4, V);
        int best = 0; double bl = N4[0][0];
        for (int k = 1; k < 4; ++k) if (N4[k][k] > bl) { bl = N4[k][k]; best = k; }
        double q0 = V[0][best], qx = V[1][best], qy = V[2][best], qz = V[3][best];
        double nq = sqrt(q0 * q0 + qx * qx + qy * qy + qz * qz);
        q0 /= nq; qx /= nq; qy /= nq; qz /= nq;
        double Rm[3][3];
        Rm[0][0] = q0*q0 + qx*qx - qy*qy - qz*qz;
        Rm[0][1] = 2.0 * (qx*qy - q0*qz);
        Rm[0][2] = 2.0 * (qx*qz + q0*qy);
        Rm[1][0] = 2.0 * (qx*qy + q0*qz);
        Rm[1][1] = q0*q0 - qx*qx + qy*qy - qz*qz;
        Rm[1][2] = 2.0 * (qy*qz - q0*qx);
        Rm[2][0] = 2.0 * (qx*qz - q0*qy);
        Rm[2][1] = 2.0 * (qy*qz + q0*qx);
        Rm[2][2] = q0*q0 - qx*qx - qy*qy + qz*qz;
        double o1 = 0, o2 = 0;
        for (int i = 0; i < 3; ++i)
            for (int j = 0; j < 3; ++j) { o1 += Rm[i][j] * cov[i][j]; o2 += Rm[j][i] * cov[i][j]; }
        if (o2 > o1) {
            for (int i = 0; i < 3; ++i)
                for (int j = i + 1; j < 3; ++j) {
                    double tv = Rm[i][j]; Rm[i][j] = Rm[j][i]; Rm[j][i] = tv;
                }
        }
        float Rf[3][3];
        for (int i = 0; i < 3; ++i)
            for (int j = 0; j < 3; ++j) {
                Rf[i][j] = (float)Rm[i][j];
                outR[(size_t)b * 9 + i * 3 + j] = Rf[i][j];
            }
        float rm[3];
        float mxv[3] = {mx0, mx1, mx2};
        float myv[3] = {my0, my1, my2};
        for (int i = 0; i < 3; ++i)
            rm[i] = Rf[i][0] * mxv[0] + Rf[i][1] * mxv[1] + Rf[i][2] * mxv[2];
        for (int i = 0; i < 3; ++i)
            for (int j = 0; j < 3; ++j)
                outT[(size_t)b * 9 + i * 3 + j] = myv[j] - rm[i];
    }
}

// ===========================================================================
extern "C" void kernel_launch(void* const* d_in, const int* in_sizes, int n_in,
                              void* d_out, int out_size, void* d_ws, size_t ws_size,
                              hipStream_t stream)
{
    const float* se  = (const float*)d_in[0];
    const float* te  = (const float*)d_in[1];
    const float* src = (const float*)d_in[2];
    const float* tgt = (const float*)d_in[3];

    float* out  = (float*)d_out;
    float* outR = out;
    float* outT = out + 72;
    float* outC = out + 144;
    float* outW = out + 144 + BATCH * NPTS;

    char* wsb = (char*)d_ws;
    float* corr_tgt  = (float*)wsb;                                    // 196608 B
    int*   corres_i  = (int*)(wsb + 196608);                           // 65536 B
    float* mean_loss = (float*)(wsb + 262144);                         // 65536 B
    float* part      = (float*)(wsb + 327680);                         // 4 MB (fallback only)

    float4* P4   = (float4*)(wsb + 327680);                            // 262144 B
    int*    topI = (int*)(wsb + 589824);                               // 655360 B

    const size_t PLANES_OFF = 4521984;
    const size_t PL_BYTES   = (size_t)3 * BATCH * NPTS * DIM * 2;      // 50331648
    const size_t NEED       = PLANES_OFF + 2 * PL_BYTES;               // 105185280
    const size_t UHAT_BYTES = (size_t)BATCH * NPTS * NPTS * 2;         // 67108864
    const size_t NEED2      = NEED + UHAT_BYTES;                       // 172294144

    unsigned short* pA = (unsigned short*)(wsb + PLANES_OFF);
    unsigned short* pB = (unsigned short*)(wsb + PLANES_OFF + PL_BYTES);
    unsigned short* uhat = (unsigned short*)(wsb + NEED);

    hipLaunchKernelGGL(split_kernel, dim3(4096), dim3(256), 0, stream, se, te, pA, pB);
    if (ws_size >= NEED2) {
        hipLaunchKernelGGL(score_h, dim3(512), dim3(256), 0, stream, pA, pB, uhat);
        hipLaunchKernelGGL(resolve, dim3(BATCH * NPTS / 4), dim3(256), 0, stream,
                           uhat, pA, pB, tgt, corr_tgt, corres_i, outC);
    } else {
        hipLaunchKernelGGL(score_mfma, dim3(512), dim3(256), 0, stream, pA, pB, tgt, part);
        hipLaunchKernelGGL(merge8_kernel, dim3(BATCH * NPTS / 256), dim3(256), 0, stream,
                           part, corr_tgt, corres_i, outC);
    }
    hipLaunchKernelGGL(prep_p4, dim3(BATCH * NPTS / 256), dim3(256), 0, stream, src, P4);
    hipLaunchKernelGGL(knn_topk, dim3(BATCH * 128), dim3(256), 0, stream, P4, topI);
    hipLaunchKernelGGL(gfm_finish, dim3(BATCH * NPTS / 4), dim3(256), 0, stream,
                       P4, corr_tgt, topI, mean_loss);
    hipLaunchKernelGGL(weight_kernel, dim3(BATCH), dim3(256), 0, stream,
                       mean_loss, outW);
    hipLaunchKernelGGL(procrustes_kernel, dim3(BATCH), dim3(256), 0, stream,
                       src, tgt, corres_i, outW, outR, outT);
}

// Round 15
// 262.668 us; speedup vs baseline: 1.3286x; 1.0742x over previous
//
#include <hip/hip_runtime.h>
#include <math.h>

#define BATCH 8
#define DIM   512
#define NPTS  2048
#define KNN   10
#define NPAIR 45
#define FCHK   32
#define FCHKSZ 64

typedef __attribute__((ext_vector_type(8))) short    bf16x8;
typedef __attribute__((ext_vector_type(4))) float    f32x4;
typedef __attribute__((ext_vector_type(4))) unsigned int u32x4;

__device__ inline unsigned short bf16_rne(float x) {
    unsigned int u = __float_as_uint(x);
    u += 0x7FFFu + ((u >> 16) & 1u);
    return (unsigned short)(u >> 16);
}
__device__ inline float bf16_to_f(unsigned short h) {
    return __uint_as_float(((unsigned int)h) << 16);
}
__device__ inline unsigned long long shflx_u64(unsigned long long v, int mask) {
    unsigned int lo = (unsigned int)v, hi = (unsigned int)(v >> 32);
    lo = (unsigned int)__shfl_xor((int)lo, mask);
    hi = (unsigned int)__shfl_xor((int)hi, mask);
    return ((unsigned long long)hi << 32) | lo;
}

// ===========================================================================
// Kernel S: split se/te into 3 bf16 planes (h,m,l), transposed to [b][n][d].
// ===========================================================================
__global__ __launch_bounds__(256)
void split_kernel(const float* __restrict__ se, const float* __restrict__ te,
                  unsigned short* __restrict__ pA, unsigned short* __restrict__ pB)
{
    const int bid = blockIdx.x;
    const int tensor = bid >> 11;
    const int rr_ = bid & 2047;
    const int b  = rr_ >> 8;
    const int dt = (rr_ >> 5) & 7;
    const int nt = rr_ & 31;
    const float* srcp = (tensor == 0 ? se : te)
                        + ((size_t)b * DIM + dt * 64) * NPTS + nt * 64;
    unsigned short* dst = (tensor == 0 ? pA : pB);
    const size_t PL = (size_t)BATCH * NPTS * DIM;
    unsigned short* base = dst + (size_t)b * NPTS * DIM + (size_t)nt * 64 * DIM + dt * 64;

    __shared__ float T[64][65];
    const int t = threadIdx.x;
    {
        int r = t >> 4, c4 = t & 15;
        #pragma unroll
        for (int it = 0; it < 4; ++it) {
            int d = r + it * 16;
            float4 v = *(const float4*)&srcp[(size_t)d * NPTS + c4 * 4];
            T[d][c4 * 4 + 0] = v.x; T[d][c4 * 4 + 1] = v.y;
            T[d][c4 * 4 + 2] = v.z; T[d][c4 * 4 + 3] = v.w;
        }
    }
    __syncthreads();
    const int n  = t >> 2;
    const int d0 = (t & 3) * 16;
    unsigned short hh[16], mm[16], ll[16];
    #pragma unroll
    for (int j = 0; j < 16; ++j) {
        float a = T[d0 + j][n];
        unsigned short h = bf16_rne(a);
        float r1 = a - bf16_to_f(h);
        unsigned short m = bf16_rne(r1);
        float r2 = r1 - bf16_to_f(m);
        unsigned short l = bf16_rne(r2);
        hh[j] = h; mm[j] = m; ll[j] = l;
    }
    unsigned short* o = base + (size_t)n * DIM + d0;
    *(u32x4*)(o)            = *(u32x4*)&hh[0];
    *(u32x4*)(o + 8)        = *(u32x4*)&hh[8];
    *(u32x4*)(o + PL)       = *(u32x4*)&mm[0];
    *(u32x4*)(o + PL + 8)   = *(u32x4*)&mm[8];
    *(u32x4*)(o + 2*PL)     = *(u32x4*)&ll[0];
    *(u32x4*)(o + 2*PL + 8) = *(u32x4*)&ll[8];
}

// ===========================================================================
// Kernel H: phase-1 GEMM on h-planes only (K=512). Writes uhat (bf16 of
// 10000*dot_h/sqrt(512)) for ALL 2048x2048 per batch.
// ===========================================================================
__global__ __launch_bounds__(256, 2)
void score_h(const unsigned short* __restrict__ pA, const unsigned short* __restrict__ pB,
             unsigned short* __restrict__ uhat)
{
    const int bid  = blockIdx.x;
    const int xcd  = bid & 7;
    const int slot = bid >> 3;
    const int g    = xcd + 8 * (slot >> 4);
    const int ntile = slot & 15;
    const int b    = g >> 2;
    const int mc   = g & 3;
    const int n0 = ntile * 128;
    const int t  = threadIdx.x;
    const int w  = t >> 6;
    const int l  = t & 63;
    const int wn = w >> 1, wm = w & 1;
    const int l15 = l & 15, l4 = l >> 4;

    __shared__ unsigned short As[128 * 64];
    __shared__ unsigned short Bs[128 * 64];

    int srow[4], skg[4], ldsoff[4];
    #pragma unroll
    for (int qq = 0; qq < 4; ++qq) {
        int s = qq * 256 + t;
        int row = s >> 3, slt = s & 7;
        srow[qq] = row;
        skg[qq] = slt ^ (row & 7);
        ldsoff[qq] = row * 64 + slt * 8;
    }
    int aroff[4], arxor[4], broff[4], brxor[4];
    #pragma unroll
    for (int i = 0; i < 4; ++i) {
        int ar = wn * 64 + i * 16 + l15;
        aroff[i] = ar * 64; arxor[i] = ar & 7;
        int br = wm * 64 + i * 16 + l15;
        broff[i] = br * 64; brxor[i] = br & 7;
    }

    const float scl = 10000.0f / sqrtf((float)DIM);
    const unsigned short* Ab = pA + (size_t)b * NPTS * DIM;
    const unsigned short* Bb = pB + (size_t)b * NPTS * DIM;

    for (int mt = 0; mt < 4; ++mt) {
        const int m0 = mc * 512 + mt * 128;
        f32x4 acc[4][4];
        #pragma unroll
        for (int i = 0; i < 4; ++i)
            #pragma unroll
            for (int j = 0; j < 4; ++j) acc[i][j] = (f32x4){0.f, 0.f, 0.f, 0.f};

        for (int k0 = 0; k0 < 512; k0 += 64) {
            __syncthreads();
            bf16x8 ra[4], rb[4];
            #pragma unroll
            for (int qq = 0; qq < 4; ++qq) {
                ra[qq] = *(const bf16x8*)&Ab[(size_t)(n0 + srow[qq]) * DIM + k0 + skg[qq] * 8];
                rb[qq] = *(const bf16x8*)&Bb[(size_t)(m0 + srow[qq]) * DIM + k0 + skg[qq] * 8];
            }
            #pragma unroll
            for (int qq = 0; qq < 4; ++qq) {
                *(bf16x8*)&As[ldsoff[qq]] = ra[qq];
                *(bf16x8*)&Bs[ldsoff[qq]] = rb[qq];
            }
            __syncthreads();
            #pragma unroll
            for (int ks = 0; ks < 2; ++ks) {
                bf16x8 af[4], bfr[4];
                #pragma unroll
                for (int i = 0; i < 4; ++i) {
                    af[i]  = *(const bf16x8*)&As[aroff[i] + (((ks * 4 + l4) ^ arxor[i]) * 8)];
                    bfr[i] = *(const bf16x8*)&Bs[broff[i] + (((ks * 4 + l4) ^ brxor[i]) * 8)];
                }
                #pragma unroll
                for (int i = 0; i < 4; ++i)
                    #pragma unroll
                    for (int j = 0; j < 4; ++j)
                        acc[i][j] = __builtin_amdgcn_mfma_f32_16x16x32_bf16(af[i], bfr[j], acc[i][j], 0, 0, 0);
            }
        }
        #pragma unroll
        for (int i = 0; i < 4; ++i) {
            #pragma unroll
            for (int j = 0; j < 4; ++j) {
                int mcol = m0 + wm * 64 + j * 16 + l15;
                #pragma unroll
                for (int r = 0; r < 4; ++r) {
                    int nabs = n0 + wn * 64 + i * 16 + l4 * 4 + r;
                    uhat[((size_t)(b * NPTS + nabs)) * NPTS + mcol] =
                        bf16_rne(scl * acc[i][j][r]);
                }
            }
        }
    }
}

// ===========================================================================
// Kernel R: resolve. One wave per row. Fast path register-only; slow path
// wave-parallel exact 26-bit rescore.
// ===========================================================================
__global__ __launch_bounds__(256)
void resolve(const unsigned short* __restrict__ uhat,
             const unsigned short* __restrict__ pA, const unsigned short* __restrict__ pB,
             const float* __restrict__ tgt,
             float* __restrict__ corr_tgt, int* __restrict__ corres_i,
             float* __restrict__ corres_out)
{
    const int wid  = threadIdx.x >> 6;
    const int lane = threadIdx.x & 63;
    const int gid  = blockIdx.x * 4 + wid;
    const int b    = gid >> 11;
    const int n    = gid & 2047;

    __shared__ int s_m[4][64];
    __shared__ int s_cnt[4];

    if (lane == 0) s_cnt[wid] = 0;
    __syncthreads();

    const unsigned short* urow = uhat + (size_t)gid * NPTS;
    float v[32];
    float lmax = -3.402823466e38f; int lk = 0;
    #pragma unroll
    for (int g2 = 0; g2 < 4; ++g2) {
        u32x4 pk = *(const u32x4*)&urow[lane * 32 + g2 * 8];
        #pragma unroll
        for (int e = 0; e < 4; ++e) {
            unsigned int w2 = pk[e];
            float f0 = __uint_as_float((w2 & 0xFFFFu) << 16);
            float f1 = __uint_as_float(w2 & 0xFFFF0000u);
            int k0 = g2 * 8 + e * 2;
            v[k0] = f0; v[k0 + 1] = f1;
            if (f0 > lmax) { lmax = f0; lk = k0; }
            if (f1 > lmax) { lmax = f1; lk = k0 + 1; }
        }
    }
    float vmax = lmax; int argm = lane * 32 + lk;
    #pragma unroll
    for (int mask = 1; mask < 64; mask <<= 1) {
        float ov = __shfl_xor(vmax, mask);
        int   oi = __shfl_xor(argm, mask);
        if (ov > vmax || (ov == vmax && oi < argm)) { vmax = ov; argm = oi; }
    }
    const float cut = vmax - 1200.0f;
    int cnt = 0;
    #pragma unroll
    for (int k = 0; k < 32; ++k) cnt += (v[k] >= cut) ? 1 : 0;
    int nc = cnt;
    #pragma unroll
    for (int mask = 1; mask < 64; mask <<= 1) nc += __shfl_xor(nc, mask);

    if (nc > 1) {
        #pragma unroll
        for (int k = 0; k < 32; ++k) {
            if (v[k] >= cut) {
                int slot = atomicAdd(&s_cnt[wid], 1);
                if (slot < 64) s_m[wid][slot] = lane * 32 + k;
            }
        }
    }
    __syncthreads();
    if (nc > 1 && lane == 0) {
        int ncc = nc > 64 ? 64 : nc;
        for (int i = 1; i < ncc; ++i) {
            int key = s_m[wid][i]; int j = i - 1;
            while (j >= 0 && s_m[wid][j] > key) { s_m[wid][j + 1] = s_m[wid][j]; --j; }
            s_m[wid][j + 1] = key;
        }
    }
    __syncthreads();

    if (nc == 1) {
        if (lane < 3) corr_tgt[(size_t)gid * 3 + lane] = tgt[((size_t)b * 3 + lane) * NPTS + argm];
        if (lane == 0) { corres_i[gid] = argm; corres_out[gid] = (float)argm; }
        return;
    }
    const int ncc = nc > 64 ? 64 : nc;

    const size_t PL = (size_t)BATCH * NPTS * DIM;
    const unsigned short* Ar = pA + ((size_t)b * NPTS + n) * DIM + lane * 8;
    bf16x8 a_h = *(const bf16x8*)&Ar[0];
    bf16x8 a_m = *(const bf16x8*)&Ar[PL];
    bf16x8 a_l = *(const bf16x8*)&Ar[2 * PL];
    float ah[8], am[8], al[8];
    #pragma unroll
    for (int e = 0; e < 8; ++e) {
        ah[e] = bf16_to_f((unsigned short)a_h[e]);
        am[e] = bf16_to_f((unsigned short)a_m[e]);
        al[e] = bf16_to_f((unsigned short)a_l[e]);
    }

    const float sqd = sqrtf((float)DIM);
    float umax = -3.402823466e38f; int uarg = 0x7fffffff;
    float myu = 0.f;
    for (int c = 0; c < ncc; ++c) {
        int mB = s_m[wid][c];
        const unsigned short* Br = pB + ((size_t)b * NPTS + mB) * DIM + lane * 8;
        bf16x8 b_h = *(const bf16x8*)&Br[0];
        bf16x8 b_m = *(const bf16x8*)&Br[PL];
        bf16x8 b_l = *(const bf16x8*)&Br[2 * PL];
        float part = 0.f;
        #pragma unroll
        for (int e = 0; e < 8; ++e) {
            float bh = bf16_to_f((unsigned short)b_h[e]);
            float bm = bf16_to_f((unsigned short)b_m[e]);
            float bl = bf16_to_f((unsigned short)b_l[e]);
            part += ah[e] * bh;
            part += ah[e] * bm;
            part += am[e] * bh;
            part += ah[e] * bl;
            part += am[e] * bm;
            part += al[e] * bh;
        }
        #pragma unroll
        for (int mask = 1; mask < 64; mask <<= 1) part += __shfl_xor(part, mask);
        float u = 10000.0f * (part / sqd);
        if (u > umax) { umax = u; uarg = mB; }
        if (lane == c) myu = u;
    }

    float p = (lane < ncc) ? expf(myu - umax) : 0.f;
    int myM = (lane < ncc) ? s_m[wid][lane] : 0;
    float tx = 0.f, ty = 0.f, tz = 0.f, ps = p;
    if (lane < ncc) {
        tx = p * tgt[((size_t)b * 3 + 0) * NPTS + myM];
        ty = p * tgt[((size_t)b * 3 + 1) * NPTS + myM];
        tz = p * tgt[((size_t)b * 3 + 2) * NPTS + myM];
    }
    #pragma unroll
    for (int mask = 1; mask < 64; mask <<= 1) {
        ps += __shfl_xor(ps, mask);
        tx += __shfl_xor(tx, mask);
        ty += __shfl_xor(ty, mask);
        tz += __shfl_xor(tz, mask);
    }
    if (lane == 0) {
        corr_tgt[(size_t)gid * 3 + 0] = tx / ps;
        corr_tgt[(size_t)gid * 3 + 1] = ty / ps;
        corr_tgt[(size_t)gid * 3 + 2] = tz / ps;
        corres_i[gid]   = uarg;
        corres_out[gid] = (float)uarg;
    }
}

// ===========================================================================
// FALLBACK Kernel A (round-8 proven): 6-product MFMA + fused online softmax
// ===========================================================================
__global__ __launch_bounds__(256, 2)
void score_mfma(const unsigned short* __restrict__ pA, const unsigned short* __restrict__ pB,
                const float* __restrict__ tgt, float* __restrict__ part)
{
    const int bid  = blockIdx.x;
    const int xcd  = bid & 7;
    const int slot = bid >> 3;
    const int g    = xcd + 8 * (slot >> 4);
    const int ntile = slot & 15;
    const int b    = g >> 2;
    const int mc   = g & 3;
    const int n0 = ntile * 128;
    const int t  = threadIdx.x;
    const int w  = t >> 6;
    const int l  = t & 63;
    const int wn = w >> 1, wm = w & 1;
    const int l15 = l & 15, l4 = l >> 4;

    __shared__ unsigned short As[128 * 64];
    __shared__ unsigned short Bs[128 * 64];

    const size_t PL = (size_t)BATCH * NPTS * DIM;

    int srow[4], skg[4], ldsoff[4];
    #pragma unroll
    for (int qq = 0; qq < 4; ++qq) {
        int s = qq * 256 + t;
        int row = s >> 3, slt = s & 7;
        srow[qq] = row;
        skg[qq] = slt ^ (row & 7);
        ldsoff[qq] = row * 64 + slt * 8;
    }
    int aroff[4], arxor[4], broff[4], brxor[4];
    #pragma unroll
    for (int i = 0; i < 4; ++i) {
        int ar = wn * 64 + i * 16 + l15;
        aroff[i] = ar * 64; arxor[i] = ar & 7;
        int br = wm * 64 + i * 16 + l15;
        broff[i] = br * 64; brxor[i] = br & 7;
    }

    float mx[16], sm[16], ax[16], ay[16], az[16]; int ag[16];
    #pragma unroll
    for (int si = 0; si < 16; ++si) {
        mx[si] = -3.402823466e38f; sm[si] = 0.f;
        ax[si] = 0.f; ay[si] = 0.f; az[si] = 0.f; ag[si] = 0;
    }

    const float sqd = sqrtf((float)DIM);
    const unsigned short* Ab = pA + (size_t)b * NPTS * DIM;
    const unsigned short* Bb = pB + (size_t)b * NPTS * DIM;
    const int AIDX[6] = {0, 0, 1, 0, 1, 2};
    const int BIDX[6] = {0, 1, 0, 2, 1, 0};

    for (int mt = 0; mt < 4; ++mt) {
        const int m0 = mc * 512 + mt * 128;
        f32x4 acc[4][4];
        #pragma unroll
        for (int i = 0; i < 4; ++i)
            #pragma unroll
            for (int j = 0; j < 4; ++j) acc[i][j] = (f32x4){0.f, 0.f, 0.f, 0.f};

        for (int q = 0; q < 6; ++q) {
            const unsigned short* Ap = Ab + (size_t)AIDX[q] * PL;
            const unsigned short* Bp = Bb + (size_t)BIDX[q] * PL;
            for (int k0 = 0; k0 < 512; k0 += 64) {
                __syncthreads();
                bf16x8 ra[4], rb[4];
                #pragma unroll
                for (int qq = 0; qq < 4; ++qq) {
                    ra[qq] = *(const bf16x8*)&Ap[(size_t)(n0 + srow[qq]) * DIM + k0 + skg[qq] * 8];
                    rb[qq] = *(const bf16x8*)&Bp[(size_t)(m0 + srow[qq]) * DIM + k0 + skg[qq] * 8];
                }
                #pragma unroll
                for (int qq = 0; qq < 4; ++qq) {
                    *(bf16x8*)&As[ldsoff[qq]] = ra[qq];
                    *(bf16x8*)&Bs[ldsoff[qq]] = rb[qq];
                }
                __syncthreads();
                #pragma unroll
                for (int ks = 0; ks < 2; ++ks) {
                    bf16x8 af[4], bfr[4];
                    #pragma unroll
                    for (int i = 0; i < 4; ++i) {
                        af[i]  = *(const bf16x8*)&As[aroff[i] + (((ks * 4 + l4) ^ arxor[i]) * 8)];
                        bfr[i] = *(const bf16x8*)&Bs[broff[i] + (((ks * 4 + l4) ^ brxor[i]) * 8)];
                    }
                    #pragma unroll
                    for (int i = 0; i < 4; ++i)
                        #pragma unroll
                        for (int j = 0; j < 4; ++j)
                            acc[i][j] = __builtin_amdgcn_mfma_f32_16x16x32_bf16(af[i], bfr[j], acc[i][j], 0, 0, 0);
                }
            }
        }
        float tg0[4], tg1[4], tg2[4];
        #pragma unroll
        for (int j = 0; j < 4; ++j) {
            int mcol = m0 + wm * 64 + j * 16 + l15;
            tg0[j] = tgt[((size_t)b * 3 + 0) * NPTS + mcol];
            tg1[j] = tgt[((size_t)b * 3 + 1) * NPTS + mcol];
            tg2[j] = tgt[((size_t)b * 3 + 2) * NPTS + mcol];
        }
        #pragma unroll
        for (int i = 0; i < 4; ++i) {
            #pragma unroll
            for (int r = 0; r < 4; ++r) {
                const int si = i * 4 + r;
                float u[4];
                float lm = -3.402823466e38f; int la = 0;
                #pragma unroll
                for (int j = 0; j < 4; ++j) {
                    float s  = acc[i][j][r] / sqd;
                    float uu = 10000.0f * s;
                    u[j] = uu;
                    if (uu > lm) { lm = uu; la = m0 + wm * 64 + j * 16 + l15; }
                }
                float nm = fmaxf(mx[si], lm);
                if (lm > mx[si]) ag[si] = la;
                float f = expf(mx[si] - nm);
                mx[si] = nm;
                float s_ = sm[si] * f, x_ = ax[si] * f, y_ = ay[si] * f, z_ = az[si] * f;
                #pragma unroll
                for (int j = 0; j < 4; ++j) {
                    float p = expf(u[j] - nm);
                    s_ += p; x_ += p * tg0[j]; y_ += p * tg1[j]; z_ += p * tg2[j];
                }
                sm[si] = s_; ax[si] = x_; ay[si] = y_; az[si] = z_;
            }
        }
    }

    #pragma unroll
    for (int si = 0; si < 16; ++si) {
        for (int mask = 1; mask < 16; mask <<= 1) {
            float omx = __shfl_xor(mx[si], mask);
            float osm = __shfl_xor(sm[si], mask);
            float oax = __shfl_xor(ax[si], mask);
            float oay = __shfl_xor(ay[si], mask);
            float oaz = __shfl_xor(az[si], mask);
            int   oag = __shfl_xor(ag[si], mask);
            float nm = fmaxf(mx[si], omx);
            float f1 = expf(mx[si] - nm), f2 = expf(omx - nm);
            sm[si] = sm[si] * f1 + osm * f2;
            ax[si] = ax[si] * f1 + oax * f2;
            ay[si] = ay[si] * f1 + oay * f2;
            az[si] = az[si] * f1 + oaz * f2;
            ag[si] = (omx > mx[si]) ? oag : ((omx == mx[si]) ? min(ag[si], oag) : ag[si]);
            mx[si] = nm;
        }
    }
    if (l15 == 0) {
        const int chunk = mc * 2 + wm;
        #pragma unroll
        for (int i = 0; i < 4; ++i)
            #pragma unroll
            for (int r = 0; r < 4; ++r) {
                const int si = i * 4 + r;
                int nabs = n0 + wn * 64 + i * 16 + l4 * 4 + r;
                size_t o = (((size_t)b * NPTS + nabs) * 8 + chunk) * 8;
                part[o + 0] = mx[si]; part[o + 1] = sm[si];
                part[o + 2] = ax[si]; part[o + 3] = ay[si]; part[o + 4] = az[si];
                part[o + 5] = __int_as_float(ag[si]);
            }
    }
}

__global__ __launch_bounds__(256)
void merge8_kernel(const float* __restrict__ part, float* __restrict__ corr_tgt,
                   int* __restrict__ corres_i, float* __restrict__ corres_out)
{
    int r = blockIdx.x * 256 + threadIdx.x;
    float m = -3.402823466e38f, s = 0.f, x = 0.f, y = 0.f, z = 0.f; int a = 0x7fffffff;
    for (int c = 0; c < 8; ++c) {
        const float* p = &part[((size_t)r * 8 + c) * 8];
        float pm = p[0]; int pa = __float_as_int(p[5]);
        float nm = fmaxf(m, pm);
        float f1 = expf(m - nm), f2 = expf(pm - nm);
        s = s * f1 + p[1] * f2;
        x = x * f1 + p[2] * f2;
        y = y * f1 + p[3] * f2;
        z = z * f1 + p[4] * f2;
        if (pm > m) a = pa; else if (pm == m) a = min(a, pa);
        m = nm;
    }
    corr_tgt[(size_t)r * 3 + 0] = x / s;
    corr_tgt[(size_t)r * 3 + 1] = y / s;
    corr_tgt[(size_t)r * 3 + 2] = z / s;
    corres_i[r]   = a;
    corres_out[r] = (float)a;
}

// ===========================================================================
// Kernel B0: P4 = (x,y,z,|p|^2) per source point
// ===========================================================================
__global__ __launch_bounds__(256)
void prep_p4(const float* __restrict__ src, float4* __restrict__ P4)
{
    int i = blockIdx.x * 256 + threadIdx.x;
    int b = i >> 11, m = i & 2047;
    float x = src[((size_t)b * 3 + 0) * NPTS + m];
    float y = src[((size_t)b * 3 + 1) * NPTS + m];
    float z = src[((size_t)b * 3 + 2) * NPTS + m];
    P4[i] = make_float4(x, y, z, x * x + y * y + z * z);
}

// ===========================================================================
// Kernel B1 (FUSED v3): 32 chunks x 64 pts; scan with 32-bit keys (~bits(w))
// + separate idx (strict < keeps first-seen = lower idx, identical to u64
// ordering); butterfly shuffle merge on packed u64 (key32<<32|idx).
// grid 2048 blocks = 8/CU = 100% occupancy.
// ===========================================================================
__global__ __launch_bounds__(256)
void knn_topk(const float4* __restrict__ P4, int* __restrict__ topI)
{
    const int bid = blockIdx.x;                    // 0..2047
    const int b = bid >> 8, nblk = bid & 255;      // 256 blocks/batch, 8 rows each
    const int t = threadIdx.x;
    const int c  = t & (FCHK - 1);                 // chunk 0..31 (lane%32)
    const int rl = t >> 5;                         // row-in-block 0..7
    const int n = nblk * 8 + rl;
    const float4* Pb = P4 + (size_t)b * NPTS;
    const float4 pn = Pb[n];

    unsigned int kx[KNN], ix[KNN];
    #pragma unroll
    for (int k = 0; k < KNN; ++k) { kx[k] = 0xFFFFFFFFu; ix[k] = 0xFFFFFFFFu; }

    const int m0 = c * FCHKSZ;
    for (int mm = 0; mm < FCHKSZ; ++mm) {
        int m = m0 + mm;
        float4 pm = Pb[m];
        float dot = pn.x * pm.x + pn.y * pm.y + pn.z * pm.z;
        float d2  = (pn.w + pm.w) - 2.0f * dot;
        if (d2 < 0.f) d2 = 0.f;
        float w = expf(-d2 * 0.5f);
        unsigned int key = ~__float_as_uint(w);
        if (key < kx[KNN - 1]) {
            unsigned int ck = key, ci = (unsigned int)m;
            #pragma unroll
            for (int k = 0; k < KNN; ++k) {
                bool lt = ck < kx[k];
                unsigned int tk = kx[k], ti = ix[k];
                kx[k] = lt ? ck : kx[k];
                ix[k] = lt ? ci : ix[k];
                ck = lt ? tk : ck;
                ci = lt ? ti : ci;
            }
        }
    }

    unsigned long long kl[KNN];
    #pragma unroll
    for (int k = 0; k < KNN; ++k)
        kl[k] = ((unsigned long long)kx[k] << 32) | ix[k];

    // butterfly merge across the 32 chunk-lanes of this row
    #pragma unroll
    for (int mask = 1; mask < FCHK; mask <<= 1) {
        unsigned long long B[KNN];
        #pragma unroll
        for (int k = 0; k < KNN; ++k) B[k] = shflx_u64(kl[k], mask);
        unsigned long long M[KNN];
        #pragma unroll
        for (int k = 0; k < KNN; ++k) {
            unsigned long long best = B[k];                     // i = 0 term
            #pragma unroll
            for (int i = 1; i <= k; ++i) {
                unsigned long long hi = kl[i - 1] > B[k - i] ? kl[i - 1] : B[k - i];
                best = hi < best ? hi : best;
            }
            unsigned long long ak = kl[k];                      // i = k+1 term
            M[k] = ak < best ? ak : best;
        }
        #pragma unroll
        for (int k = 0; k < KNN; ++k) kl[k] = M[k];
    }

    if (c == 0) {
        size_t gid = (size_t)(b << 11) + n;
        #pragma unroll
        for (int k = 0; k < KNN; ++k)
            topI[gid * KNN + k] = (int)(kl[k] & 0xFFFFFFFFull);
    }
}

// ===========================================================================
// Kernel B2: wave-per-n GFM finish (4096 blocks x 4 waves)
// ===========================================================================
__global__ __launch_bounds__(256)
void gfm_finish(const float4* __restrict__ P4, const float* __restrict__ corr_tgt,
                const int* __restrict__ topI, float* __restrict__ mean_loss)
{
    const int wid  = threadIdx.x >> 6;
    const int lane = threadIdx.x & 63;
    const int gid  = blockIdx.x * 4 + wid;
    const int b    = gid >> 11;

    __shared__ float PT[4][KNN][6];
    __shared__ float LS[4][48];
    __shared__ float SR[4][48];
    __shared__ float TOT[4][48];

    if (lane < KNN) {
        int idx = topI[(size_t)gid * KNN + lane];
        float4 pk = P4[(b << 11) + idx];
        size_t o = ((size_t)(b << 11) + idx) * 3;
        PT[wid][lane][0] = pk.x; PT[wid][lane][1] = pk.y; PT[wid][lane][2] = pk.z;
        PT[wid][lane][3] = corr_tgt[o];
        PT[wid][lane][4] = corr_tgt[o + 1];
        PT[wid][lane][5] = corr_tgt[o + 2];
    }
    float4 pn = P4[gid];
    size_t on = (size_t)gid * 3;
    const float cnx = corr_tgt[on], cny = corr_tgt[on + 1], cnz = corr_tgt[on + 2];
    __syncthreads();

    int pi = 0, pj = 1;
    {
        int pp = lane;
        #pragma unroll
        for (int r = 0; r < 9; ++r) {
            int cnt = 9 - r;
            if (pp >= 0 && pp < cnt) { pi = r; pj = r + 1 + pp; }
            pp -= cnt;
        }
    }

    float ls_p = 0.f, rg_p = 0.f;
    if (lane < NPAIR) {
        float e1x = PT[wid][pi][0] - pn.x, e1y = PT[wid][pi][1] - pn.y, e1z = PT[wid][pi][2] - pn.z;
        float e2x = PT[wid][pj][0] - pn.x, e2y = PT[wid][pj][1] - pn.y, e2z = PT[wid][pj][2] - pn.z;
        float cx = e1y * e2z - e1z * e2y;
        float cy = e1z * e2x - e1x * e2z;
        float cz = e1x * e2y - e1y * e2x;
        float as_ = 0.5f * sqrtf(cx * cx + cy * cy + cz * cz);
        float f1x = PT[wid][pi][3] - cnx, f1y = PT[wid][pi][4] - cny, f1z = PT[wid][pi][5] - cnz;
        float f2x = PT[wid][pj][3] - cnx, f2y = PT[wid][pj][4] - cny, f2z = PT[wid][pj][5] - cnz;
        float gx = f1y * f2z - f1z * f2y;
        float gy = f1z * f2x - f1x * f2z;
        float gz = f1x * f2y - f1y * f2x;
        float at_ = 0.5f * sqrtf(gx * gx + gy * gy + gz * gz);
        float tl2 = at_ + 1e-6f;
        float dd  = as_ - tl2;
        float e2_ = 1e-6f * 1e-6f;
        float num = (e2_ + e2_) + dd * dd;
        float den = (1e-6f + 1e-6f) + (as_ + tl2);
        ls_p = num / den;
        rg_p = sqrtf(num);
        LS[wid][lane] = ls_p;
    }
    __syncthreads();

    int rk = 0;
    if (lane < NPAIR) {
        #pragma unroll
        for (int q = 0; q < NPAIR; ++q) {
            float lq = LS[wid][q];
            rk += (lq < ls_p) || (lq == ls_p && q < lane);
        }
        SR[wid][rk] = ls_p;
    }
    __syncthreads();

    float tot_p = 0.f;
    if (lane < NPAIR) {
        tot_p = SR[wid][lane] + 0.1f * rg_p;
        TOT[wid][lane] = tot_p;
    }
    __syncthreads();

    int rt2 = 0;
    if (lane < NPAIR) {
        #pragma unroll
        for (int q = 0; q < NPAIR; ++q) {
            float tq = TOT[wid][q];
            rt2 += (tq < tot_p) || (tq == tot_p && q < lane);
        }
        SR[wid][rt2] = tot_p;
    }
    __syncthreads();

    float med = SR[wid][22];
    float thr = 3.0f * med;
    if (lane < KNN) {
        float v = tot_p;
        v = (v > thr) ? 0.0f : v;
        LS[wid][lane] = sqrtf(v + 1e-6f);
    }
    __syncthreads();
    if (lane == 0) {
        float acc = 0.f;
        #pragma unroll
        for (int k = 0; k < KNN; ++k) acc += LS[wid][k];
        mean_loss[gid] = acc / 10.0f;
    }
}

// ===========================================================================
// Kernel C: per-batch min + binary weight
// ===========================================================================
__global__ __launch_bounds__(256)
void weight_kernel(const float* __restrict__ mean_loss, float* __restrict__ weight_out)
{
    const int b = blockIdx.x;
    const int t = threadIdx.x;
    __shared__ float red[256];
    float mn = 3.402823466e38f;
    for (int i = t; i < NPTS; i += 256)
        mn = fminf(mn, mean_loss[(size_t)b * NPTS + i]);
    red[t] = mn; __syncthreads();
    for (int s2 = 128; s2 > 0; s2 >>= 1) {
        if (t < s2) red[t] = fminf(red[t], red[t + s2]);
        __syncthreads();
    }
    float ml = red[0];
    for (int i = t; i < NPTS; i += 256) {
        float d = mean_loss[(size_t)b * NPTS + i] - ml;
        float e = expf(-20.0f * d);
        float wts = 2.0f * (e / (1.0f + e));
        weight_out[(size_t)b * NPTS + i] = (wts > 0.5f) ? 1.0f : 0.0f;
    }
}

// ===========================================================================
// Kernel D: weighted Procrustes per batch (Horn quaternion)
// ===========================================================================
__device__ void jacobi4(double A[4][4], double V[4][4]) {
    for (int i = 0; i < 4; ++i)
        for (int j = 0; j < 4; ++j) V[i][j] = (i == j) ? 1.0 : 0.0;
    for (int sweep = 0; sweep < 12; ++sweep) {
        for (int p = 0; p < 3; ++p) for (int q = p + 1; q < 4; ++q) {
            double apq = A[p][q];
            if (fabs(apq) < 1e-30) continue;
            double theta = (A[q][q] - A[p][p]) / (2.0 * apq);
            double tt = (theta >= 0 ? 1.0 : -1.0) / (fabs(theta) + sqrt(theta * theta + 1.0));
            double c = 1.0 / sqrt(tt * tt + 1.0), s = tt * c;
            for (int k = 0; k < 4; ++k) {
                double akp = A[k][p], akq = A[k][q];
                A[k][p] = c * akp - s * akq;
                A[k][q] = s * akp + c * akq;
            }
            for (int k = 0; k < 4; ++k) {
                double apk = A[p][k], aqk = A[q][k];
                A[p][k] = c * apk - s * aqk;
                A[q][k] = s * apk + c * aqk;
            }
            for (int k = 0; k < 4; ++k) {
                double vkp = V[k][p], vkq = V[k][q];
                V[k][p] = c * vkp - s * vkq;
                V[k][q] = s * vkp + c * vkq;
            }
        }
    }
}

__global__ __launch_bounds__(256)
void procrustes_kernel(const float* __restrict__ src, const float* __restrict__ tgt,
                       const int* __restrict__ corres_i, const float* __restrict__ weight,
                       float* __restrict__ outR, float* __restrict__ outT)
{
    const int b = blockIdx.x;
    const int t = threadIdx.x;
    __shared__ float red[256][9];
    __shared__ float s_tw, s_mx[3], s_my[3];
    __shared__ float s_cov[9];

    float a0 = 0, a1 = 0, a2 = 0, a3 = 0, a4 = 0, a5 = 0, a6 = 0;
    for (int i = t; i < NPTS; i += 256) {
        float w = weight[(size_t)b * NPTS + i];
        float X0 = src[((size_t)b * 3 + 0) * NPTS + i];
        float X1 = src[((size_t)b * 3 + 1) * NPTS + i];
        float X2 = src[((size_t)b * 3 + 2) * NPTS + i];
        int c = corres_i[(size_t)b * NPTS + i];
        float Y0 = tgt[((size_t)b * 3 + 0) * NPTS + c];
        float Y1 = tgt[((size_t)b * 3 + 1) * NPTS + c];
        float Y2 = tgt[((size_t)b * 3 + 2) * NPTS + c];
        a0 += w;
        a1 += w * X0; a2 += w * X1; a3 += w * X2;
        a4 += w * Y0; a5 += w * Y1; a6 += w * Y2;
    }
    red[t][0] = a0; red[t][1] = a1; red[t][2] = a2; red[t][3] = a3;
    red[t][4] = a4; red[t][5] = a5; red[t][6] = a6; red[t][7] = 0; red[t][8] = 0;
    __syncthreads();
    for (int s2 = 128; s2 > 0; s2 >>= 1) {
        if (t < s2)
            for (int k = 0; k < 7; ++k) red[t][k] += red[t + s2][k];
        __syncthreads();
    }
    if (t == 0) {
        float tw = red[0][0];
        float itw = tw + 1e-7f;
        s_tw = tw;
        s_mx[0] = red[0][1] / itw; s_mx[1] = red[0][2] / itw; s_mx[2] = red[0][3] / itw;
        s_my[0] = red[0][4] / itw; s_my[1] = red[0][5] / itw; s_my[2] = red[0][6] / itw;
    }
    __syncthreads();
    const float twp = s_tw + 1e-7f;
    const float mx0 = s_mx[0], mx1 = s_mx[1], mx2 = s_mx[2];
    const float my0 = s_my[0], my1 = s_my[1], my2 = s_my[2];

    float cv[9] = {0,0,0,0,0,0,0,0,0};
    for (int i = t; i < NPTS; i += 256) {
        float w = weight[(size_t)b * NPTS + i];
        float nwn = w / twp;
        float X0 = src[((size_t)b * 3 + 0) * NPTS + i] - mx0;
        float X1 = src[((size_t)b * 3 + 1) * NPTS + i] - mx1;
        float X2 = src[((size_t)b * 3 + 2) * NPTS + i] - mx2;
        int c = corres_i[(size_t)b * NPTS + i];
        float Y0 = tgt[((size_t)b * 3 + 0) * NPTS + c] - my0;
        float Y1 = tgt[((size_t)b * 3 + 1) * NPTS + c] - my1;
        float Y2 = tgt[((size_t)b * 3 + 2) * NPTS + c] - my2;
        float b0 = nwn * X0, b1 = nwn * X1, b2 = nwn * X2;
        cv[0] += Y0 * b0; cv[1] += Y0 * b1; cv[2] += Y0 * b2;
        cv[3] += Y1 * b0; cv[4] += Y1 * b1; cv[5] += Y1 * b2;
        cv[6] += Y2 * b0; cv[7] += Y2 * b1; cv[8] += Y2 * b2;
    }
    __syncthreads();
    for (int k = 0; k < 9; ++k) red[t][k] = cv[k];
    __syncthreads();
    for (int s2 = 128; s2 > 0; s2 >>= 1) {
        if (t < s2)
            for (int k = 0; k < 9; ++k) red[t][k] += red[t + s2][k];
        __syncthreads();
    }
    if (t == 0) for (int k = 0; k < 9; ++k) s_cov[k] = red[0][k];
    __syncthreads();

    if (t == 0) {
        double cov[3][3];
        for (int i = 0; i < 3; ++i)
            for (int j = 0; j < 3; ++j) cov[i][j] = (double)s_cov[i * 3 + j];
        double S[3][3];
        for (int a = 0; a < 3; ++a)
            for (int bb = 0; bb < 3; ++bb) S[a][bb] = cov[bb][a];
        double N4[4][4];
        N4[0][0] = S[0][0] + S[1][1] + S[2][2];
        N4[0][1] = S[1][2] - S[2][1];
        N4[0][2] = S[2][0] - S[0][2];
        N4[0][3] = S[0][1] - S[1][0];
        N4[1][1] = S[0][0] - S[1][1] - S[2][2];
        N4[1][2] = S[0][1] + S[1][0];
        N4[1][3] = S[2][0] + S[0][2];
        N4[2][2] = -S[0][0] + S[1][1] - S[2][2];
        N4[2][3] = S[1][2] + S[2][1];
        N4[3][3] = -S[0][0] - S[1][1] + S[2][2];
        N4[1][0] = N4[0][1]; N4[2][0] = N4[0][2]; N4[3][0] = N4[0][3];
        N4[2][1] = N4[1][2]; N4[3][1] = N4[1][3]; N4[3][2] = N4[2][3];
        double V[4][4];
        jacobi4(N4, V);
        int best = 0; double bl = N4[0][0];
        for (int k = 1; k < 4; ++k) if (N4[k][k] > bl) { bl = N4[k][k]; best = k; }
        double q0 = V[0][best], qx = V[1][best], qy = V[2][best], qz = V[3][best];
        double nq = sqrt(q0 * q0 + qx * qx + qy * qy + qz * qz);
        q0 /= nq; qx /= nq; qy /= nq; qz /= nq;
        double Rm[3][3];
        Rm[0][0] = q0*q0 + qx*qx - qy*qy - qz*qz;
        Rm[0][1] = 2.0 * (qx*qy - q0*qz);
        Rm[0][2] = 2.0 * (qx*qz + q0*qy);
        Rm[1][0] = 2.0 * (qx*qy + q0*qz);
        Rm[1][1] = q0*q0 - qx*qx + qy*qy - qz*qz;
        Rm[1][2] = 2.0 * (qy*qz - q0*qx);
        Rm[2][0] = 2.0 * (qx*qz - q0*qy);
        Rm[2][1] = 2.0 * (qy*qz + q0*qx);
        Rm[2][2] = q0*q0 - qx*qx - qy*qy + qz*qz;
        double o1 = 0, o2 = 0;
        for (int i = 0; i < 3; ++i)
            for (int j = 0; j < 3; ++j) { o1 += Rm[i][j] * cov[i][j]; o2 += Rm[j][i] * cov[i][j]; }
        if (o2 > o1) {
            for (int i = 0; i < 3; ++i)
                for (int j = i + 1; j < 3; ++j) {
                    double tv = Rm[i][j]; Rm[i][j] = Rm[j][i]; Rm[j][i] = tv;
                }
        }
        float Rf[3][3];
        for (int i = 0; i < 3; ++i)
            for (int j = 0; j < 3; ++j) {
                Rf[i][j] = (float)Rm[i][j];
                outR[(size_t)b * 9 + i * 3 + j] = Rf[i][j];
            }
        float rm[3];
        float mxv[3] = {mx0, mx1, mx2};
        float myv[3] = {my0, my1, my2};
        for (int i = 0; i < 3; ++i)
            rm[i] = Rf[i][0] * mxv[0] + Rf[i][1] * mxv[1] + Rf[i][2] * mxv[2];
        for (int i = 0; i < 3; ++i)
            for (int j = 0; j < 3; ++j)
                outT[(size_t)b * 9 + i * 3 + j] = myv[j] - rm[i];
    }
}

// ===========================================================================
extern "C" void kernel_launch(void* const* d_in, const int* in_sizes, int n_in,
                              void* d_out, int out_size, void* d_ws, size_t ws_size,
                              hipStream_t stream)
{
    const float* se  = (const float*)d_in[0];
    const float* te  = (const float*)d_in[1];
    const float* src = (const float*)d_in[2];
    const float* tgt = (const float*)d_in[3];

    float* out  = (float*)d_out;
    float* outR = out;
    float* outT = out + 72;
    float* outC = out + 144;
    float* outW = out + 144 + BATCH * NPTS;

    char* wsb = (char*)d_ws;
    float* corr_tgt  = (float*)wsb;                                    // 196608 B
    int*   corres_i  = (int*)(wsb + 196608);                           // 65536 B
    float* mean_loss = (float*)(wsb + 262144);                         // 65536 B
    float* part      = (float*)(wsb + 327680);                         // 4 MB (fallback only)

    float4* P4   = (float4*)(wsb + 327680);                            // 262144 B
    int*    topI = (int*)(wsb + 589824);                               // 655360 B

    const size_t PLANES_OFF = 4521984;
    const size_t PL_BYTES   = (size_t)3 * BATCH * NPTS * DIM * 2;      // 50331648
    const size_t NEED       = PLANES_OFF + 2 * PL_BYTES;               // 105185280
    const size_t UHAT_BYTES = (size_t)BATCH * NPTS * NPTS * 2;         // 67108864
    const size_t NEED2      = NEED + UHAT_BYTES;                       // 172294144

    unsigned short* pA = (unsigned short*)(wsb + PLANES_OFF);
    unsigned short* pB = (unsigned short*)(wsb + PLANES_OFF + PL_BYTES);
    unsigned short* uhat = (unsigned short*)(wsb + NEED);

    hipLaunchKernelGGL(split_kernel, dim3(4096), dim3(256), 0, stream, se, te, pA, pB);
    if (ws_size >= NEED2) {
        hipLaunchKernelGGL(score_h, dim3(512), dim3(256), 0, stream, pA, pB, uhat);
        hipLaunchKernelGGL(resolve, dim3(BATCH * NPTS / 4), dim3(256), 0, stream,
                           uhat, pA, pB, tgt, corr_tgt, corres_i, outC);
    } else {
        hipLaunchKernelGGL(score_mfma, dim3(512), dim3(256), 0, stream, pA, pB, tgt, part);
        hipLaunchKernelGGL(merge8_kernel, dim3(BATCH * NPTS / 256), dim3(256), 0, stream,
                           part, corr_tgt, corres_i, outC);
    }
    hipLaunchKernelGGL(prep_p4, dim3(BATCH * NPTS / 256), dim3(256), 0, stream, src, P4);
    hipLaunchKernelGGL(knn_topk, dim3(BATCH * 256), dim3(256), 0, stream, P4, topI);
    hipLaunchKernelGGL(gfm_finish, dim3(BATCH * NPTS / 4), dim3(256), 0, stream,
                       P4, corr_tgt, topI, mean_loss);
    hipLaunchKernelGGL(weight_kernel, dim3(BATCH), dim3(256), 0, stream,
                       mean_loss, outW);
    hipLaunchKernelGGL(procrustes_kernel, dim3(BATCH), dim3(256), 0, stream,
                       src, tgt, corres_i, outW, outR, outT);
}

// Round 16
// 230.914 us; speedup vs baseline: 1.5113x; 1.1375x over previous
//
#include <hip/hip_runtime.h>
#include <math.h>

#define BATCH 8
#define DIM   512
#define NPTS  2048
#define KNN   10
#define NPAIR 45
#define KCAP  64

typedef __attribute__((ext_vector_type(8))) short    bf16x8;
typedef __attribute__((ext_vector_type(4))) float    f32x4;
typedef __attribute__((ext_vector_type(4))) unsigned int u32x4;

__device__ inline unsigned short bf16_rne(float x) {
    unsigned int u = __float_as_uint(x);
    u += 0x7FFFu + ((u >> 16) & 1u);
    return (unsigned short)(u >> 16);
}
__device__ inline float bf16_to_f(unsigned short h) {
    return __uint_as_float(((unsigned int)h) << 16);
}
__device__ inline unsigned long long shflx_u64(unsigned long long v, int mask) {
    unsigned int lo = (unsigned int)v, hi = (unsigned int)(v >> 32);
    lo = (unsigned int)__shfl_xor((int)lo, mask);
    hi = (unsigned int)__shfl_xor((int)hi, mask);
    return ((unsigned long long)hi << 32) | lo;
}

// ===========================================================================
// Kernel S: split se/te into 3 bf16 planes (h,m,l), transposed to [b][n][d].
// ===========================================================================
__global__ __launch_bounds__(256)
void split_kernel(const float* __restrict__ se, const float* __restrict__ te,
                  unsigned short* __restrict__ pA, unsigned short* __restrict__ pB)
{
    const int bid = blockIdx.x;
    const int tensor = bid >> 11;
    const int rr_ = bid & 2047;
    const int b  = rr_ >> 8;
    const int dt = (rr_ >> 5) & 7;
    const int nt = rr_ & 31;
    const float* srcp = (tensor == 0 ? se : te)
                        + ((size_t)b * DIM + dt * 64) * NPTS + nt * 64;
    unsigned short* dst = (tensor == 0 ? pA : pB);
    const size_t PL = (size_t)BATCH * NPTS * DIM;
    unsigned short* base = dst + (size_t)b * NPTS * DIM + (size_t)nt * 64 * DIM + dt * 64;

    __shared__ float T[64][65];
    const int t = threadIdx.x;
    {
        int r = t >> 4, c4 = t & 15;
        #pragma unroll
        for (int it = 0; it < 4; ++it) {
            int d = r + it * 16;
            float4 v = *(const float4*)&srcp[(size_t)d * NPTS + c4 * 4];
            T[d][c4 * 4 + 0] = v.x; T[d][c4 * 4 + 1] = v.y;
            T[d][c4 * 4 + 2] = v.z; T[d][c4 * 4 + 3] = v.w;
        }
    }
    __syncthreads();
    const int n  = t >> 2;
    const int d0 = (t & 3) * 16;
    unsigned short hh[16], mm[16], ll[16];
    #pragma unroll
    for (int j = 0; j < 16; ++j) {
        float a = T[d0 + j][n];
        unsigned short h = bf16_rne(a);
        float r1 = a - bf16_to_f(h);
        unsigned short m = bf16_rne(r1);
        float r2 = r1 - bf16_to_f(m);
        unsigned short l = bf16_rne(r2);
        hh[j] = h; mm[j] = m; ll[j] = l;
    }
    unsigned short* o = base + (size_t)n * DIM + d0;
    *(u32x4*)(o)            = *(u32x4*)&hh[0];
    *(u32x4*)(o + 8)        = *(u32x4*)&hh[8];
    *(u32x4*)(o + PL)       = *(u32x4*)&mm[0];
    *(u32x4*)(o + PL + 8)   = *(u32x4*)&mm[8];
    *(u32x4*)(o + 2*PL)     = *(u32x4*)&ll[0];
    *(u32x4*)(o + 2*PL + 8) = *(u32x4*)&ll[8];
}

// ===========================================================================
// Kernel H: phase-1 GEMM on h-planes only (K=512). Writes uhat (bf16 of
// 10000*dot_h/sqrt(512)) for ALL 2048x2048 per batch.
// ===========================================================================
__global__ __launch_bounds__(256, 2)
void score_h(const unsigned short* __restrict__ pA, const unsigned short* __restrict__ pB,
             unsigned short* __restrict__ uhat)
{
    const int bid  = blockIdx.x;
    const int xcd  = bid & 7;
    const int slot = bid >> 3;
    const int g    = xcd + 8 * (slot >> 4);
    const int ntile = slot & 15;
    const int b    = g >> 2;
    const int mc   = g & 3;
    const int n0 = ntile * 128;
    const int t  = threadIdx.x;
    const int w  = t >> 6;
    const int l  = t & 63;
    const int wn = w >> 1, wm = w & 1;
    const int l15 = l & 15, l4 = l >> 4;

    __shared__ unsigned short As[128 * 64];
    __shared__ unsigned short Bs[128 * 64];

    int srow[4], skg[4], ldsoff[4];
    #pragma unroll
    for (int qq = 0; qq < 4; ++qq) {
        int s = qq * 256 + t;
        int row = s >> 3, slt = s & 7;
        srow[qq] = row;
        skg[qq] = slt ^ (row & 7);
        ldsoff[qq] = row * 64 + slt * 8;
    }
    int aroff[4], arxor[4], broff[4], brxor[4];
    #pragma unroll
    for (int i = 0; i < 4; ++i) {
        int ar = wn * 64 + i * 16 + l15;
        aroff[i] = ar * 64; arxor[i] = ar & 7;
        int br = wm * 64 + i * 16 + l15;
        broff[i] = br * 64; brxor[i] = br & 7;
    }

    const float scl = 10000.0f / sqrtf((float)DIM);
    const unsigned short* Ab = pA + (size_t)b * NPTS * DIM;
    const unsigned short* Bb = pB + (size_t)b * NPTS * DIM;

    for (int mt = 0; mt < 4; ++mt) {
        const int m0 = mc * 512 + mt * 128;
        f32x4 acc[4][4];
        #pragma unroll
        for (int i = 0; i < 4; ++i)
            #pragma unroll
            for (int j = 0; j < 4; ++j) acc[i][j] = (f32x4){0.f, 0.f, 0.f, 0.f};

        for (int k0 = 0; k0 < 512; k0 += 64) {
            __syncthreads();
            bf16x8 ra[4], rb[4];
            #pragma unroll
            for (int qq = 0; qq < 4; ++qq) {
                ra[qq] = *(const bf16x8*)&Ab[(size_t)(n0 + srow[qq]) * DIM + k0 + skg[qq] * 8];
                rb[qq] = *(const bf16x8*)&Bb[(size_t)(m0 + srow[qq]) * DIM + k0 + skg[qq] * 8];
            }
            #pragma unroll
            for (int qq = 0; qq < 4; ++qq) {
                *(bf16x8*)&As[ldsoff[qq]] = ra[qq];
                *(bf16x8*)&Bs[ldsoff[qq]] = rb[qq];
            }
            __syncthreads();
            #pragma unroll
            for (int ks = 0; ks < 2; ++ks) {
                bf16x8 af[4], bfr[4];
                #pragma unroll
                for (int i = 0; i < 4; ++i) {
                    af[i]  = *(const bf16x8*)&As[aroff[i] + (((ks * 4 + l4) ^ arxor[i]) * 8)];
                    bfr[i] = *(const bf16x8*)&Bs[broff[i] + (((ks * 4 + l4) ^ brxor[i]) * 8)];
                }
                #pragma unroll
                for (int i = 0; i < 4; ++i)
                    #pragma unroll
                    for (int j = 0; j < 4; ++j)
                        acc[i][j] = __builtin_amdgcn_mfma_f32_16x16x32_bf16(af[i], bfr[j], acc[i][j], 0, 0, 0);
            }
        }
        #pragma unroll
        for (int i = 0; i < 4; ++i) {
            #pragma unroll
            for (int j = 0; j < 4; ++j) {
                int mcol = m0 + wm * 64 + j * 16 + l15;
                #pragma unroll
                for (int r = 0; r < 4; ++r) {
                    int nabs = n0 + wn * 64 + i * 16 + l4 * 4 + r;
                    uhat[((size_t)(b * NPTS + nabs)) * NPTS + mcol] =
                        bf16_rne(scl * acc[i][j][r]);
                }
            }
        }
    }
}

// ===========================================================================
// Kernel R: resolve. One wave per row. Fast path register-only; slow path
// wave-parallel exact 26-bit rescore.
// ===========================================================================
__global__ __launch_bounds__(256)
void resolve(const unsigned short* __restrict__ uhat,
             const unsigned short* __restrict__ pA, const unsigned short* __restrict__ pB,
             const float* __restrict__ tgt,
             float* __restrict__ corr_tgt, int* __restrict__ corres_i,
             float* __restrict__ corres_out)
{
    const int wid  = threadIdx.x >> 6;
    const int lane = threadIdx.x & 63;
    const int gid  = blockIdx.x * 4 + wid;
    const int b    = gid >> 11;
    const int n    = gid & 2047;

    __shared__ int s_m[4][64];
    __shared__ int s_cnt[4];

    if (lane == 0) s_cnt[wid] = 0;
    __syncthreads();

    const unsigned short* urow = uhat + (size_t)gid * NPTS;
    float v[32];
    float lmax = -3.402823466e38f; int lk = 0;
    #pragma unroll
    for (int g2 = 0; g2 < 4; ++g2) {
        u32x4 pk = *(const u32x4*)&urow[lane * 32 + g2 * 8];
        #pragma unroll
        for (int e = 0; e < 4; ++e) {
            unsigned int w2 = pk[e];
            float f0 = __uint_as_float((w2 & 0xFFFFu) << 16);
            float f1 = __uint_as_float(w2 & 0xFFFF0000u);
            int k0 = g2 * 8 + e * 2;
            v[k0] = f0; v[k0 + 1] = f1;
            if (f0 > lmax) { lmax = f0; lk = k0; }
            if (f1 > lmax) { lmax = f1; lk = k0 + 1; }
        }
    }
    float vmax = lmax; int argm = lane * 32 + lk;
    #pragma unroll
    for (int mask = 1; mask < 64; mask <<= 1) {
        float ov = __shfl_xor(vmax, mask);
        int   oi = __shfl_xor(argm, mask);
        if (ov > vmax || (ov == vmax && oi < argm)) { vmax = ov; argm = oi; }
    }
    const float cut = vmax - 1200.0f;
    int cnt2 = 0;
    #pragma unroll
    for (int k = 0; k < 32; ++k) cnt2 += (v[k] >= cut) ? 1 : 0;
    int nc = cnt2;
    #pragma unroll
    for (int mask = 1; mask < 64; mask <<= 1) nc += __shfl_xor(nc, mask);

    if (nc > 1) {
        #pragma unroll
        for (int k = 0; k < 32; ++k) {
            if (v[k] >= cut) {
                int slot = atomicAdd(&s_cnt[wid], 1);
                if (slot < 64) s_m[wid][slot] = lane * 32 + k;
            }
        }
    }
    __syncthreads();
    if (nc > 1 && lane == 0) {
        int ncc = nc > 64 ? 64 : nc;
        for (int i = 1; i < ncc; ++i) {
            int key = s_m[wid][i]; int j = i - 1;
            while (j >= 0 && s_m[wid][j] > key) { s_m[wid][j + 1] = s_m[wid][j]; --j; }
            s_m[wid][j + 1] = key;
        }
    }
    __syncthreads();

    if (nc == 1) {
        if (lane < 3) corr_tgt[(size_t)gid * 3 + lane] = tgt[((size_t)b * 3 + lane) * NPTS + argm];
        if (lane == 0) { corres_i[gid] = argm; corres_out[gid] = (float)argm; }
        return;
    }
    const int ncc = nc > 64 ? 64 : nc;

    const size_t PL = (size_t)BATCH * NPTS * DIM;
    const unsigned short* Ar = pA + ((size_t)b * NPTS + n) * DIM + lane * 8;
    bf16x8 a_h = *(const bf16x8*)&Ar[0];
    bf16x8 a_m = *(const bf16x8*)&Ar[PL];
    bf16x8 a_l = *(const bf16x8*)&Ar[2 * PL];
    float ah[8], am[8], al[8];
    #pragma unroll
    for (int e = 0; e < 8; ++e) {
        ah[e] = bf16_to_f((unsigned short)a_h[e]);
        am[e] = bf16_to_f((unsigned short)a_m[e]);
        al[e] = bf16_to_f((unsigned short)a_l[e]);
    }

    const float sqd = sqrtf((float)DIM);
    float umax = -3.402823466e38f; int uarg = 0x7fffffff;
    float myu = 0.f;
    for (int c = 0; c < ncc; ++c) {
        int mB = s_m[wid][c];
        const unsigned short* Br = pB + ((size_t)b * NPTS + mB) * DIM + lane * 8;
        bf16x8 b_h = *(const bf16x8*)&Br[0];
        bf16x8 b_m = *(const bf16x8*)&Br[PL];
        bf16x8 b_l = *(const bf16x8*)&Br[2 * PL];
        float part = 0.f;
        #pragma unroll
        for (int e = 0; e < 8; ++e) {
            float bh = bf16_to_f((unsigned short)b_h[e]);
            float bm = bf16_to_f((unsigned short)b_m[e]);
            float bl = bf16_to_f((unsigned short)b_l[e]);
            part += ah[e] * bh;
            part += ah[e] * bm;
            part += am[e] * bh;
            part += ah[e] * bl;
            part += am[e] * bm;
            part += al[e] * bh;
        }
        #pragma unroll
        for (int mask = 1; mask < 64; mask <<= 1) part += __shfl_xor(part, mask);
        float u = 10000.0f * (part / sqd);
        if (u > umax) { umax = u; uarg = mB; }
        if (lane == c) myu = u;
    }

    float p = (lane < ncc) ? expf(myu - umax) : 0.f;
    int myM = (lane < ncc) ? s_m[wid][lane] : 0;
    float tx = 0.f, ty = 0.f, tz = 0.f, ps = p;
    if (lane < ncc) {
        tx = p * tgt[((size_t)b * 3 + 0) * NPTS + myM];
        ty = p * tgt[((size_t)b * 3 + 1) * NPTS + myM];
        tz = p * tgt[((size_t)b * 3 + 2) * NPTS + myM];
    }
    #pragma unroll
    for (int mask = 1; mask < 64; mask <<= 1) {
        ps += __shfl_xor(ps, mask);
        tx += __shfl_xor(tx, mask);
        ty += __shfl_xor(ty, mask);
        tz += __shfl_xor(tz, mask);
    }
    if (lane == 0) {
        corr_tgt[(size_t)gid * 3 + 0] = tx / ps;
        corr_tgt[(size_t)gid * 3 + 1] = ty / ps;
        corr_tgt[(size_t)gid * 3 + 2] = tz / ps;
        corres_i[gid]   = uarg;
        corres_out[gid] = (float)uarg;
    }
}

// ===========================================================================
// FALLBACK Kernel A (round-8 proven): 6-product MFMA + fused online softmax
// ===========================================================================
__global__ __launch_bounds__(256, 2)
void score_mfma(const unsigned short* __restrict__ pA, const unsigned short* __restrict__ pB,
                const float* __restrict__ tgt, float* __restrict__ part)
{
    const int bid  = blockIdx.x;
    const int xcd  = bid & 7;
    const int slot = bid >> 3;
    const int g    = xcd + 8 * (slot >> 4);
    const int ntile = slot & 15;
    const int b    = g >> 2;
    const int mc   = g & 3;
    const int n0 = ntile * 128;
    const int t  = threadIdx.x;
    const int w  = t >> 6;
    const int l  = t & 63;
    const int wn = w >> 1, wm = w & 1;
    const int l15 = l & 15, l4 = l >> 4;

    __shared__ unsigned short As[128 * 64];
    __shared__ unsigned short Bs[128 * 64];

    const size_t PL = (size_t)BATCH * NPTS * DIM;

    int srow[4], skg[4], ldsoff[4];
    #pragma unroll
    for (int qq = 0; qq < 4; ++qq) {
        int s = qq * 256 + t;
        int row = s >> 3, slt = s & 7;
        srow[qq] = row;
        skg[qq] = slt ^ (row & 7);
        ldsoff[qq] = row * 64 + slt * 8;
    }
    int aroff[4], arxor[4], broff[4], brxor[4];
    #pragma unroll
    for (int i = 0; i < 4; ++i) {
        int ar = wn * 64 + i * 16 + l15;
        aroff[i] = ar * 64; arxor[i] = ar & 7;
        int br = wm * 64 + i * 16 + l15;
        broff[i] = br * 64; brxor[i] = br & 7;
    }

    float mx[16], sm[16], ax[16], ay[16], az[16]; int ag[16];
    #pragma unroll
    for (int si = 0; si < 16; ++si) {
        mx[si] = -3.402823466e38f; sm[si] = 0.f;
        ax[si] = 0.f; ay[si] = 0.f; az[si] = 0.f; ag[si] = 0;
    }

    const float sqd = sqrtf((float)DIM);
    const unsigned short* Ab = pA + (size_t)b * NPTS * DIM;
    const unsigned short* Bb = pB + (size_t)b * NPTS * DIM;
    const int AIDX[6] = {0, 0, 1, 0, 1, 2};
    const int BIDX[6] = {0, 1, 0, 2, 1, 0};

    for (int mt = 0; mt < 4; ++mt) {
        const int m0 = mc * 512 + mt * 128;
        f32x4 acc[4][4];
        #pragma unroll
        for (int i = 0; i < 4; ++i)
            #pragma unroll
            for (int j = 0; j < 4; ++j) acc[i][j] = (f32x4){0.f, 0.f, 0.f, 0.f};

        for (int q = 0; q < 6; ++q) {
            const unsigned short* Ap = Ab + (size_t)AIDX[q] * PL;
            const unsigned short* Bp = Bb + (size_t)BIDX[q] * PL;
            for (int k0 = 0; k0 < 512; k0 += 64) {
                __syncthreads();
                bf16x8 ra[4], rb[4];
                #pragma unroll
                for (int qq = 0; qq < 4; ++qq) {
                    ra[qq] = *(const bf16x8*)&Ap[(size_t)(n0 + srow[qq]) * DIM + k0 + skg[qq] * 8];
                    rb[qq] = *(const bf16x8*)&Bp[(size_t)(m0 + srow[qq]) * DIM + k0 + skg[qq] * 8];
                }
                #pragma unroll
                for (int qq = 0; qq < 4; ++qq) {
                    *(bf16x8*)&As[ldsoff[qq]] = ra[qq];
                    *(bf16x8*)&Bs[ldsoff[qq]] = rb[qq];
                }
                __syncthreads();
                #pragma unroll
                for (int ks = 0; ks < 2; ++ks) {
                    bf16x8 af[4], bfr[4];
                    #pragma unroll
                    for (int i = 0; i < 4; ++i) {
                        af[i]  = *(const bf16x8*)&As[aroff[i] + (((ks * 4 + l4) ^ arxor[i]) * 8)];
                        bfr[i] = *(const bf16x8*)&Bs[broff[i] + (((ks * 4 + l4) ^ brxor[i]) * 8)];
                    }
                    #pragma unroll
                    for (int i = 0; i < 4; ++i)
                        #pragma unroll
                        for (int j = 0; j < 4; ++j)
                            acc[i][j] = __builtin_amdgcn_mfma_f32_16x16x32_bf16(af[i], bfr[j], acc[i][j], 0, 0, 0);
                }
            }
        }
        float tg0[4], tg1[4], tg2[4];
        #pragma unroll
        for (int j = 0; j < 4; ++j) {
            int mcol = m0 + wm * 64 + j * 16 + l15;
            tg0[j] = tgt[((size_t)b * 3 + 0) * NPTS + mcol];
            tg1[j] = tgt[((size_t)b * 3 + 1) * NPTS + mcol];
            tg2[j] = tgt[((size_t)b * 3 + 2) * NPTS + mcol];
        }
        #pragma unroll
        for (int i = 0; i < 4; ++i) {
            #pragma unroll
            for (int r = 0; r < 4; ++r) {
                const int si = i * 4 + r;
                float u[4];
                float lm = -3.402823466e38f; int la = 0;
                #pragma unroll
                for (int j = 0; j < 4; ++j) {
                    float s  = acc[i][j][r] / sqd;
                    float uu = 10000.0f * s;
                    u[j] = uu;
                    if (uu > lm) { lm = uu; la = m0 + wm * 64 + j * 16 + l15; }
                }
                float nm = fmaxf(mx[si], lm);
                if (lm > mx[si]) ag[si] = la;
                float f = expf(mx[si] - nm);
                mx[si] = nm;
                float s_ = sm[si] * f, x_ = ax[si] * f, y_ = ay[si] * f, z_ = az[si] * f;
                #pragma unroll
                for (int j = 0; j < 4; ++j) {
                    float p = expf(u[j] - nm);
                    s_ += p; x_ += p * tg0[j]; y_ += p * tg1[j]; z_ += p * tg2[j];
                }
                sm[si] = s_; ax[si] = x_; ay[si] = y_; az[si] = z_;
            }
        }
    }

    #pragma unroll
    for (int si = 0; si < 16; ++si) {
        for (int mask = 1; mask < 16; mask <<= 1) {
            float omx = __shfl_xor(mx[si], mask);
            float osm = __shfl_xor(sm[si], mask);
            float oax = __shfl_xor(ax[si], mask);
            float oay = __shfl_xor(ay[si], mask);
            float oaz = __shfl_xor(az[si], mask);
            int   oag = __shfl_xor(ag[si], mask);
            float nm = fmaxf(mx[si], omx);
            float f1 = expf(mx[si] - nm), f2 = expf(omx - nm);
            sm[si] = sm[si] * f1 + osm * f2;
            ax[si] = ax[si] * f1 + oax * f2;
            ay[si] = ay[si] * f1 + oay * f2;
            az[si] = az[si] * f1 + oaz * f2;
            ag[si] = (omx > mx[si]) ? oag : ((omx == mx[si]) ? min(ag[si], oag) : ag[si]);
            mx[si] = nm;
        }
    }
    if (l15 == 0) {
        const int chunk = mc * 2 + wm;
        #pragma unroll
        for (int i = 0; i < 4; ++i)
            #pragma unroll
            for (int r = 0; r < 4; ++r) {
                const int si = i * 4 + r;
                int nabs = n0 + wn * 64 + i * 16 + l4 * 4 + r;
                size_t o = (((size_t)b * NPTS + nabs) * 8 + chunk) * 8;
                part[o + 0] = mx[si]; part[o + 1] = sm[si];
                part[o + 2] = ax[si]; part[o + 3] = ay[si]; part[o + 4] = az[si];
                part[o + 5] = __int_as_float(ag[si]);
            }
    }
}

__global__ __launch_bounds__(256)
void merge8_kernel(const float* __restrict__ part, float* __restrict__ corr_tgt,
                   int* __restrict__ corres_i, float* __restrict__ corres_out)
{
    int r = blockIdx.x * 256 + threadIdx.x;
    float m = -3.402823466e38f, s = 0.f, x = 0.f, y = 0.f, z = 0.f; int a = 0x7fffffff;
    for (int c = 0; c < 8; ++c) {
        const float* p = &part[((size_t)r * 8 + c) * 8];
        float pm = p[0]; int pa = __float_as_int(p[5]);
        float nm = fmaxf(m, pm);
        float f1 = expf(m - nm), f2 = expf(pm - nm);
        s = s * f1 + p[1] * f2;
        x = x * f1 + p[2] * f2;
        y = y * f1 + p[3] * f2;
        z = z * f1 + p[4] * f2;
        if (pm > m) a = pa; else if (pm == m) a = min(a, pa);
        m = nm;
    }
    corr_tgt[(size_t)r * 3 + 0] = x / s;
    corr_tgt[(size_t)r * 3 + 1] = y / s;
    corr_tgt[(size_t)r * 3 + 2] = z / s;
    corres_i[r]   = a;
    corres_out[r] = (float)a;
}

// ===========================================================================
// Kernel B0: P4 = (x,y,z,|p|^2) per source point
// ===========================================================================
__global__ __launch_bounds__(256)
void prep_p4(const float* __restrict__ src, float4* __restrict__ P4)
{
    int i = blockIdx.x * 256 + threadIdx.x;
    int b = i >> 11, m = i & 2047;
    float x = src[((size_t)b * 3 + 0) * NPTS + m];
    float y = src[((size_t)b * 3 + 1) * NPTS + m];
    float z = src[((size_t)b * 3 + 2) * NPTS + m];
    P4[i] = make_float4(x, y, z, x * x + y * y + z * z);
}

// ===========================================================================
// Kernel B1 (v4): threshold-prefilter top-10. One 32-lane group per row.
// Pass 1: lane-min of clamped d2 (no chain/expf). T = 10th-smallest lane-min
// (upper bound for 10th-smallest d2). Pass 2: admit d2 <= T+1e-4 (margin
// covers any w-rounding tie window ~2.4e-7), exact u64 key (expf w, idx) into
// LDS. Final: butterfly merge of <=64 keys. cnt>KCAP -> proven chain fallback.
// ===========================================================================
__global__ __launch_bounds__(256)
void knn_topk(const float4* __restrict__ P4, int* __restrict__ topI)
{
    const int bid = blockIdx.x;                    // 0..2047
    const int b = bid >> 8, nblk = bid & 255;
    const int t = threadIdx.x;
    const int c  = t & 31;                         // lane-in-group
    const int rl = t >> 5;                         // row-in-block 0..7
    const int n = nblk * 8 + rl;
    const float4* Pb = P4 + (size_t)b * NPTS;
    const float4 pn = Pb[n];

    __shared__ unsigned long long Lbuf[8][KCAP];   // 4 KB
    __shared__ int cnt[8];
    if (c == 0) cnt[rl] = 0;
    __syncthreads();

    // ---- pass 1: lane-min of clamped d2 over strided candidates ----
    float lmin = 3.402823466e38f;
    for (int i = 0; i < 64; ++i) {
        int m = i * 32 + c;
        float4 pm = Pb[m];
        float dot = pn.x * pm.x + pn.y * pm.y + pn.z * pm.z;
        float d2 = (pn.w + pm.w) - 2.0f * dot;
        d2 = fmaxf(d2, 0.f);
        lmin = fminf(lmin, d2);
    }
    // ---- T = 10th smallest of 32 lane-mins (dups only enlarge T) ----
    float vv = lmin, Tt = 0.f;
    for (int r = 0; r < 10; ++r) {
        float gm = vv;
        #pragma unroll
        for (int mask = 1; mask < 32; mask <<= 1)
            gm = fminf(gm, __shfl_xor(gm, mask));
        Tt = gm;
        vv = (vv == gm) ? 3.402823466e38f : vv;
    }
    const float Tp = Tt + 1e-4f;

    // ---- pass 2: collect admitted candidates with exact keys ----
    for (int i = 0; i < 64; ++i) {
        int m = i * 32 + c;
        float4 pm = Pb[m];
        float dot = pn.x * pm.x + pn.y * pm.y + pn.z * pm.z;
        float d2 = (pn.w + pm.w) - 2.0f * dot;
        d2 = fmaxf(d2, 0.f);
        if (d2 <= Tp) {
            float w = expf(-d2 * 0.5f);
            unsigned long long key =
                ((unsigned long long)(~__float_as_uint(w)) << 32) | (unsigned int)m;
            int slot = atomicAdd(&cnt[rl], 1);
            if (slot < KCAP) Lbuf[rl][slot] = key;
        }
    }
    __syncthreads();

    unsigned long long kl[KNN];
    const int cr = cnt[rl];
    if (cr <= KCAP) {
        const unsigned long long UMAX = 0xFFFFFFFFFFFFFFFFull;
        unsigned long long e0 = (c      < cr) ? Lbuf[rl][c]      : UMAX;
        unsigned long long e1 = (c + 32 < cr) ? Lbuf[rl][c + 32] : UMAX;
        kl[0] = e0 < e1 ? e0 : e1;
        kl[1] = e0 < e1 ? e1 : e0;
        #pragma unroll
        for (int k = 2; k < KNN; ++k) kl[k] = UMAX;
    } else {
        // fallback: proven per-lane chain scan (unreachable for sane data)
        unsigned int kx[KNN], ix[KNN];
        #pragma unroll
        for (int k = 0; k < KNN; ++k) { kx[k] = 0xFFFFFFFFu; ix[k] = 0xFFFFFFFFu; }
        for (int i = 0; i < 64; ++i) {
            int m = i * 32 + c;
            float4 pm = Pb[m];
            float dot = pn.x * pm.x + pn.y * pm.y + pn.z * pm.z;
            float d2 = (pn.w + pm.w) - 2.0f * dot;
            d2 = fmaxf(d2, 0.f);
            float w = expf(-d2 * 0.5f);
            unsigned int key = ~__float_as_uint(w);
            if (key < kx[KNN - 1]) {
                unsigned int ck = key, ci = (unsigned int)m;
                #pragma unroll
                for (int k = 0; k < KNN; ++k) {
                    bool lt = ck < kx[k];
                    unsigned int tk = kx[k], ti = ix[k];
                    kx[k] = lt ? ck : kx[k];
                    ix[k] = lt ? ci : ix[k];
                    ck = lt ? tk : ck;
                    ci = lt ? ti : ci;
                }
            }
        }
        #pragma unroll
        for (int k = 0; k < KNN; ++k)
            kl[k] = ((unsigned long long)kx[k] << 32) | ix[k];
    }

    // ---- butterfly merge across the 32 lanes of this row-group ----
    #pragma unroll
    for (int mask = 1; mask < 32; mask <<= 1) {
        unsigned long long B[KNN];
        #pragma unroll
        for (int k = 0; k < KNN; ++k) B[k] = shflx_u64(kl[k], mask);
        unsigned long long M[KNN];
        #pragma unroll
        for (int k = 0; k < KNN; ++k) {
            unsigned long long best = B[k];
            #pragma unroll
            for (int i = 1; i <= k; ++i) {
                unsigned long long hi = kl[i - 1] > B[k - i] ? kl[i - 1] : B[k - i];
                best = hi < best ? hi : best;
            }
            unsigned long long ak = kl[k];
            M[k] = ak < best ? ak : best;
        }
        #pragma unroll
        for (int k = 0; k < KNN; ++k) kl[k] = M[k];
    }

    if (c == 0) {
        size_t gid = (size_t)(b << 11) + n;
        #pragma unroll
        for (int k = 0; k < KNN; ++k)
            topI[gid * KNN + k] = (int)(kl[k] & 0xFFFFFFFFull);
    }
}

// ===========================================================================
// Kernel B2: wave-per-n GFM finish (4096 blocks x 4 waves)
// ===========================================================================
__global__ __launch_bounds__(256)
void gfm_finish(const float4* __restrict__ P4, const float* __restrict__ corr_tgt,
                const int* __restrict__ topI, float* __restrict__ mean_loss)
{
    const int wid  = threadIdx.x >> 6;
    const int lane = threadIdx.x & 63;
    const int gid  = blockIdx.x * 4 + wid;
    const int b    = gid >> 11;

    __shared__ float PT[4][KNN][6];
    __shared__ float LS[4][48];
    __shared__ float SR[4][48];
    __shared__ float TOT[4][48];

    if (lane < KNN) {
        int idx = topI[(size_t)gid * KNN + lane];
        float4 pk = P4[(b << 11) + idx];
        size_t o = ((size_t)(b << 11) + idx) * 3;
        PT[wid][lane][0] = pk.x; PT[wid][lane][1] = pk.y; PT[wid][lane][2] = pk.z;
        PT[wid][lane][3] = corr_tgt[o];
        PT[wid][lane][4] = corr_tgt[o + 1];
        PT[wid][lane][5] = corr_tgt[o + 2];
    }
    float4 pn = P4[gid];
    size_t on = (size_t)gid * 3;
    const float cnx = corr_tgt[on], cny = corr_tgt[on + 1], cnz = corr_tgt[on + 2];
    __syncthreads();

    int pi = 0, pj = 1;
    {
        int pp = lane;
        #pragma unroll
        for (int r = 0; r < 9; ++r) {
            int cnt3 = 9 - r;
            if (pp >= 0 && pp < cnt3) { pi = r; pj = r + 1 + pp; }
            pp -= cnt3;
        }
    }

    float ls_p = 0.f, rg_p = 0.f;
    if (lane < NPAIR) {
        float e1x = PT[wid][pi][0] - pn.x, e1y = PT[wid][pi][1] - pn.y, e1z = PT[wid][pi][2] - pn.z;
        float e2x = PT[wid][pj][0] - pn.x, e2y = PT[wid][pj][1] - pn.y, e2z = PT[wid][pj][2] - pn.z;
        float cx = e1y * e2z - e1z * e2y;
        float cy = e1z * e2x - e1x * e2z;
        float cz = e1x * e2y - e1y * e2x;
        float as_ = 0.5f * sqrtf(cx * cx + cy * cy + cz * cz);
        float f1x = PT[wid][pi][3] - cnx, f1y = PT[wid][pi][4] - cny, f1z = PT[wid][pi][5] - cnz;
        float f2x = PT[wid][pj][3] - cnx, f2y = PT[wid][pj][4] - cny, f2z = PT[wid][pj][5] - cnz;
        float gx = f1y * f2z - f1z * f2y;
        float gy = f1z * f2x - f1x * f2z;
        float gz = f1x * f2y - f1y * f2x;
        float at_ = 0.5f * sqrtf(gx * gx + gy * gy + gz * gz);
        float tl2 = at_ + 1e-6f;
        float dd  = as_ - tl2;
        float e2_ = 1e-6f * 1e-6f;
        float num = (e2_ + e2_) + dd * dd;
        float den = (1e-6f + 1e-6f) + (as_ + tl2);
        ls_p = num / den;
        rg_p = sqrtf(num);
        LS[wid][lane] = ls_p;
    }
    __syncthreads();

    int rk = 0;
    if (lane < NPAIR) {
        #pragma unroll
        for (int q = 0; q < NPAIR; ++q) {
            float lq = LS[wid][q];
            rk += (lq < ls_p) || (lq == ls_p && q < lane);
        }
        SR[wid][rk] = ls_p;
    }
    __syncthreads();

    float tot_p = 0.f;
    if (lane < NPAIR) {
        tot_p = SR[wid][lane] + 0.1f * rg_p;
        TOT[wid][lane] = tot_p;
    }
    __syncthreads();

    int rt2 = 0;
    if (lane < NPAIR) {
        #pragma unroll
        for (int q = 0; q < NPAIR; ++q) {
            float tq = TOT[wid][q];
            rt2 += (tq < tot_p) || (tq == tot_p && q < lane);
        }
        SR[wid][rt2] = tot_p;
    }
    __syncthreads();

    float med = SR[wid][22];
    float thr = 3.0f * med;
    if (lane < KNN) {
        float v = tot_p;
        v = (v > thr) ? 0.0f : v;
        LS[wid][lane] = sqrtf(v + 1e-6f);
    }
    __syncthreads();
    if (lane == 0) {
        float acc = 0.f;
        #pragma unroll
        for (int k = 0; k < KNN; ++k) acc += LS[wid][k];
        mean_loss[gid] = acc / 10.0f;
    }
}

// ===========================================================================
// Kernel C: per-batch min + binary weight
// ===========================================================================
__global__ __launch_bounds__(256)
void weight_kernel(const float* __restrict__ mean_loss, float* __restrict__ weight_out)
{
    const int b = blockIdx.x;
    const int t = threadIdx.x;
    __shared__ float red[256];
    float mn = 3.402823466e38f;
    for (int i = t; i < NPTS; i += 256)
        mn = fminf(mn, mean_loss[(size_t)b * NPTS + i]);
    red[t] = mn; __syncthreads();
    for (int s2 = 128; s2 > 0; s2 >>= 1) {
        if (t < s2) red[t] = fminf(red[t], red[t + s2]);
        __syncthreads();
    }
    float ml = red[0];
    for (int i = t; i < NPTS; i += 256) {
        float d = mean_loss[(size_t)b * NPTS + i] - ml;
        float e = expf(-20.0f * d);
        float wts = 2.0f * (e / (1.0f + e));
        weight_out[(size_t)b * NPTS + i] = (wts > 0.5f) ? 1.0f : 0.0f;
    }
}

// ===========================================================================
// Kernel D: weighted Procrustes per batch (Horn quaternion)
// ===========================================================================
__device__ void jacobi4(double A[4][4], double V[4][4]) {
    for (int i = 0; i < 4; ++i)
        for (int j = 0; j < 4; ++j) V[i][j] = (i == j) ? 1.0 : 0.0;
    for (int sweep = 0; sweep < 12; ++sweep) {
        for (int p = 0; p < 3; ++p) for (int q = p + 1; q < 4; ++q) {
            double apq = A[p][q];
            if (fabs(apq) < 1e-30) continue;
            double theta = (A[q][q] - A[p][p]) / (2.0 * apq);
            double tt = (theta >= 0 ? 1.0 : -1.0) / (fabs(theta) + sqrt(theta * theta + 1.0));
            double c = 1.0 / sqrt(tt * tt + 1.0), s = tt * c;
            for (int k = 0; k < 4; ++k) {
                double akp = A[k][p], akq = A[k][q];
                A[k][p] = c * akp - s * akq;
                A[k][q] = s * akp + c * akq;
            }
            for (int k = 0; k < 4; ++k) {
                double apk = A[p][k], aqk = A[q][k];
                A[p][k] = c * apk - s * aqk;
                A[q][k] = s * apk + c * aqk;
            }
            for (int k = 0; k < 4; ++k) {
                double vkp = V[k][p], vkq = V[k][q];
                V[k][p] = c * vkp - s * vkq;
                V[k][q] = s * vkp + c * vkq;
            }
        }
    }
}

__global__ __launch_bounds__(256)
void procrustes_kernel(const float* __restrict__ src, const float* __restrict__ tgt,
                       const int* __restrict__ corres_i, const float* __restrict__ weight,
                       float* __restrict__ outR, float* __restrict__ outT)
{
    const int b = blockIdx.x;
    const int t = threadIdx.x;
    __shared__ float red[256][9];
    __shared__ float s_tw, s_mx[3], s_my[3];
    __shared__ float s_cov[9];

    float a0 = 0, a1 = 0, a2 = 0, a3 = 0, a4 = 0, a5 = 0, a6 = 0;
    for (int i = t; i < NPTS; i += 256) {
        float w = weight[(size_t)b * NPTS + i];
        float X0 = src[((size_t)b * 3 + 0) * NPTS + i];
        float X1 = src[((size_t)b * 3 + 1) * NPTS + i];
        float X2 = src[((size_t)b * 3 + 2) * NPTS + i];
        int c = corres_i[(size_t)b * NPTS + i];
        float Y0 = tgt[((size_t)b * 3 + 0) * NPTS + c];
        float Y1 = tgt[((size_t)b * 3 + 1) * NPTS + c];
        float Y2 = tgt[((size_t)b * 3 + 2) * NPTS + c];
        a0 += w;
        a1 += w * X0; a2 += w * X1; a3 += w * X2;
        a4 += w * Y0; a5 += w * Y1; a6 += w * Y2;
    }
    red[t][0] = a0; red[t][1] = a1; red[t][2] = a2; red[t][3] = a3;
    red[t][4] = a4; red[t][5] = a5; red[t][6] = a6; red[t][7] = 0; red[t][8] = 0;
    __syncthreads();
    for (int s2 = 128; s2 > 0; s2 >>= 1) {
        if (t < s2)
            for (int k = 0; k < 7; ++k) red[t][k] += red[t + s2][k];
        __syncthreads();
    }
    if (t == 0) {
        float tw = red[0][0];
        float itw = tw + 1e-7f;
        s_tw = tw;
        s_mx[0] = red[0][1] / itw; s_mx[1] = red[0][2] / itw; s_mx[2] = red[0][3] / itw;
        s_my[0] = red[0][4] / itw; s_my[1] = red[0][5] / itw; s_my[2] = red[0][6] / itw;
    }
    __syncthreads();
    const float twp = s_tw + 1e-7f;
    const float mx0 = s_mx[0], mx1 = s_mx[1], mx2 = s_mx[2];
    const float my0 = s_my[0], my1 = s_my[1], my2 = s_my[2];

    float cv[9] = {0,0,0,0,0,0,0,0,0};
    for (int i = t; i < NPTS; i += 256) {
        float w = weight[(size_t)b * NPTS + i];
        float nwn = w / twp;
        float X0 = src[((size_t)b * 3 + 0) * NPTS + i] - mx0;
        float X1 = src[((size_t)b * 3 + 1) * NPTS + i] - mx1;
        float X2 = src[((size_t)b * 3 + 2) * NPTS + i] - mx2;
        int c = corres_i[(size_t)b * NPTS + i];
        float Y0 = tgt[((size_t)b * 3 + 0) * NPTS + c] - my0;
        float Y1 = tgt[((size_t)b * 3 + 1) * NPTS + c] - my1;
        float Y2 = tgt[((size_t)b * 3 + 2) * NPTS + c] - my2;
        float b0 = nwn * X0, b1 = nwn * X1, b2 = nwn * X2;
        cv[0] += Y0 * b0; cv[1] += Y0 * b1; cv[2] += Y0 * b2;
        cv[3] += Y1 * b0; cv[4] += Y1 * b1; cv[5] += Y1 * b2;
        cv[6] += Y2 * b0; cv[7] += Y2 * b1; cv[8] += Y2 * b2;
    }
    __syncthreads();
    for (int k = 0; k < 9; ++k) red[t][k] = cv[k];
    __syncthreads();
    for (int s2 = 128; s2 > 0; s2 >>= 1) {
        if (t < s2)
            for (int k = 0; k < 9; ++k) red[t][k] += red[t + s2][k];
        __syncthreads();
    }
    if (t == 0) for (int k = 0; k < 9; ++k) s_cov[k] = red[0][k];
    __syncthreads();

    if (t == 0) {
        double cov[3][3];
        for (int i = 0; i < 3; ++i)
            for (int j = 0; j < 3; ++j) cov[i][j] = (double)s_cov[i * 3 + j];
        double S[3][3];
        for (int a = 0; a < 3; ++a)
            for (int bb = 0; bb < 3; ++bb) S[a][bb] = cov[bb][a];
        double N4[4][4];
        N4[0][0] = S[0][0] + S[1][1] + S[2][2];
        N4[0][1] = S[1][2] - S[2][1];
        N4[0][2] = S[2][0] - S[0][2];
        N4[0][3] = S[0][1] - S[1][0];
        N4[1][1] = S[0][0] - S[1][1] - S[2][2];
        N4[1][2] = S[0][1] + S[1][0];
        N4[1][3] = S[2][0] + S[0][2];
        N4[2][2] = -S[0][0] + S[1][1] - S[2][2];
        N4[2][3] = S[1][2] + S[2][1];
        N4[3][3] = -S[0][0] - S[1][1] + S[2][2];
        N4[1][0] = N4[0][1]; N4[2][0] = N4[0][2]; N4[3][0] = N4[0][3];
        N4[2][1] = N4[1][2]; N4[3][1] = N4[1][3]; N4[3][2] = N4[2][3];
        double V[4][4];
        jacobi4(N4, V);
        int best = 0; double bl = N4[0][0];
        for (int k = 1; k < 4; ++k) if (N4[k][k] > bl) { bl = N4[k][k]; best = k; }
        double q0 = V[0][best], qx = V[1][best], qy = V[2][best], qz = V[3][best];
        double nq = sqrt(q0 * q0 + qx * qx + qy * qy + qz * qz);
        q0 /= nq; qx /= nq; qy /= nq; qz /= nq;
        double Rm[3][3];
        Rm[0][0] = q0*q0 + qx*qx - qy*qy - qz*qz;
        Rm[0][1] = 2.0 * (qx*qy - q0*qz);
        Rm[0][2] = 2.0 * (qx*qz + q0*qy);
        Rm[1][0] = 2.0 * (qx*qy + q0*qz);
        Rm[1][1] = q0*q0 - qx*qx + qy*qy - qz*qz;
        Rm[1][2] = 2.0 * (qy*qz - q0*qx);
        Rm[2][0] = 2.0 * (qx*qz - q0*qy);
        Rm[2][1] = 2.0 * (qy*qz + q0*qx);
        Rm[2][2] = q0*q0 - qx*qx - qy*qy + qz*qz;
        double o1 = 0, o2 = 0;
        for (int i = 0; i < 3; ++i)
            for (int j = 0; j < 3; ++j) { o1 += Rm[i][j] * cov[i][j]; o2 += Rm[j][i] * cov[i][j]; }
        if (o2 > o1) {
            for (int i = 0; i < 3; ++i)
                for (int j = i + 1; j < 3; ++j) {
                    double tv = Rm[i][j]; Rm[i][j] = Rm[j][i]; Rm[j][i] = tv;
                }
        }
        float Rf[3][3];
        for (int i = 0; i < 3; ++i)
            for (int j = 0; j < 3; ++j) {
                Rf[i][j] = (float)Rm[i][j];
                outR[(size_t)b * 9 + i * 3 + j] = Rf[i][j];
            }
        float rm[3];
        float mxv[3] = {mx0, mx1, mx2};
        float myv[3] = {my0, my1, my2};
        for (int i = 0; i < 3; ++i)
            rm[i] = Rf[i][0] * mxv[0] + Rf[i][1] * mxv[1] + Rf[i][2] * mxv[2];
        for (int i = 0; i < 3; ++i)
            for (int j = 0; j < 3; ++j)
                outT[(size_t)b * 9 + i * 3 + j] = myv[j] - rm[i];
    }
}

// ===========================================================================
extern "C" void kernel_launch(void* const* d_in, const int* in_sizes, int n_in,
                              void* d_out, int out_size, void* d_ws, size_t ws_size,
                              hipStream_t stream)
{
    const float* se  = (const float*)d_in[0];
    const float* te  = (const float*)d_in[1];
    const float* src = (const float*)d_in[2];
    const float* tgt = (const float*)d_in[3];

    float* out  = (float*)d_out;
    float* outR = out;
    float* outT = out + 72;
    float* outC = out + 144;
    float* outW = out + 144 + BATCH * NPTS;

    char* wsb = (char*)d_ws;
    float* corr_tgt  = (float*)wsb;                                    // 196608 B
    int*   corres_i  = (int*)(wsb + 196608);                           // 65536 B
    float* mean_loss = (float*)(wsb + 262144);                         // 65536 B
    float* part      = (float*)(wsb + 327680);                         // 4 MB (fallback only)

    float4* P4   = (float4*)(wsb + 327680);                            // 262144 B
    int*    topI = (int*)(wsb + 589824);                               // 655360 B

    const size_t PLANES_OFF = 4521984;
    const size_t PL_BYTES   = (size_t)3 * BATCH * NPTS * DIM * 2;      // 50331648
    const size_t NEED       = PLANES_OFF + 2 * PL_BYTES;               // 105185280
    const size_t UHAT_BYTES = (size_t)BATCH * NPTS * NPTS * 2;         // 67108864
    const size_t NEED2      = NEED + UHAT_BYTES;                       // 172294144

    unsigned short* pA = (unsigned short*)(wsb + PLANES_OFF);
    unsigned short* pB = (unsigned short*)(wsb + PLANES_OFF + PL_BYTES);
    unsigned short* uhat = (unsigned short*)(wsb + NEED);

    hipLaunchKernelGGL(split_kernel, dim3(4096), dim3(256), 0, stream, se, te, pA, pB);
    if (ws_size >= NEED2) {
        hipLaunchKernelGGL(score_h, dim3(512), dim3(256), 0, stream, pA, pB, uhat);
        hipLaunchKernelGGL(resolve, dim3(BATCH * NPTS / 4), dim3(256), 0, stream,
                           uhat, pA, pB, tgt, corr_tgt, corres_i, outC);
    } else {
        hipLaunchKernelGGL(score_mfma, dim3(512), dim3(256), 0, stream, pA, pB, tgt, part);
        hipLaunchKernelGGL(merge8_kernel, dim3(BATCH * NPTS / 256), dim3(256), 0, stream,
                           part, corr_tgt, corres_i, outC);
    }
    hipLaunchKernelGGL(prep_p4, dim3(BATCH * NPTS / 256), dim3(256), 0, stream, src, P4);
    hipLaunchKernelGGL(knn_topk, dim3(BATCH * 256), dim3(256), 0, stream, P4, topI);
    hipLaunchKernelGGL(gfm_finish, dim3(BATCH * NPTS / 4), dim3(256), 0, stream,
                       P4, corr_tgt, topI, mean_loss);
    hipLaunchKernelGGL(weight_kernel, dim3(BATCH), dim3(256), 0, stream,
                       mean_loss, outW);
    hipLaunchKernelGGL(procrustes_kernel, dim3(BATCH), dim3(256), 0, stream,
                       src, tgt, corres_i, outW, outR, outT);
}